// Round 1
// baseline (1135.787 us; speedup 1.0000x reference)
//
#include <hip/hip_runtime.h>
#include <math.h>

#define Bb 64
#define N0 1024
#define NE 16384
#define Fd 128
#define K1 512
#define K2 256

__device__ __forceinline__ float wred_sum(float v) {
#pragma unroll
  for (int o = 32; o > 0; o >>= 1) v += __shfl_down(v, o, 64);
  return v;
}
__device__ __forceinline__ float wred_max(float v) {
#pragma unroll
  for (int o = 32; o > 0; o >>= 1) v = fmaxf(v, __shfl_down(v, o, 64));
  return v;
}

// ---- build binary adjacency as bitmask: adj[b][i] = 32 words of row bits ----
__global__ void k_scatter(const int* __restrict__ src, const int* __restrict__ dst,
                          unsigned* __restrict__ adj) {
  int idx = blockIdx.x * 256 + threadIdx.x;
  if (idx >= Bb * NE) return;
  int b = idx >> 14, e = idx & (NE - 1);
  int u = src[b * NE + e], v = dst[b * NE + e];
  if (u == v) return;
  atomicOr(&adj[((b << 10) + u) * 32 + (v >> 5)], 1u << (v & 31));
  atomicOr(&adj[((b << 10) + v) * 32 + (u >> 5)], 1u << (u & 31));
}

__global__ void k_degree(const unsigned* __restrict__ adj, float* __restrict__ dis0,
                         float* __restrict__ dis1) {
  int row = blockIdx.x * 256 + threadIdx.x;
  if (row >= Bb * N0) return;
  int d = 0;
  const unsigned* w = adj + (size_t)row * 32;
#pragma unroll
  for (int i = 0; i < 32; ++i) d += __popc(w[i]);
  dis0[row] = d > 0 ? rsqrtf((float)d) : 0.f;
  dis1[row] = rsqrtf((float)(d + 1));
}

// ---- C[M,128] = X[M,128] @ W[128,128], M % 64 == 0, grid = M/64, block 256 ----
__global__ __launch_bounds__(256) void k_gemm128(const float* __restrict__ X,
                                                 const float* __restrict__ W,
                                                 float* __restrict__ C) {
  __shared__ float Xs[64][132];
  __shared__ float Ws[32][132];
  int t = threadIdx.x;
  size_t row0 = (size_t)blockIdx.x * 64;
  const float4* Xg = (const float4*)(X + row0 * Fd);
#pragma unroll
  for (int i = 0; i < 8; ++i) {
    int f4 = t + 256 * i;
    float4 v = Xg[f4];
    *(float4*)&Xs[f4 >> 5][(f4 & 31) * 4] = v;
  }
  int r0 = (t >> 5) * 8, c0 = (t & 31) * 4;
  float acc[8][4] = {};
  for (int kb = 0; kb < 128; kb += 32) {
    __syncthreads();
#pragma unroll
    for (int i = 0; i < 4; ++i) {
      int f4 = t + 256 * i;
      float4 v = ((const float4*)(W + (size_t)kb * Fd))[f4];
      *(float4*)&Ws[f4 >> 5][(f4 & 31) * 4] = v;
    }
    __syncthreads();
#pragma unroll
    for (int k = 0; k < 32; ++k) {
      float4 wv = *(const float4*)&Ws[k][c0];
#pragma unroll
      for (int i = 0; i < 8; ++i) {
        float xv = Xs[r0 + i][kb + k];
        acc[i][0] += xv * wv.x; acc[i][1] += xv * wv.y;
        acc[i][2] += xv * wv.z; acc[i][3] += xv * wv.w;
      }
    }
  }
#pragma unroll
  for (int i = 0; i < 8; ++i) {
    float4 o = make_float4(acc[i][0], acc[i][1], acc[i][2], acc[i][3]);
    *(float4*)&C[(row0 + r0 + i) * Fd + c0] = o;
  }
}

// ---- conv1: h1 = relu(dis1_i*(sum_{j in N(i)} dis1_j XW_j + dis1_i XW_i) + b1) ----
__global__ __launch_bounds__(128) void k_conv1(const unsigned* __restrict__ adj,
    const float* __restrict__ XW, const float* __restrict__ dis1,
    const float* __restrict__ b1, float* __restrict__ h1) {
  int row = blockIdx.x, f = threadIdx.x;
  int base = row & ~(N0 - 1);
  __shared__ unsigned wbuf[32];
  if (f < 32) wbuf[f] = adj[(size_t)row * 32 + f];
  __syncthreads();
  const float* XWb = XW + (size_t)base * Fd;
  const float* db = dis1 + base;
  float di = dis1[row];
  float acc = di * XW[(size_t)row * Fd + f];
  for (int w = 0; w < 32; ++w) {
    unsigned m = wbuf[w];
    while (m) {
      int j = (w << 5) + __ffs(m) - 1;
      m &= m - 1;
      acc += db[j] * XWb[(size_t)j * Fd + f];
    }
  }
  h1[(size_t)row * Fd + f] = fmaxf(di * acc + b1[f], 0.f);
}

// ---- NIS on binary A: score_i = sum_f |h_i - dis0_i * sum_j dis0_j h_j| ----
__global__ __launch_bounds__(128) void k_nis1(const unsigned* __restrict__ adj,
    const float* __restrict__ h, const float* __restrict__ dis0, float* __restrict__ score) {
  int row = blockIdx.x, f = threadIdx.x;
  int base = row & ~(N0 - 1);
  __shared__ unsigned wbuf[32];
  __shared__ float red[2];
  if (f < 32) wbuf[f] = adj[(size_t)row * 32 + f];
  __syncthreads();
  const float* hb = h + (size_t)base * Fd;
  const float* db = dis0 + base;
  float acc = 0.f;
  for (int w = 0; w < 32; ++w) {
    unsigned m = wbuf[w];
    while (m) {
      int j = (w << 5) + __ffs(m) - 1;
      m &= m - 1;
      acc += db[j] * hb[(size_t)j * Fd + f];
    }
  }
  float val = h[(size_t)row * Fd + f] - dis0[row] * acc;
  float p = wred_sum(fabsf(val));
  if ((f & 63) == 0) red[f >> 6] = p;
  __syncthreads();
  if (f == 0) score[row] = red[0] + red[1];
}

// ---- exact top-k per graph: bitonic sort of (score,idx) packed u64 keys ----
__global__ __launch_bounds__(1024) void k_topk(const float* __restrict__ score,
                                               int* __restrict__ perm, int n, int k) {
  __shared__ unsigned long long keys[1024];
  int b = blockIdx.x, t = threadIdx.x;
  float s = score[b * n + t];
  unsigned ub = __float_as_uint(s);
  unsigned su = (ub & 0x80000000u) ? ~ub : (ub | 0x80000000u);  // monotone map
  keys[t] = ((unsigned long long)(~su) << 32) | (unsigned)t;    // asc sort = desc score, asc idx
  __syncthreads();
  for (int kk = 2; kk <= n; kk <<= 1) {
    for (int j = kk >> 1; j > 0; j >>= 1) {
      int ixj = t ^ j;
      if (ixj > t) {
        unsigned long long a = keys[t], c = keys[ixj];
        bool up = ((t & kk) == 0);
        if ((a > c) == up) { keys[t] = c; keys[ixj] = a; }
      }
      __syncthreads();
    }
  }
  if (t < k) perm[b * k + t] = (int)(keys[t] & 0xffffffffu);
}

// ---- gather pooled rows + attention dots ----
__global__ __launch_bounds__(128) void k_gather(const float* __restrict__ h,
    const int* __restrict__ perm, const float* __restrict__ att, float* __restrict__ Xp,
    float* __restrict__ ar, float* __restrict__ ac, int n, int k) {
  int idx = blockIdx.x, f = threadIdx.x;
  int b = idx / k;
  __shared__ float red[4];
  int p = perm[idx];
  float v = h[((size_t)b * n + p) * Fd + f];
  Xp[(size_t)idx * Fd + f] = v;
  float r1 = wred_sum(v * att[f]);
  float r2 = wred_sum(v * att[Fd + f]);
  if ((f & 63) == 0) { red[f >> 6] = r1; red[2 + (f >> 6)] = r2; }
  __syncthreads();
  if (f == 0) { ar[idx] = red[0] + red[1]; ac[idx] = red[2] + red[3]; }
}

// ---- readout: g[b][0:128] (+)= relu(max), g[b][128:256] (+)= relu(mean) ----
__global__ __launch_bounds__(128) void k_readout(const float* __restrict__ X, int n,
                                                 float* __restrict__ g, int init) {
  int b = blockIdx.x, f = threadIdx.x;
  float mx = -3.0e38f, sm = 0.f;
  const float* Xb = X + (size_t)b * n * Fd + f;
  for (int i = 0; i < n; ++i) {
    float v = Xb[(size_t)i * Fd];
    mx = fmaxf(mx, v); sm += v;
  }
  float a = fmaxf(mx, 0.f);
  float m2 = fmaxf(sm / (float)n, 0.f);
  if (init) { g[b * 384 + f] = a; g[b * 384 + 128 + f] = m2; }
  else      { g[b * 384 + f] += a; g[b * 384 + 128 + f] += m2; }
}

// ---- A1 = softmax_row(leakyrelu(ar_i+ac_j) + bit(pi,pj)), K1=512 wide ----
__global__ __launch_bounds__(512) void k_buildA_bit(const unsigned* __restrict__ adj,
    const int* __restrict__ perm, const float* __restrict__ ar, const float* __restrict__ ac,
    float* __restrict__ A) {
  int bi = blockIdx.x;
  int b = bi >> 9, i = bi & (K1 - 1), j = threadIdx.x;
  __shared__ float redA[8], redB[8];
  int pi = perm[(b << 9) + i];
  int pj = perm[(b << 9) + j];
  float x = ar[(b << 9) + i] + ac[(b << 9) + j];
  x = x > 0.f ? x : 0.2f * x;
  unsigned word = adj[(size_t)((b << 10) + pi) * 32 + (pj >> 5)];
  x += (float)((word >> (pj & 31)) & 1u);
  int lane = j & 63, w = j >> 6;
  float m = wred_max(x);
  if (lane == 0) redA[w] = m;
  __syncthreads();
  m = redA[0];
#pragma unroll
  for (int q = 1; q < 8; ++q) m = fmaxf(m, redA[q]);
  float e = expf(x - m);
  float s = wred_sum(e);
  if (lane == 0) redB[w] = s;
  __syncthreads();
  s = redB[0];
#pragma unroll
  for (int q = 1; q < 8; ++q) s += redB[q];
  A[((size_t)(b << 9) + i) * K1 + j] = e / s;
}

// ---- A2 = softmax_row(leakyrelu(ar_i+ac_j) + A1[pi,pj]), K2=256 wide ----
__global__ __launch_bounds__(256) void k_buildA_dense(const float* __restrict__ Aprev,
    const int* __restrict__ perm, const float* __restrict__ ar, const float* __restrict__ ac,
    float* __restrict__ A) {
  int bi = blockIdx.x;
  int b = bi >> 8, i = bi & (K2 - 1), j = threadIdx.x;
  __shared__ float redA[4], redB[4];
  int pi = perm[(b << 8) + i];
  int pj = perm[(b << 8) + j];
  float x = ar[(b << 8) + i] + ac[(b << 8) + j];
  x = x > 0.f ? x : 0.2f * x;
  x += Aprev[((size_t)(b << 9) + pi) * K1 + pj];
  int lane = j & 63, w = j >> 6;
  float m = wred_max(x);
  if (lane == 0) redA[w] = m;
  __syncthreads();
  m = redA[0];
#pragma unroll
  for (int q = 1; q < 4; ++q) m = fmaxf(m, redA[q]);
  float e = expf(x - m);
  float s = wred_sum(e);
  if (lane == 0) redB[w] = s;
  __syncthreads();
  s = redB[0];
#pragma unroll
  for (int q = 1; q < 4; ++q) s += redB[q];
  A[((size_t)(b << 8) + i) * K2 + j] = e / s;
}

// ---- per-row stats of dense A: rowsum, diag -> dis_conv, selfadd, dis_nis, diag ----
__global__ void k_prep(const float* __restrict__ A, int n, float* __restrict__ disc,
                       float* __restrict__ sa, float* __restrict__ disn,
                       float* __restrict__ diagO) {
  int row = blockIdx.x, j = threadIdx.x;
  int i = row & (n - 1);
  __shared__ float red[8];
  __shared__ float dsh;
  float a = A[(size_t)row * n + j];
  if (j == i) dsh = a;
  float v = wred_sum(a);
  int lane = j & 63, w = j >> 6, nw = blockDim.x >> 6;
  if (lane == 0) red[w] = v;
  __syncthreads();
  float s = 0.f;
  for (int q = 0; q < nw; ++q) s += red[q];
  float d = dsh;
  if (j == 0) {
    float sav = (d == 0.f) ? 1.f : 0.f;
    float deg = s + sav;
    disc[row] = deg > 0.f ? rsqrtf(deg) : 0.f;
    sa[row] = sav;
    float deg0 = s - d;
    disn[row] = deg0 > 0.f ? rsqrtf(deg0) : 0.f;
    diagO[row] = d;
  }
}

__global__ void k_scale(const float* __restrict__ X, const float* __restrict__ dis,
                        float* __restrict__ Y, int total) {
  int idx = blockIdx.x * 256 + threadIdx.x;
  if (idx < total) Y[idx] = dis[idx >> 7] * X[idx];
}

// ---- dense T[b] = A[b](n x n) @ Y[b](n x 128); tile 32 rows, block 256 ----
__global__ __launch_bounds__(256) void k_mm(const float* __restrict__ A,
                                            const float* __restrict__ Y,
                                            float* __restrict__ T, int n) {
  int tiles = n >> 5;
  int b = blockIdx.x / tiles, rt = blockIdx.x - b * tiles;
  __shared__ float As[32][36];
  __shared__ float Ys[32][132];
  int t = threadIdx.x;
  const float* Ab = A + (size_t)b * n * n + (size_t)(rt * 32) * n;
  const float* Yb = Y + (size_t)b * n * Fd;
  int r0 = (t >> 5) * 4, c0 = (t & 31) * 4;
  float acc[4][4] = {};
  for (int kb = 0; kb < n; kb += 32) {
    __syncthreads();
    {
      int r = t >> 3, c4 = t & 7;
      float4 v = *(const float4*)&Ab[(size_t)r * n + kb + c4 * 4];
      *(float4*)&As[r][c4 * 4] = v;
    }
#pragma unroll
    for (int ii = 0; ii < 4; ++ii) {
      int f4 = t + 256 * ii;
      int r = f4 >> 5, c4 = f4 & 31;
      float4 v = *(const float4*)&Yb[(size_t)(kb + r) * Fd + c4 * 4];
      *(float4*)&Ys[r][c4 * 4] = v;
    }
    __syncthreads();
#pragma unroll
    for (int k = 0; k < 32; ++k) {
      float4 wv = *(const float4*)&Ys[k][c0];
#pragma unroll
      for (int i = 0; i < 4; ++i) {
        float av = As[r0 + i][k];
        acc[i][0] += av * wv.x; acc[i][1] += av * wv.y;
        acc[i][2] += av * wv.z; acc[i][3] += av * wv.w;
      }
    }
  }
  int orow = rt * 32 + r0;
#pragma unroll
  for (int i = 0; i < 4; ++i) {
    float4 o = make_float4(acc[i][0], acc[i][1], acc[i][2], acc[i][3]);
    *(float4*)&T[((size_t)b * n + orow + i) * Fd + c0] = o;
  }
}

__global__ __launch_bounds__(128) void k_conv_epi(const float* __restrict__ T,
    const float* __restrict__ Y, const float* __restrict__ disc, const float* __restrict__ sa,
    const float* __restrict__ bias, float* __restrict__ h) {
  int row = blockIdx.x, f = threadIdx.x;
  size_t o = (size_t)row * Fd + f;
  float v = T[o] + sa[row] * Y[o];
  h[o] = fmaxf(disc[row] * v + bias[f], 0.f);
}

__global__ __launch_bounds__(128) void k_nis_epi(const float* __restrict__ h,
    const float* __restrict__ T, const float* __restrict__ Yn, const float* __restrict__ disn,
    const float* __restrict__ diag, float* __restrict__ score) {
  int row = blockIdx.x, f = threadIdx.x;
  __shared__ float red[2];
  size_t o = (size_t)row * Fd + f;
  float val = h[o] - disn[row] * (T[o] - diag[row] * Yn[o]);
  float p = wred_sum(fabsf(val));
  if ((f & 63) == 0) red[f >> 6] = p;
  __syncthreads();
  if (f == 0) score[row] = red[0] + red[1];
}

__global__ __launch_bounds__(128) void k_xskew(const float* __restrict__ skew,
    const float* __restrict__ Wsk, const float* __restrict__ bsk, float* __restrict__ g) {
  int b = blockIdx.x, f = threadIdx.x;
  float acc = bsk[f];
  for (int s = 0; s < 64; ++s) acc += skew[b * 64 + s] * Wsk[s * Fd + f];
  g[b * 384 + 256 + f] = fmaxf(acc, 0.f);
}

__global__ __launch_bounds__(128) void k_mlp1(const float* __restrict__ g,
    const float* __restrict__ Wl, const float* __restrict__ bl, float* __restrict__ o) {
  int b = blockIdx.x, f = threadIdx.x;
  float acc = bl[f];
  for (int s = 0; s < 384; ++s) acc += g[b * 384 + s] * Wl[s * 128 + f];
  o[b * 128 + f] = fmaxf(acc, 0.f);
}
__global__ __launch_bounds__(64) void k_mlp2(const float* __restrict__ x,
    const float* __restrict__ Wl, const float* __restrict__ bl, float* __restrict__ o) {
  int b = blockIdx.x, f = threadIdx.x;
  float acc = bl[f];
  for (int s = 0; s < 128; ++s) acc += x[b * 128 + s] * Wl[s * 64 + f];
  o[b * 64 + f] = fmaxf(acc, 0.f);
}
__global__ __launch_bounds__(64) void k_mlp3(const float* __restrict__ x,
    const float* __restrict__ Wl, const float* __restrict__ bl, float* __restrict__ out) {
  int b = blockIdx.x, f = threadIdx.x;
  __shared__ float lg[10];
  if (f < 10) {
    float acc = bl[f];
    for (int s = 0; s < 64; ++s) acc += x[b * 64 + s] * Wl[s * 10 + f];
    lg[f] = acc;
  }
  __syncthreads();
  if (f == 0) {
    float m = lg[0];
    for (int c = 1; c < 10; ++c) m = fmaxf(m, lg[c]);
    float s = 0.f;
    for (int c = 0; c < 10; ++c) s += expf(lg[c] - m);
    float l = logf(s);
    for (int c = 0; c < 10; ++c) out[b * 10 + c] = lg[c] - m - l;
  }
}

extern "C" void kernel_launch(void* const* d_in, const int* in_sizes, int n_in,
                              void* d_out, int out_size, void* d_ws, size_t ws_size,
                              hipStream_t stream) {
  const float* x    = (const float*)d_in[0];
  const int*   src  = (const int*)d_in[1];
  const int*   dst  = (const int*)d_in[2];
  const float* skew = (const float*)d_in[3];
  const float* W1   = (const float*)d_in[4];
  const float* b1   = (const float*)d_in[5];
  const float* W2   = (const float*)d_in[6];
  const float* b2   = (const float*)d_in[7];
  const float* W3   = (const float*)d_in[8];
  const float* b3   = (const float*)d_in[9];
  const float* att1 = (const float*)d_in[10];
  const float* att2 = (const float*)d_in[11];
  const float* Wsk  = (const float*)d_in[12];
  const float* bsk  = (const float*)d_in[13];
  const float* Wl1  = (const float*)d_in[14];
  const float* bl1  = (const float*)d_in[15];
  const float* Wl2  = (const float*)d_in[16];
  const float* bl2  = (const float*)d_in[17];
  const float* Wl3  = (const float*)d_in[18];
  const float* bl3  = (const float*)d_in[19];
  float* out = (float*)d_out;

  char* base = (char*)d_ws;
  size_t off = 0;
  auto alloc = [&](size_t bytes) -> void* {
    void* p = base + off;
    off += (bytes + 255) & ~(size_t)255;
    return p;
  };

  unsigned* adj = (unsigned*)alloc((size_t)Bb * N0 * 32 * 4);        // 8 MB
  float* dis0 = (float*)alloc((size_t)Bb * N0 * 4);
  float* dis1 = (float*)alloc((size_t)Bb * N0 * 4);
  float* bigA = (float*)alloc((size_t)64 * 1024 * 1024);             // 64 MB multi-use
  float* XW  = bigA;                                                  // [B,1024,128]
  float* h1  = bigA + (size_t)Bb * N0 * Fd;                           // [B,1024,128]
  float* A1  = bigA;                                                  // [B,512,512] (after h1 dead)
  float* XW3 = bigA;                                                  // [B,256,128] (after A1 dead)
  float* h3  = bigA + (size_t)Bb * K2 * Fd;                           // [B,256,128]
  float* score = (float*)alloc((size_t)Bb * N0 * 4);
  int*   perm1 = (int*)alloc((size_t)Bb * K1 * 4);
  float* Xp1 = (float*)alloc((size_t)Bb * K1 * Fd * 4);               // later reused as A2
  float* A2  = Xp1;                                                   // [B,256,256] = same bytes
  float* ar1 = (float*)alloc((size_t)Bb * K1 * 4);
  float* ac1 = (float*)alloc((size_t)Bb * K1 * 4);
  float* disc2 = (float*)alloc((size_t)Bb * K1 * 4);
  float* sa2   = (float*)alloc((size_t)Bb * K1 * 4);
  float* disn2 = (float*)alloc((size_t)Bb * K1 * 4);
  float* diag2 = (float*)alloc((size_t)Bb * K1 * 4);
  float* XW2 = (float*)alloc((size_t)Bb * K1 * Fd * 4);               // Y2 in-place, later Yn
  float* h2  = (float*)alloc((size_t)Bb * K1 * Fd * 4);
  float* T   = (float*)alloc((size_t)Bb * K1 * Fd * 4);
  int*   perm2 = (int*)alloc((size_t)Bb * K2 * 4);
  float* Xp2 = (float*)alloc((size_t)Bb * K2 * Fd * 4);
  float* ar2 = (float*)alloc((size_t)Bb * K2 * 4);
  float* ac2 = (float*)alloc((size_t)Bb * K2 * 4);
  float* disc3 = (float*)alloc((size_t)Bb * K2 * 4);
  float* sa3   = (float*)alloc((size_t)Bb * K2 * 4);
  float* disn3 = (float*)alloc((size_t)Bb * K2 * 4);
  float* diag3 = (float*)alloc((size_t)Bb * K2 * 4);
  float* g  = (float*)alloc((size_t)Bb * 384 * 4);
  float* t1 = (float*)alloc((size_t)Bb * 128 * 4);
  float* t2 = (float*)alloc((size_t)Bb * 64 * 4);
  (void)ws_size; (void)in_sizes; (void)n_in; (void)out_size;

  // stage 1: binary graph
  hipMemsetAsync(adj, 0, (size_t)Bb * N0 * 32 * 4, stream);
  k_scatter<<<(Bb * NE + 255) / 256, 256, 0, stream>>>(src, dst, adj);
  k_degree<<<(Bb * N0 + 255) / 256, 256, 0, stream>>>(adj, dis0, dis1);
  k_gemm128<<<Bb * N0 / 64, 256, 0, stream>>>(x, W1, XW);
  k_conv1<<<Bb * N0, 128, 0, stream>>>(adj, XW, dis1, b1, h1);
  k_nis1<<<Bb * N0, 128, 0, stream>>>(adj, h1, dis0, score);
  k_topk<<<Bb, N0, 0, stream>>>(score, perm1, N0, K1);
  k_gather<<<Bb * K1, 128, 0, stream>>>(h1, perm1, att1, Xp1, ar1, ac1, N0, K1);
  k_readout<<<Bb, 128, 0, stream>>>(Xp1, K1, g, 1);
  k_buildA_bit<<<Bb * K1, K1, 0, stream>>>(adj, perm1, ar1, ac1, A1);  // overwrites XW/h1

  // stage 2: dense A1
  k_prep<<<Bb * K1, K1, 0, stream>>>(A1, K1, disc2, sa2, disn2, diag2);
  k_gemm128<<<Bb * K1 / 64, 256, 0, stream>>>(Xp1, W2, XW2);
  k_scale<<<(Bb * K1 * Fd + 255) / 256, 256, 0, stream>>>(XW2, disc2, XW2, Bb * K1 * Fd);
  k_mm<<<Bb * (K1 / 32), 256, 0, stream>>>(A1, XW2, T, K1);
  k_conv_epi<<<Bb * K1, 128, 0, stream>>>(T, XW2, disc2, sa2, b2, h2);
  k_scale<<<(Bb * K1 * Fd + 255) / 256, 256, 0, stream>>>(h2, disn2, XW2, Bb * K1 * Fd); // Yn
  k_mm<<<Bb * (K1 / 32), 256, 0, stream>>>(A1, XW2, T, K1);
  k_nis_epi<<<Bb * K1, 128, 0, stream>>>(h2, T, XW2, disn2, diag2, score);
  k_topk<<<Bb, K1, 0, stream>>>(score, perm2, K1, K2);
  k_gather<<<Bb * K2, 128, 0, stream>>>(h2, perm2, att2, Xp2, ar2, ac2, K1, K2);
  k_readout<<<Bb, 128, 0, stream>>>(Xp2, K2, g, 0);
  k_buildA_dense<<<Bb * K2, K2, 0, stream>>>(A1, perm2, ar2, ac2, A2);  // overwrites Xp1

  // stage 3: dense A2
  k_prep<<<Bb * K2, K2, 0, stream>>>(A2, K2, disc3, sa3, disn3, diag3);
  k_gemm128<<<Bb * K2 / 64, 256, 0, stream>>>(Xp2, W3, XW3);           // overwrites A1 region
  k_scale<<<(Bb * K2 * Fd + 255) / 256, 256, 0, stream>>>(XW3, disc3, XW3, Bb * K2 * Fd);
  k_mm<<<Bb * (K2 / 32), 256, 0, stream>>>(A2, XW3, T, K2);
  k_conv_epi<<<Bb * K2, 128, 0, stream>>>(T, XW3, disc3, sa3, b3, h3);
  k_readout<<<Bb, 128, 0, stream>>>(h3, K2, g, 0);

  // head
  k_xskew<<<Bb, 128, 0, stream>>>(skew, Wsk, bsk, g);
  k_mlp1<<<Bb, 128, 0, stream>>>(g, Wl1, bl1, t1);
  k_mlp2<<<Bb, 64, 0, stream>>>(t1, Wl2, bl2, t2);
  k_mlp3<<<Bb, 64, 0, stream>>>(t2, Wl3, bl3, out);
}

// Round 2
// 956.078 us; speedup vs baseline: 1.1880x; 1.1880x over previous
//
#include <hip/hip_runtime.h>
#include <math.h>

#define Bb 64
#define N0 1024
#define NE 16384
#define Fd 128
#define K1 512
#define K2 256

__device__ __forceinline__ float wred_sum(float v) {
#pragma unroll
  for (int o = 32; o > 0; o >>= 1) v += __shfl_down(v, o, 64);
  return v;
}
__device__ __forceinline__ float wred_max(float v) {
#pragma unroll
  for (int o = 32; o > 0; o >>= 1) v = fmaxf(v, __shfl_down(v, o, 64));
  return v;
}

// ---- build binary adjacency as bitmask: adj[b][i] = 32 words of row bits ----
__global__ void k_scatter(const int* __restrict__ src, const int* __restrict__ dst,
                          unsigned* __restrict__ adj) {
  int idx = blockIdx.x * 256 + threadIdx.x;
  if (idx >= Bb * NE) return;
  int b = idx >> 14, e = idx & (NE - 1);
  int u = src[b * NE + e], v = dst[b * NE + e];
  if (u == v) return;
  atomicOr(&adj[((b << 10) + u) * 32 + (v >> 5)], 1u << (v & 31));
  atomicOr(&adj[((b << 10) + v) * 32 + (u >> 5)], 1u << (u & 31));
}

__global__ void k_degree(const unsigned* __restrict__ adj, float* __restrict__ dis0,
                         float* __restrict__ dis1) {
  int row = blockIdx.x * 256 + threadIdx.x;
  if (row >= Bb * N0) return;
  int d = 0;
  const unsigned* w = adj + (size_t)row * 32;
#pragma unroll
  for (int i = 0; i < 32; ++i) d += __popc(w[i]);
  dis0[row] = d > 0 ? rsqrtf((float)d) : 0.f;
  dis1[row] = rsqrtf((float)(d + 1));
}

// ---- C[M,128] = X[M,128] @ W[128,128], M % 64 == 0, grid = M/64, block 256 ----
__global__ __launch_bounds__(256) void k_gemm128(const float* __restrict__ X,
                                                 const float* __restrict__ W,
                                                 float* __restrict__ C) {
  __shared__ float Xs[64][132];
  __shared__ float Ws[32][132];
  int t = threadIdx.x;
  size_t row0 = (size_t)blockIdx.x * 64;
  const float4* Xg = (const float4*)(X + row0 * Fd);
#pragma unroll
  for (int i = 0; i < 8; ++i) {
    int f4 = t + 256 * i;
    float4 v = Xg[f4];
    *(float4*)&Xs[f4 >> 5][(f4 & 31) * 4] = v;
  }
  int r0 = (t >> 5) * 8, c0 = (t & 31) * 4;
  float acc[8][4] = {};
  for (int kb = 0; kb < 128; kb += 32) {
    __syncthreads();
#pragma unroll
    for (int i = 0; i < 4; ++i) {
      int f4 = t + 256 * i;
      float4 v = ((const float4*)(W + (size_t)kb * Fd))[f4];
      *(float4*)&Ws[f4 >> 5][(f4 & 31) * 4] = v;
    }
    __syncthreads();
#pragma unroll
    for (int k = 0; k < 32; ++k) {
      float4 wv = *(const float4*)&Ws[k][c0];
#pragma unroll
      for (int i = 0; i < 8; ++i) {
        float xv = Xs[r0 + i][kb + k];
        acc[i][0] += xv * wv.x; acc[i][1] += xv * wv.y;
        acc[i][2] += xv * wv.z; acc[i][3] += xv * wv.w;
      }
    }
  }
#pragma unroll
  for (int i = 0; i < 8; ++i) {
    float4 o = make_float4(acc[i][0], acc[i][1], acc[i][2], acc[i][3]);
    *(float4*)&C[(row0 + r0 + i) * Fd + c0] = o;
  }
}

// ---- cooperative bitmask -> (idx, weight) list decode; returns degree ----
__device__ __forceinline__ int decode_adj(const unsigned* __restrict__ adjrow,
                                          const float* __restrict__ wsrc,
                                          int* idxs, float* wts, int t) {
  __shared__ unsigned wbuf[32];
  __shared__ int boff[32];
  __shared__ int degsh;
  if (t < 32) wbuf[t] = adjrow[t];
  __syncthreads();
  if (t == 0) {
    int s = 0;
#pragma unroll
    for (int w = 0; w < 32; ++w) { boff[w] = s; s += __popc(wbuf[w]); }
    degsh = s;
  }
  __syncthreads();
  if (t < 32) {
    unsigned m = wbuf[t];
    int o = boff[t];
    int bas = t << 5;
    while (m) {
      int j = bas + __ffs(m) - 1;
      m &= m - 1;
      idxs[o] = j; wts[o] = wsrc[j]; ++o;
    }
  } else if (t == 32) {
    int d = degsh, dp = (d + 7) & ~7;
    for (int p = d; p < dp; ++p) { idxs[p] = 0; wts[p] = 0.f; }
  }
  __syncthreads();
  return degsh;
}

// ---- gather-accumulate with 8 loads in flight ----
__device__ __forceinline__ float gather8(const float* __restrict__ srcb,
                                         const int* idxs, const float* wts,
                                         int deg, int f) {
  float acc = 0.f;
  int dp = (deg + 7) & ~7;
  for (int i = 0; i < dp; i += 8) {
    int jj[8]; float ww[8], vv[8];
#pragma unroll
    for (int u = 0; u < 8; ++u) { jj[u] = idxs[i + u]; ww[u] = wts[i + u]; }
#pragma unroll
    for (int u = 0; u < 8; ++u) vv[u] = srcb[(size_t)jj[u] * Fd + f];
#pragma unroll
    for (int u = 0; u < 8; ++u) acc += ww[u] * vv[u];
  }
  return acc;
}

// ---- conv1: h1 = relu(dis1_i*(sum_{j in N(i)} dis1_j XW_j + dis1_i XW_i) + b1) ----
__global__ __launch_bounds__(128) void k_conv1(const unsigned* __restrict__ adj,
    const float* __restrict__ XW, const float* __restrict__ dis1,
    const float* __restrict__ b1, float* __restrict__ h1) {
  __shared__ int idxs[1032];
  __shared__ float wts[1032];
  int row = blockIdx.x, f = threadIdx.x;
  int base = row & ~(N0 - 1);
  int deg = decode_adj(adj + (size_t)row * 32, dis1 + base, idxs, wts, f);
  float di = dis1[row];
  float acc = gather8(XW + (size_t)base * Fd, idxs, wts, deg, f);
  acc += di * XW[(size_t)row * Fd + f];
  h1[(size_t)row * Fd + f] = fmaxf(di * acc + b1[f], 0.f);
}

// ---- NIS on binary A: score_i = sum_f |h_i - dis0_i * sum_j dis0_j h_j| ----
__global__ __launch_bounds__(128) void k_nis1(const unsigned* __restrict__ adj,
    const float* __restrict__ h, const float* __restrict__ dis0, float* __restrict__ score) {
  __shared__ int idxs[1032];
  __shared__ float wts[1032];
  __shared__ float red[2];
  int row = blockIdx.x, f = threadIdx.x;
  int base = row & ~(N0 - 1);
  int deg = decode_adj(adj + (size_t)row * 32, dis0 + base, idxs, wts, f);
  float acc = gather8(h + (size_t)base * Fd, idxs, wts, deg, f);
  float val = h[(size_t)row * Fd + f] - dis0[row] * acc;
  float p = wred_sum(fabsf(val));
  if ((f & 63) == 0) red[f >> 6] = p;
  __syncthreads();
  if (f == 0) score[row] = red[0] + red[1];
}

// ---- exact top-k per graph: bitonic sort of (score,idx) packed u64 keys ----
__global__ __launch_bounds__(1024) void k_topk(const float* __restrict__ score,
                                               int* __restrict__ perm, int n, int k) {
  __shared__ unsigned long long keys[1024];
  int b = blockIdx.x, t = threadIdx.x;
  float s = score[b * n + t];
  unsigned ub = __float_as_uint(s);
  unsigned su = (ub & 0x80000000u) ? ~ub : (ub | 0x80000000u);  // monotone map
  keys[t] = ((unsigned long long)(~su) << 32) | (unsigned)t;    // asc sort = desc score, asc idx
  __syncthreads();
  for (int kk = 2; kk <= n; kk <<= 1) {
    for (int j = kk >> 1; j > 0; j >>= 1) {
      int ixj = t ^ j;
      if (ixj > t) {
        unsigned long long a = keys[t], c = keys[ixj];
        bool up = ((t & kk) == 0);
        if ((a > c) == up) { keys[t] = c; keys[ixj] = a; }
      }
      __syncthreads();
    }
  }
  if (t < k) perm[b * k + t] = (int)(keys[t] & 0xffffffffu);
}

// ---- gather pooled rows + attention dots ----
__global__ __launch_bounds__(128) void k_gather(const float* __restrict__ h,
    const int* __restrict__ perm, const float* __restrict__ att, float* __restrict__ Xp,
    float* __restrict__ ar, float* __restrict__ ac, int n, int k) {
  int idx = blockIdx.x, f = threadIdx.x;
  int b = idx / k;
  __shared__ float red[4];
  int p = perm[idx];
  float v = h[((size_t)b * n + p) * Fd + f];
  Xp[(size_t)idx * Fd + f] = v;
  float r1 = wred_sum(v * att[f]);
  float r2 = wred_sum(v * att[Fd + f]);
  if ((f & 63) == 0) { red[f >> 6] = r1; red[2 + (f >> 6)] = r2; }
  __syncthreads();
  if (f == 0) { ar[idx] = red[0] + red[1]; ac[idx] = red[2] + red[3]; }
}

// ---- readout: g[b][0:128] (+)= relu(max), g[b][128:256] (+)= relu(mean) ----
__global__ __launch_bounds__(128) void k_readout(const float* __restrict__ X, int n,
                                                 float* __restrict__ g, int init) {
  int b = blockIdx.x, f = threadIdx.x;
  float mx = -3.0e38f, sm = 0.f;
  const float* Xb = X + (size_t)b * n * Fd + f;
  for (int i = 0; i < n; ++i) {
    float v = Xb[(size_t)i * Fd];
    mx = fmaxf(mx, v); sm += v;
  }
  float a = fmaxf(mx, 0.f);
  float m2 = fmaxf(sm / (float)n, 0.f);
  if (init) { g[b * 384 + f] = a; g[b * 384 + 128 + f] = m2; }
  else      { g[b * 384 + f] += a; g[b * 384 + 128 + f] += m2; }
}

// ---- A1 = softmax_row(leakyrelu(ar_i+ac_j) + bit(pi,pj)), K1=512 wide ----
__global__ __launch_bounds__(512) void k_buildA_bit(const unsigned* __restrict__ adj,
    const int* __restrict__ perm, const float* __restrict__ ar, const float* __restrict__ ac,
    float* __restrict__ A) {
  int bi = blockIdx.x;
  int b = bi >> 9, i = bi & (K1 - 1), j = threadIdx.x;
  __shared__ float redA[8], redB[8];
  int pi = perm[(b << 9) + i];
  int pj = perm[(b << 9) + j];
  float x = ar[(b << 9) + i] + ac[(b << 9) + j];
  x = x > 0.f ? x : 0.2f * x;
  unsigned word = adj[(size_t)((b << 10) + pi) * 32 + (pj >> 5)];
  x += (float)((word >> (pj & 31)) & 1u);
  int lane = j & 63, w = j >> 6;
  float m = wred_max(x);
  if (lane == 0) redA[w] = m;
  __syncthreads();
  m = redA[0];
#pragma unroll
  for (int q = 1; q < 8; ++q) m = fmaxf(m, redA[q]);
  float e = expf(x - m);
  float s = wred_sum(e);
  if (lane == 0) redB[w] = s;
  __syncthreads();
  s = redB[0];
#pragma unroll
  for (int q = 1; q < 8; ++q) s += redB[q];
  A[((size_t)(b << 9) + i) * K1 + j] = e / s;
}

// ---- A2 = softmax_row(leakyrelu(ar_i+ac_j) + A1[pi,pj]), K2=256 wide ----
__global__ __launch_bounds__(256) void k_buildA_dense(const float* __restrict__ Aprev,
    const int* __restrict__ perm, const float* __restrict__ ar, const float* __restrict__ ac,
    float* __restrict__ A) {
  int bi = blockIdx.x;
  int b = bi >> 8, i = bi & (K2 - 1), j = threadIdx.x;
  __shared__ float redA[4], redB[4];
  int pi = perm[(b << 8) + i];
  int pj = perm[(b << 8) + j];
  float x = ar[(b << 8) + i] + ac[(b << 8) + j];
  x = x > 0.f ? x : 0.2f * x;
  x += Aprev[((size_t)(b << 9) + pi) * K1 + pj];
  int lane = j & 63, w = j >> 6;
  float m = wred_max(x);
  if (lane == 0) redA[w] = m;
  __syncthreads();
  m = redA[0];
#pragma unroll
  for (int q = 1; q < 4; ++q) m = fmaxf(m, redA[q]);
  float e = expf(x - m);
  float s = wred_sum(e);
  if (lane == 0) redB[w] = s;
  __syncthreads();
  s = redB[0];
#pragma unroll
  for (int q = 1; q < 4; ++q) s += redB[q];
  A[((size_t)(b << 8) + i) * K2 + j] = e / s;
}

// ---- per-row stats of dense A: rowsum, diag -> dis_conv, selfadd, dis_nis, diag ----
__global__ void k_prep(const float* __restrict__ A, int n, float* __restrict__ disc,
                       float* __restrict__ sa, float* __restrict__ disn,
                       float* __restrict__ diagO) {
  int row = blockIdx.x, j = threadIdx.x;
  int i = row & (n - 1);
  __shared__ float red[8];
  __shared__ float dsh;
  float a = A[(size_t)row * n + j];
  if (j == i) dsh = a;
  float v = wred_sum(a);
  int lane = j & 63, w = j >> 6, nw = blockDim.x >> 6;
  if (lane == 0) red[w] = v;
  __syncthreads();
  float s = 0.f;
  for (int q = 0; q < nw; ++q) s += red[q];
  float d = dsh;
  if (j == 0) {
    float sav = (d == 0.f) ? 1.f : 0.f;
    float deg = s + sav;
    disc[row] = deg > 0.f ? rsqrtf(deg) : 0.f;
    sa[row] = sav;
    float deg0 = s - d;
    disn[row] = deg0 > 0.f ? rsqrtf(deg0) : 0.f;
    diagO[row] = d;
  }
}

__global__ void k_scale(const float* __restrict__ X, const float* __restrict__ dis,
                        float* __restrict__ Y, int total) {
  int idx = blockIdx.x * 256 + threadIdx.x;
  if (idx < total) Y[idx] = dis[idx >> 7] * X[idx];
}

// ---- dense T[b] = A[b](n x n) @ Y[b](n x 128); tile 32 rows, block 256 ----
__global__ __launch_bounds__(256) void k_mm(const float* __restrict__ A,
                                            const float* __restrict__ Y,
                                            float* __restrict__ T, int n) {
  int tiles = n >> 5;
  int b = blockIdx.x / tiles, rt = blockIdx.x - b * tiles;
  __shared__ float As[32][36];
  __shared__ float Ys[32][132];
  int t = threadIdx.x;
  const float* Ab = A + (size_t)b * n * n + (size_t)(rt * 32) * n;
  const float* Yb = Y + (size_t)b * n * Fd;
  int r0 = (t >> 5) * 4, c0 = (t & 31) * 4;
  float acc[4][4] = {};
  for (int kb = 0; kb < n; kb += 32) {
    __syncthreads();
    {
      int r = t >> 3, c4 = t & 7;
      float4 v = *(const float4*)&Ab[(size_t)r * n + kb + c4 * 4];
      *(float4*)&As[r][c4 * 4] = v;
    }
#pragma unroll
    for (int ii = 0; ii < 4; ++ii) {
      int f4 = t + 256 * ii;
      int r = f4 >> 5, c4 = f4 & 31;
      float4 v = *(const float4*)&Yb[(size_t)(kb + r) * Fd + c4 * 4];
      *(float4*)&Ys[r][c4 * 4] = v;
    }
    __syncthreads();
#pragma unroll
    for (int k = 0; k < 32; ++k) {
      float4 wv = *(const float4*)&Ys[k][c0];
#pragma unroll
      for (int i = 0; i < 4; ++i) {
        float av = As[r0 + i][k];
        acc[i][0] += av * wv.x; acc[i][1] += av * wv.y;
        acc[i][2] += av * wv.z; acc[i][3] += av * wv.w;
      }
    }
  }
  int orow = rt * 32 + r0;
#pragma unroll
  for (int i = 0; i < 4; ++i) {
    float4 o = make_float4(acc[i][0], acc[i][1], acc[i][2], acc[i][3]);
    *(float4*)&T[((size_t)b * n + orow + i) * Fd + c0] = o;
  }
}

__global__ __launch_bounds__(128) void k_conv_epi(const float* __restrict__ T,
    const float* __restrict__ Y, const float* __restrict__ disc, const float* __restrict__ sa,
    const float* __restrict__ bias, float* __restrict__ h) {
  int row = blockIdx.x, f = threadIdx.x;
  size_t o = (size_t)row * Fd + f;
  float v = T[o] + sa[row] * Y[o];
  h[o] = fmaxf(disc[row] * v + bias[f], 0.f);
}

__global__ __launch_bounds__(128) void k_nis_epi(const float* __restrict__ h,
    const float* __restrict__ T, const float* __restrict__ Yn, const float* __restrict__ disn,
    const float* __restrict__ diag, float* __restrict__ score) {
  int row = blockIdx.x, f = threadIdx.x;
  __shared__ float red[2];
  size_t o = (size_t)row * Fd + f;
  float val = h[o] - disn[row] * (T[o] - diag[row] * Yn[o]);
  float p = wred_sum(fabsf(val));
  if ((f & 63) == 0) red[f >> 6] = p;
  __syncthreads();
  if (f == 0) score[row] = red[0] + red[1];
}

__global__ __launch_bounds__(128) void k_xskew(const float* __restrict__ skew,
    const float* __restrict__ Wsk, const float* __restrict__ bsk, float* __restrict__ g) {
  int b = blockIdx.x, f = threadIdx.x;
  float acc = bsk[f];
  for (int s = 0; s < 64; ++s) acc += skew[b * 64 + s] * Wsk[s * Fd + f];
  g[b * 384 + 256 + f] = fmaxf(acc, 0.f);
}

__global__ __launch_bounds__(128) void k_mlp1(const float* __restrict__ g,
    const float* __restrict__ Wl, const float* __restrict__ bl, float* __restrict__ o) {
  int b = blockIdx.x, f = threadIdx.x;
  float acc = bl[f];
  for (int s = 0; s < 384; ++s) acc += g[b * 384 + s] * Wl[s * 128 + f];
  o[b * 128 + f] = fmaxf(acc, 0.f);
}
__global__ __launch_bounds__(64) void k_mlp2(const float* __restrict__ x,
    const float* __restrict__ Wl, const float* __restrict__ bl, float* __restrict__ o) {
  int b = blockIdx.x, f = threadIdx.x;
  float acc = bl[f];
  for (int s = 0; s < 128; ++s) acc += x[b * 128 + s] * Wl[s * 64 + f];
  o[b * 64 + f] = fmaxf(acc, 0.f);
}
__global__ __launch_bounds__(64) void k_mlp3(const float* __restrict__ x,
    const float* __restrict__ Wl, const float* __restrict__ bl, float* __restrict__ out) {
  int b = blockIdx.x, f = threadIdx.x;
  __shared__ float lg[10];
  if (f < 10) {
    float acc = bl[f];
    for (int s = 0; s < 64; ++s) acc += x[b * 64 + s] * Wl[s * 10 + f];
    lg[f] = acc;
  }
  __syncthreads();
  if (f == 0) {
    float m = lg[0];
    for (int c = 1; c < 10; ++c) m = fmaxf(m, lg[c]);
    float s = 0.f;
    for (int c = 0; c < 10; ++c) s += expf(lg[c] - m);
    float l = logf(s);
    for (int c = 0; c < 10; ++c) out[b * 10 + c] = lg[c] - m - l;
  }
}

extern "C" void kernel_launch(void* const* d_in, const int* in_sizes, int n_in,
                              void* d_out, int out_size, void* d_ws, size_t ws_size,
                              hipStream_t stream) {
  const float* x    = (const float*)d_in[0];
  const int*   src  = (const int*)d_in[1];
  const int*   dst  = (const int*)d_in[2];
  const float* skew = (const float*)d_in[3];
  const float* W1   = (const float*)d_in[4];
  const float* b1   = (const float*)d_in[5];
  const float* W2   = (const float*)d_in[6];
  const float* b2   = (const float*)d_in[7];
  const float* W3   = (const float*)d_in[8];
  const float* b3   = (const float*)d_in[9];
  const float* att1 = (const float*)d_in[10];
  const float* att2 = (const float*)d_in[11];
  const float* Wsk  = (const float*)d_in[12];
  const float* bsk  = (const float*)d_in[13];
  const float* Wl1  = (const float*)d_in[14];
  const float* bl1  = (const float*)d_in[15];
  const float* Wl2  = (const float*)d_in[16];
  const float* bl2  = (const float*)d_in[17];
  const float* Wl3  = (const float*)d_in[18];
  const float* bl3  = (const float*)d_in[19];
  float* out = (float*)d_out;

  char* base = (char*)d_ws;
  size_t off = 0;
  auto alloc = [&](size_t bytes) -> void* {
    void* p = base + off;
    off += (bytes + 255) & ~(size_t)255;
    return p;
  };

  unsigned* adj = (unsigned*)alloc((size_t)Bb * N0 * 32 * 4);        // 8 MB
  float* dis0 = (float*)alloc((size_t)Bb * N0 * 4);
  float* dis1 = (float*)alloc((size_t)Bb * N0 * 4);
  float* bigA = (float*)alloc((size_t)64 * 1024 * 1024);             // 64 MB multi-use
  float* XW  = bigA;                                                  // [B,1024,128]
  float* h1  = bigA + (size_t)Bb * N0 * Fd;                           // [B,1024,128]
  float* A1  = bigA;                                                  // [B,512,512] (after h1 dead)
  float* XW3 = bigA;                                                  // [B,256,128] (after A1 dead)
  float* h3  = bigA + (size_t)Bb * K2 * Fd;                           // [B,256,128]
  float* score = (float*)alloc((size_t)Bb * N0 * 4);
  int*   perm1 = (int*)alloc((size_t)Bb * K1 * 4);
  float* Xp1 = (float*)alloc((size_t)Bb * K1 * Fd * 4);               // later reused as A2
  float* A2  = Xp1;                                                   // [B,256,256] = same bytes
  float* ar1 = (float*)alloc((size_t)Bb * K1 * 4);
  float* ac1 = (float*)alloc((size_t)Bb * K1 * 4);
  float* disc2 = (float*)alloc((size_t)Bb * K1 * 4);
  float* sa2   = (float*)alloc((size_t)Bb * K1 * 4);
  float* disn2 = (float*)alloc((size_t)Bb * K1 * 4);
  float* diag2 = (float*)alloc((size_t)Bb * K1 * 4);
  float* XW2 = (float*)alloc((size_t)Bb * K1 * Fd * 4);               // Y2 in-place, later Yn
  float* h2  = (float*)alloc((size_t)Bb * K1 * Fd * 4);
  float* T   = (float*)alloc((size_t)Bb * K1 * Fd * 4);
  int*   perm2 = (int*)alloc((size_t)Bb * K2 * 4);
  float* Xp2 = (float*)alloc((size_t)Bb * K2 * Fd * 4);
  float* ar2 = (float*)alloc((size_t)Bb * K2 * 4);
  float* ac2 = (float*)alloc((size_t)Bb * K2 * 4);
  float* disc3 = (float*)alloc((size_t)Bb * K2 * 4);
  float* sa3   = (float*)alloc((size_t)Bb * K2 * 4);
  float* disn3 = (float*)alloc((size_t)Bb * K2 * 4);
  float* diag3 = (float*)alloc((size_t)Bb * K2 * 4);
  float* g  = (float*)alloc((size_t)Bb * 384 * 4);
  float* t1 = (float*)alloc((size_t)Bb * 128 * 4);
  float* t2 = (float*)alloc((size_t)Bb * 64 * 4);
  (void)ws_size; (void)in_sizes; (void)n_in; (void)out_size;

  // stage 1: binary graph
  hipMemsetAsync(adj, 0, (size_t)Bb * N0 * 32 * 4, stream);
  k_scatter<<<(Bb * NE + 255) / 256, 256, 0, stream>>>(src, dst, adj);
  k_degree<<<(Bb * N0 + 255) / 256, 256, 0, stream>>>(adj, dis0, dis1);
  k_gemm128<<<Bb * N0 / 64, 256, 0, stream>>>(x, W1, XW);
  k_conv1<<<Bb * N0, 128, 0, stream>>>(adj, XW, dis1, b1, h1);
  k_nis1<<<Bb * N0, 128, 0, stream>>>(adj, h1, dis0, score);
  k_topk<<<Bb, N0, 0, stream>>>(score, perm1, N0, K1);
  k_gather<<<Bb * K1, 128, 0, stream>>>(h1, perm1, att1, Xp1, ar1, ac1, N0, K1);
  k_readout<<<Bb, 128, 0, stream>>>(Xp1, K1, g, 1);
  k_buildA_bit<<<Bb * K1, K1, 0, stream>>>(adj, perm1, ar1, ac1, A1);  // overwrites XW/h1

  // stage 2: dense A1
  k_prep<<<Bb * K1, K1, 0, stream>>>(A1, K1, disc2, sa2, disn2, diag2);
  k_gemm128<<<Bb * K1 / 64, 256, 0, stream>>>(Xp1, W2, XW2);
  k_scale<<<(Bb * K1 * Fd + 255) / 256, 256, 0, stream>>>(XW2, disc2, XW2, Bb * K1 * Fd);
  k_mm<<<Bb * (K1 / 32), 256, 0, stream>>>(A1, XW2, T, K1);
  k_conv_epi<<<Bb * K1, 128, 0, stream>>>(T, XW2, disc2, sa2, b2, h2);
  k_scale<<<(Bb * K1 * Fd + 255) / 256, 256, 0, stream>>>(h2, disn2, XW2, Bb * K1 * Fd); // Yn
  k_mm<<<Bb * (K1 / 32), 256, 0, stream>>>(A1, XW2, T, K1);
  k_nis_epi<<<Bb * K1, 128, 0, stream>>>(h2, T, XW2, disn2, diag2, score);
  k_topk<<<Bb, K1, 0, stream>>>(score, perm2, K1, K2);
  k_gather<<<Bb * K2, 128, 0, stream>>>(h2, perm2, att2, Xp2, ar2, ac2, K1, K2);
  k_readout<<<Bb, 128, 0, stream>>>(Xp2, K2, g, 0);
  k_buildA_dense<<<Bb * K2, K2, 0, stream>>>(A1, perm2, ar2, ac2, A2);  // overwrites Xp1

  // stage 3: dense A2
  k_prep<<<Bb * K2, K2, 0, stream>>>(A2, K2, disc3, sa3, disn3, diag3);
  k_gemm128<<<Bb * K2 / 64, 256, 0, stream>>>(Xp2, W3, XW3);           // overwrites A1 region
  k_scale<<<(Bb * K2 * Fd + 255) / 256, 256, 0, stream>>>(XW3, disc3, XW3, Bb * K2 * Fd);
  k_mm<<<Bb * (K2 / 32), 256, 0, stream>>>(A2, XW3, T, K2);
  k_conv_epi<<<Bb * K2, 128, 0, stream>>>(T, XW3, disc3, sa3, b3, h3);
  k_readout<<<Bb, 128, 0, stream>>>(h3, K2, g, 0);

  // head
  k_xskew<<<Bb, 128, 0, stream>>>(skew, Wsk, bsk, g);
  k_mlp1<<<Bb, 128, 0, stream>>>(g, Wl1, bl1, t1);
  k_mlp2<<<Bb, 64, 0, stream>>>(t1, Wl2, bl2, t2);
  k_mlp3<<<Bb, 64, 0, stream>>>(t2, Wl3, bl3, out);
}

// Round 3
// 716.823 us; speedup vs baseline: 1.5845x; 1.3338x over previous
//
#include <hip/hip_runtime.h>
#include <math.h>

#define Bb 64
#define N0 1024
#define NE 16384
#define Fd 128
#define K1 512
#define K2 256

__device__ __forceinline__ float wred_sum(float v) {
#pragma unroll
  for (int o = 32; o > 0; o >>= 1) v += __shfl_down(v, o, 64);
  return v;
}
__device__ __forceinline__ float wred_max(float v) {
#pragma unroll
  for (int o = 32; o > 0; o >>= 1) v = fmaxf(v, __shfl_down(v, o, 64));
  return v;
}

// ---- build binary adjacency as bitmask: adj[b][i] = 32 words of row bits ----
__global__ void k_scatter(const int* __restrict__ src, const int* __restrict__ dst,
                          unsigned* __restrict__ adj) {
  int idx = blockIdx.x * 256 + threadIdx.x;
  if (idx >= Bb * NE) return;
  int b = idx >> 14, e = idx & (NE - 1);
  int u = src[b * NE + e], v = dst[b * NE + e];
  if (u == v) return;
  atomicOr(&adj[((b << 10) + u) * 32 + (v >> 5)], 1u << (v & 31));
  atomicOr(&adj[((b << 10) + v) * 32 + (u >> 5)], 1u << (u & 31));
}

__global__ void k_degree(const unsigned* __restrict__ adj, float* __restrict__ dis0,
                         float* __restrict__ dis1) {
  int row = blockIdx.x * 256 + threadIdx.x;
  if (row >= Bb * N0) return;
  int d = 0;
  const unsigned* w = adj + (size_t)row * 32;
#pragma unroll
  for (int i = 0; i < 32; ++i) d += __popc(w[i]);
  dis0[row] = d > 0 ? rsqrtf((float)d) : 0.f;
  dis1[row] = rsqrtf((float)(d + 1));
}

// ---- C[M,128] = X[M,128] @ W[128,128], M % 64 == 0, grid = M/64, block 256 ----
__global__ __launch_bounds__(256) void k_gemm128(const float* __restrict__ X,
                                                 const float* __restrict__ W,
                                                 float* __restrict__ C) {
  __shared__ float Xs[64][132];
  __shared__ float Ws[32][132];
  int t = threadIdx.x;
  size_t row0 = (size_t)blockIdx.x * 64;
  const float4* Xg = (const float4*)(X + row0 * Fd);
#pragma unroll
  for (int i = 0; i < 8; ++i) {
    int f4 = t + 256 * i;
    float4 v = Xg[f4];
    *(float4*)&Xs[f4 >> 5][(f4 & 31) * 4] = v;
  }
  int r0 = (t >> 5) * 8, c0 = (t & 31) * 4;
  float acc[8][4] = {};
  for (int kb = 0; kb < 128; kb += 32) {
    __syncthreads();
#pragma unroll
    for (int i = 0; i < 4; ++i) {
      int f4 = t + 256 * i;
      float4 v = ((const float4*)(W + (size_t)kb * Fd))[f4];
      *(float4*)&Ws[f4 >> 5][(f4 & 31) * 4] = v;
    }
    __syncthreads();
#pragma unroll
    for (int k = 0; k < 32; ++k) {
      float4 wv = *(const float4*)&Ws[k][c0];
#pragma unroll
      for (int i = 0; i < 8; ++i) {
        float xv = Xs[r0 + i][kb + k];
        acc[i][0] += xv * wv.x; acc[i][1] += xv * wv.y;
        acc[i][2] += xv * wv.z; acc[i][3] += xv * wv.w;
      }
    }
  }
#pragma unroll
  for (int i = 0; i < 8; ++i) {
    float4 o = make_float4(acc[i][0], acc[i][1], acc[i][2], acc[i][3]);
    *(float4*)&C[(row0 + r0 + i) * Fd + c0] = o;
  }
}

// ---- cooperative bitmask -> (idx, weight) list decode; returns degree ----
__device__ __forceinline__ int decode_adj(const unsigned* __restrict__ adjrow,
                                          const float* __restrict__ wsrc,
                                          int* idxs, float* wts, int t) {
  __shared__ unsigned wbuf[32];
  __shared__ int boff[32];
  __shared__ int degsh;
  if (t < 32) wbuf[t] = adjrow[t];
  __syncthreads();
  if (t == 0) {
    int s = 0;
#pragma unroll
    for (int w = 0; w < 32; ++w) { boff[w] = s; s += __popc(wbuf[w]); }
    degsh = s;
  }
  __syncthreads();
  if (t < 32) {
    unsigned m = wbuf[t];
    int o = boff[t];
    int bas = t << 5;
    while (m) {
      int j = bas + __ffs(m) - 1;
      m &= m - 1;
      idxs[o] = j; wts[o] = wsrc[j]; ++o;
    }
  } else if (t == 32) {
    int d = degsh, dp = (d + 7) & ~7;
    for (int p = d; p < dp; ++p) { idxs[p] = 0; wts[p] = 0.f; }
  }
  __syncthreads();
  return degsh;
}

// ---- gather-accumulate with 8 loads in flight ----
__device__ __forceinline__ float gather8(const float* __restrict__ srcb,
                                         const int* idxs, const float* wts,
                                         int deg, int f) {
  float acc = 0.f;
  int dp = (deg + 7) & ~7;
  for (int i = 0; i < dp; i += 8) {
    int jj[8]; float ww[8], vv[8];
#pragma unroll
    for (int u = 0; u < 8; ++u) { jj[u] = idxs[i + u]; ww[u] = wts[i + u]; }
#pragma unroll
    for (int u = 0; u < 8; ++u) vv[u] = srcb[(size_t)jj[u] * Fd + f];
#pragma unroll
    for (int u = 0; u < 8; ++u) acc += ww[u] * vv[u];
  }
  return acc;
}

// ---- conv1: h1 = relu(dis1_i*(sum_{j in N(i)} dis1_j XW_j + dis1_i XW_i) + b1) ----
__global__ __launch_bounds__(128) void k_conv1(const unsigned* __restrict__ adj,
    const float* __restrict__ XW, const float* __restrict__ dis1,
    const float* __restrict__ b1, float* __restrict__ h1) {
  __shared__ int idxs[1032];
  __shared__ float wts[1032];
  int row = blockIdx.x, f = threadIdx.x;
  int base = row & ~(N0 - 1);
  int deg = decode_adj(adj + (size_t)row * 32, dis1 + base, idxs, wts, f);
  float di = dis1[row];
  float acc = gather8(XW + (size_t)base * Fd, idxs, wts, deg, f);
  acc += di * XW[(size_t)row * Fd + f];
  h1[(size_t)row * Fd + f] = fmaxf(di * acc + b1[f], 0.f);
}

// ---- NIS on binary A: score_i = sum_f |h_i - dis0_i * sum_j dis0_j h_j| ----
__global__ __launch_bounds__(128) void k_nis1(const unsigned* __restrict__ adj,
    const float* __restrict__ h, const float* __restrict__ dis0, float* __restrict__ score) {
  __shared__ int idxs[1032];
  __shared__ float wts[1032];
  __shared__ float red[2];
  int row = blockIdx.x, f = threadIdx.x;
  int base = row & ~(N0 - 1);
  int deg = decode_adj(adj + (size_t)row * 32, dis0 + base, idxs, wts, f);
  float acc = gather8(h + (size_t)base * Fd, idxs, wts, deg, f);
  float val = h[(size_t)row * Fd + f] - dis0[row] * acc;
  float p = wred_sum(fabsf(val));
  if ((f & 63) == 0) red[f >> 6] = p;
  __syncthreads();
  if (f == 0) score[row] = red[0] + red[1];
}

// ---- exact top-k per graph: bitonic sort of (score,idx) packed u64 keys ----
__global__ __launch_bounds__(1024) void k_topk(const float* __restrict__ score,
                                               int* __restrict__ perm, int n, int k) {
  __shared__ unsigned long long keys[1024];
  int b = blockIdx.x, t = threadIdx.x;
  float s = score[b * n + t];
  unsigned ub = __float_as_uint(s);
  unsigned su = (ub & 0x80000000u) ? ~ub : (ub | 0x80000000u);  // monotone map
  keys[t] = ((unsigned long long)(~su) << 32) | (unsigned)t;    // asc sort = desc score, asc idx
  __syncthreads();
  for (int kk = 2; kk <= n; kk <<= 1) {
    for (int j = kk >> 1; j > 0; j >>= 1) {
      int ixj = t ^ j;
      if (ixj > t) {
        unsigned long long a = keys[t], c = keys[ixj];
        bool up = ((t & kk) == 0);
        if ((a > c) == up) { keys[t] = c; keys[ixj] = a; }
      }
      __syncthreads();
    }
  }
  if (t < k) perm[b * k + t] = (int)(keys[t] & 0xffffffffu);
}

// ---- gather pooled rows + attention dots ----
__global__ __launch_bounds__(128) void k_gather(const float* __restrict__ h,
    const int* __restrict__ perm, const float* __restrict__ att, float* __restrict__ Xp,
    float* __restrict__ ar, float* __restrict__ ac, int n, int k) {
  int idx = blockIdx.x, f = threadIdx.x;
  int b = idx / k;
  __shared__ float red[4];
  int p = perm[idx];
  float v = h[((size_t)b * n + p) * Fd + f];
  Xp[(size_t)idx * Fd + f] = v;
  float r1 = wred_sum(v * att[f]);
  float r2 = wred_sum(v * att[Fd + f]);
  if ((f & 63) == 0) { red[f >> 6] = r1; red[2 + (f >> 6)] = r2; }
  __syncthreads();
  if (f == 0) { ar[idx] = red[0] + red[1]; ac[idx] = red[2] + red[3]; }
}

// ---- readout: g[b][0:128] (+)= relu(max), g[b][128:256] (+)= relu(mean) ----
// 1024 threads: f = t&127, row-slice rs = t>>7 (8 slices), 8 loads in flight.
__global__ __launch_bounds__(1024) void k_readout(const float* __restrict__ X, int n,
                                                  float* __restrict__ g, int init) {
  int b = blockIdx.x, t = threadIdx.x;
  int f = t & 127, rs = t >> 7;
  __shared__ float smax[8][128];
  __shared__ float ssum[8][128];
  int per = n >> 3;  // rows per slice (64 or 32)
  const float* Xs = X + ((size_t)b * n + (size_t)rs * per) * Fd + f;
  float mx = -3.0e38f, sm = 0.f;
  for (int j = 0; j < per; j += 8) {
    float vv[8];
#pragma unroll
    for (int u = 0; u < 8; ++u) vv[u] = Xs[(size_t)(j + u) * Fd];
#pragma unroll
    for (int u = 0; u < 8; ++u) { mx = fmaxf(mx, vv[u]); sm += vv[u]; }
  }
  smax[rs][f] = mx; ssum[rs][f] = sm;
  __syncthreads();
  if (t < 128) {
    float m = smax[0][f], s = ssum[0][f];
#pragma unroll
    for (int q = 1; q < 8; ++q) { m = fmaxf(m, smax[q][f]); s += ssum[q][f]; }
    float a = fmaxf(m, 0.f);
    float m2 = fmaxf(s / (float)n, 0.f);
    if (init) { g[b * 384 + f] = a; g[b * 384 + 128 + f] = m2; }
    else      { g[b * 384 + f] += a; g[b * 384 + 128 + f] += m2; }
  }
}

// ---- A1 = softmax_row(leakyrelu(ar_i+ac_j) + bit(pi,pj)), K1=512 wide ----
__global__ __launch_bounds__(512) void k_buildA_bit(const unsigned* __restrict__ adj,
    const int* __restrict__ perm, const float* __restrict__ ar, const float* __restrict__ ac,
    float* __restrict__ A) {
  int bi = blockIdx.x;
  int b = bi >> 9, i = bi & (K1 - 1), j = threadIdx.x;
  __shared__ float redA[8], redB[8];
  int pi = perm[(b << 9) + i];
  int pj = perm[(b << 9) + j];
  float x = ar[(b << 9) + i] + ac[(b << 9) + j];
  x = x > 0.f ? x : 0.2f * x;
  unsigned word = adj[(size_t)((b << 10) + pi) * 32 + (pj >> 5)];
  x += (float)((word >> (pj & 31)) & 1u);
  int lane = j & 63, w = j >> 6;
  float m = wred_max(x);
  if (lane == 0) redA[w] = m;
  __syncthreads();
  m = redA[0];
#pragma unroll
  for (int q = 1; q < 8; ++q) m = fmaxf(m, redA[q]);
  float e = expf(x - m);
  float s = wred_sum(e);
  if (lane == 0) redB[w] = s;
  __syncthreads();
  s = redB[0];
#pragma unroll
  for (int q = 1; q < 8; ++q) s += redB[q];
  A[((size_t)(b << 9) + i) * K1 + j] = e / s;
}

// ---- A2 = softmax_row(leakyrelu(ar_i+ac_j) + A1[pi,pj]), K2=256 wide ----
__global__ __launch_bounds__(256) void k_buildA_dense(const float* __restrict__ Aprev,
    const int* __restrict__ perm, const float* __restrict__ ar, const float* __restrict__ ac,
    float* __restrict__ A) {
  int bi = blockIdx.x;
  int b = bi >> 8, i = bi & (K2 - 1), j = threadIdx.x;
  __shared__ float redA[4], redB[4];
  int pi = perm[(b << 8) + i];
  int pj = perm[(b << 8) + j];
  float x = ar[(b << 8) + i] + ac[(b << 8) + j];
  x = x > 0.f ? x : 0.2f * x;
  x += Aprev[((size_t)(b << 9) + pi) * K1 + pj];
  int lane = j & 63, w = j >> 6;
  float m = wred_max(x);
  if (lane == 0) redA[w] = m;
  __syncthreads();
  m = redA[0];
#pragma unroll
  for (int q = 1; q < 4; ++q) m = fmaxf(m, redA[q]);
  float e = expf(x - m);
  float s = wred_sum(e);
  if (lane == 0) redB[w] = s;
  __syncthreads();
  s = redB[0];
#pragma unroll
  for (int q = 1; q < 4; ++q) s += redB[q];
  A[((size_t)(b << 8) + i) * K2 + j] = e / s;
}

// ---- per-row stats of dense A: rowsum, diag -> dis_conv, selfadd, dis_nis, diag ----
__global__ void k_prep(const float* __restrict__ A, int n, float* __restrict__ disc,
                       float* __restrict__ sa, float* __restrict__ disn,
                       float* __restrict__ diagO) {
  int row = blockIdx.x, j = threadIdx.x;
  int i = row & (n - 1);
  __shared__ float red[8];
  __shared__ float dsh;
  float a = A[(size_t)row * n + j];
  if (j == i) dsh = a;
  float v = wred_sum(a);
  int lane = j & 63, w = j >> 6, nw = blockDim.x >> 6;
  if (lane == 0) red[w] = v;
  __syncthreads();
  float s = 0.f;
  for (int q = 0; q < nw; ++q) s += red[q];
  float d = dsh;
  if (j == 0) {
    float sav = (d == 0.f) ? 1.f : 0.f;
    float deg = s + sav;
    disc[row] = deg > 0.f ? rsqrtf(deg) : 0.f;
    sa[row] = sav;
    float deg0 = s - d;
    disn[row] = deg0 > 0.f ? rsqrtf(deg0) : 0.f;
    diagO[row] = d;
  }
}

__global__ void k_scale(const float* __restrict__ X, const float* __restrict__ dis,
                        float* __restrict__ Y, int total) {
  int idx = blockIdx.x * 256 + threadIdx.x;
  if (idx < total) Y[idx] = dis[idx >> 7] * X[idx];
}

// ---- dense T[b] = A[b](n x n) @ Y[b](n x 128); tile 32 rows, block 256 ----
__global__ __launch_bounds__(256) void k_mm(const float* __restrict__ A,
                                            const float* __restrict__ Y,
                                            float* __restrict__ T, int n) {
  int tiles = n >> 5;
  int b = blockIdx.x / tiles, rt = blockIdx.x - b * tiles;
  __shared__ float As[32][36];
  __shared__ float Ys[32][132];
  int t = threadIdx.x;
  const float* Ab = A + (size_t)b * n * n + (size_t)(rt * 32) * n;
  const float* Yb = Y + (size_t)b * n * Fd;
  int r0 = (t >> 5) * 4, c0 = (t & 31) * 4;
  float acc[4][4] = {};
  for (int kb = 0; kb < n; kb += 32) {
    __syncthreads();
    {
      int r = t >> 3, c4 = t & 7;
      float4 v = *(const float4*)&Ab[(size_t)r * n + kb + c4 * 4];
      *(float4*)&As[r][c4 * 4] = v;
    }
#pragma unroll
    for (int ii = 0; ii < 4; ++ii) {
      int f4 = t + 256 * ii;
      int r = f4 >> 5, c4 = f4 & 31;
      float4 v = *(const float4*)&Yb[(size_t)(kb + r) * Fd + c4 * 4];
      *(float4*)&Ys[r][c4 * 4] = v;
    }
    __syncthreads();
#pragma unroll
    for (int k = 0; k < 32; ++k) {
      float4 wv = *(const float4*)&Ys[k][c0];
#pragma unroll
      for (int i = 0; i < 4; ++i) {
        float av = As[r0 + i][k];
        acc[i][0] += av * wv.x; acc[i][1] += av * wv.y;
        acc[i][2] += av * wv.z; acc[i][3] += av * wv.w;
      }
    }
  }
  int orow = rt * 32 + r0;
#pragma unroll
  for (int i = 0; i < 4; ++i) {
    float4 o = make_float4(acc[i][0], acc[i][1], acc[i][2], acc[i][3]);
    *(float4*)&T[((size_t)b * n + orow + i) * Fd + c0] = o;
  }
}

__global__ __launch_bounds__(128) void k_conv_epi(const float* __restrict__ T,
    const float* __restrict__ Y, const float* __restrict__ disc, const float* __restrict__ sa,
    const float* __restrict__ bias, float* __restrict__ h) {
  int row = blockIdx.x, f = threadIdx.x;
  size_t o = (size_t)row * Fd + f;
  float v = T[o] + sa[row] * Y[o];
  h[o] = fmaxf(disc[row] * v + bias[f], 0.f);
}

__global__ __launch_bounds__(128) void k_nis_epi(const float* __restrict__ h,
    const float* __restrict__ T, const float* __restrict__ Yn, const float* __restrict__ disn,
    const float* __restrict__ diag, float* __restrict__ score) {
  int row = blockIdx.x, f = threadIdx.x;
  __shared__ float red[2];
  size_t o = (size_t)row * Fd + f;
  float val = h[o] - disn[row] * (T[o] - diag[row] * Yn[o]);
  float p = wred_sum(fabsf(val));
  if ((f & 63) == 0) red[f >> 6] = p;
  __syncthreads();
  if (f == 0) score[row] = red[0] + red[1];
}

__global__ __launch_bounds__(128) void k_xskew(const float* __restrict__ skew,
    const float* __restrict__ Wsk, const float* __restrict__ bsk, float* __restrict__ g) {
  int b = blockIdx.x, f = threadIdx.x;
  float acc = bsk[f];
  for (int s = 0; s < 64; ++s) acc += skew[b * 64 + s] * Wsk[s * Fd + f];
  g[b * 384 + 256 + f] = fmaxf(acc, 0.f);
}

__global__ __launch_bounds__(128) void k_mlp1(const float* __restrict__ g,
    const float* __restrict__ Wl, const float* __restrict__ bl, float* __restrict__ o) {
  int b = blockIdx.x, f = threadIdx.x;
  float acc = bl[f];
  for (int s = 0; s < 384; ++s) acc += g[b * 384 + s] * Wl[s * 128 + f];
  o[b * 128 + f] = fmaxf(acc, 0.f);
}
__global__ __launch_bounds__(64) void k_mlp2(const float* __restrict__ x,
    const float* __restrict__ Wl, const float* __restrict__ bl, float* __restrict__ o) {
  int b = blockIdx.x, f = threadIdx.x;
  float acc = bl[f];
  for (int s = 0; s < 128; ++s) acc += x[b * 128 + s] * Wl[s * 64 + f];
  o[b * 64 + f] = fmaxf(acc, 0.f);
}
__global__ __launch_bounds__(64) void k_mlp3(const float* __restrict__ x,
    const float* __restrict__ Wl, const float* __restrict__ bl, float* __restrict__ out) {
  int b = blockIdx.x, f = threadIdx.x;
  __shared__ float lg[10];
  if (f < 10) {
    float acc = bl[f];
    for (int s = 0; s < 64; ++s) acc += x[b * 64 + s] * Wl[s * 10 + f];
    lg[f] = acc;
  }
  __syncthreads();
  if (f == 0) {
    float m = lg[0];
    for (int c = 1; c < 10; ++c) m = fmaxf(m, lg[c]);
    float s = 0.f;
    for (int c = 0; c < 10; ++c) s += expf(lg[c] - m);
    float l = logf(s);
    for (int c = 0; c < 10; ++c) out[b * 10 + c] = lg[c] - m - l;
  }
}

extern "C" void kernel_launch(void* const* d_in, const int* in_sizes, int n_in,
                              void* d_out, int out_size, void* d_ws, size_t ws_size,
                              hipStream_t stream) {
  const float* x    = (const float*)d_in[0];
  const int*   src  = (const int*)d_in[1];
  const int*   dst  = (const int*)d_in[2];
  const float* skew = (const float*)d_in[3];
  const float* W1   = (const float*)d_in[4];
  const float* b1   = (const float*)d_in[5];
  const float* W2   = (const float*)d_in[6];
  const float* b2   = (const float*)d_in[7];
  const float* W3   = (const float*)d_in[8];
  const float* b3   = (const float*)d_in[9];
  const float* att1 = (const float*)d_in[10];
  const float* att2 = (const float*)d_in[11];
  const float* Wsk  = (const float*)d_in[12];
  const float* bsk  = (const float*)d_in[13];
  const float* Wl1  = (const float*)d_in[14];
  const float* bl1  = (const float*)d_in[15];
  const float* Wl2  = (const float*)d_in[16];
  const float* bl2  = (const float*)d_in[17];
  const float* Wl3  = (const float*)d_in[18];
  const float* bl3  = (const float*)d_in[19];
  float* out = (float*)d_out;

  char* base = (char*)d_ws;
  size_t off = 0;
  auto alloc = [&](size_t bytes) -> void* {
    void* p = base + off;
    off += (bytes + 255) & ~(size_t)255;
    return p;
  };

  unsigned* adj = (unsigned*)alloc((size_t)Bb * N0 * 32 * 4);        // 8 MB
  float* dis0 = (float*)alloc((size_t)Bb * N0 * 4);
  float* dis1 = (float*)alloc((size_t)Bb * N0 * 4);
  float* bigA = (float*)alloc((size_t)64 * 1024 * 1024);             // 64 MB multi-use
  float* XW  = bigA;                                                  // [B,1024,128]
  float* h1  = bigA + (size_t)Bb * N0 * Fd;                           // [B,1024,128]
  float* A1  = bigA;                                                  // [B,512,512] (after h1 dead)
  float* XW3 = bigA;                                                  // [B,256,128] (after A1 dead)
  float* h3  = bigA + (size_t)Bb * K2 * Fd;                           // [B,256,128]
  float* score = (float*)alloc((size_t)Bb * N0 * 4);
  int*   perm1 = (int*)alloc((size_t)Bb * K1 * 4);
  float* Xp1 = (float*)alloc((size_t)Bb * K1 * Fd * 4);               // later reused as A2
  float* A2  = Xp1;                                                   // [B,256,256] = same bytes
  float* ar1 = (float*)alloc((size_t)Bb * K1 * 4);
  float* ac1 = (float*)alloc((size_t)Bb * K1 * 4);
  float* disc2 = (float*)alloc((size_t)Bb * K1 * 4);
  float* sa2   = (float*)alloc((size_t)Bb * K1 * 4);
  float* disn2 = (float*)alloc((size_t)Bb * K1 * 4);
  float* diag2 = (float*)alloc((size_t)Bb * K1 * 4);
  float* XW2 = (float*)alloc((size_t)Bb * K1 * Fd * 4);               // Y2 in-place, later Yn
  float* h2  = (float*)alloc((size_t)Bb * K1 * Fd * 4);
  float* T   = (float*)alloc((size_t)Bb * K1 * Fd * 4);
  int*   perm2 = (int*)alloc((size_t)Bb * K2 * 4);
  float* Xp2 = (float*)alloc((size_t)Bb * K2 * Fd * 4);
  float* ar2 = (float*)alloc((size_t)Bb * K2 * 4);
  float* ac2 = (float*)alloc((size_t)Bb * K2 * 4);
  float* disc3 = (float*)alloc((size_t)Bb * K2 * 4);
  float* sa3   = (float*)alloc((size_t)Bb * K2 * 4);
  float* disn3 = (float*)alloc((size_t)Bb * K2 * 4);
  float* diag3 = (float*)alloc((size_t)Bb * K2 * 4);
  float* g  = (float*)alloc((size_t)Bb * 384 * 4);
  float* t1 = (float*)alloc((size_t)Bb * 128 * 4);
  float* t2 = (float*)alloc((size_t)Bb * 64 * 4);
  (void)ws_size; (void)in_sizes; (void)n_in; (void)out_size;

  // stage 1: binary graph
  hipMemsetAsync(adj, 0, (size_t)Bb * N0 * 32 * 4, stream);
  k_scatter<<<(Bb * NE + 255) / 256, 256, 0, stream>>>(src, dst, adj);
  k_degree<<<(Bb * N0 + 255) / 256, 256, 0, stream>>>(adj, dis0, dis1);
  k_gemm128<<<Bb * N0 / 64, 256, 0, stream>>>(x, W1, XW);
  k_conv1<<<Bb * N0, 128, 0, stream>>>(adj, XW, dis1, b1, h1);
  k_nis1<<<Bb * N0, 128, 0, stream>>>(adj, h1, dis0, score);
  k_topk<<<Bb, N0, 0, stream>>>(score, perm1, N0, K1);
  k_gather<<<Bb * K1, 128, 0, stream>>>(h1, perm1, att1, Xp1, ar1, ac1, N0, K1);
  k_readout<<<Bb, 1024, 0, stream>>>(Xp1, K1, g, 1);
  k_buildA_bit<<<Bb * K1, K1, 0, stream>>>(adj, perm1, ar1, ac1, A1);  // overwrites XW/h1

  // stage 2: dense A1
  k_prep<<<Bb * K1, K1, 0, stream>>>(A1, K1, disc2, sa2, disn2, diag2);
  k_gemm128<<<Bb * K1 / 64, 256, 0, stream>>>(Xp1, W2, XW2);
  k_scale<<<(Bb * K1 * Fd + 255) / 256, 256, 0, stream>>>(XW2, disc2, XW2, Bb * K1 * Fd);
  k_mm<<<Bb * (K1 / 32), 256, 0, stream>>>(A1, XW2, T, K1);
  k_conv_epi<<<Bb * K1, 128, 0, stream>>>(T, XW2, disc2, sa2, b2, h2);
  k_scale<<<(Bb * K1 * Fd + 255) / 256, 256, 0, stream>>>(h2, disn2, XW2, Bb * K1 * Fd); // Yn
  k_mm<<<Bb * (K1 / 32), 256, 0, stream>>>(A1, XW2, T, K1);
  k_nis_epi<<<Bb * K1, 128, 0, stream>>>(h2, T, XW2, disn2, diag2, score);
  k_topk<<<Bb, K1, 0, stream>>>(score, perm2, K1, K2);
  k_gather<<<Bb * K2, 128, 0, stream>>>(h2, perm2, att2, Xp2, ar2, ac2, K1, K2);
  k_readout<<<Bb, 1024, 0, stream>>>(Xp2, K2, g, 0);
  k_buildA_dense<<<Bb * K2, K2, 0, stream>>>(A1, perm2, ar2, ac2, A2);  // overwrites Xp1

  // stage 3: dense A2
  k_prep<<<Bb * K2, K2, 0, stream>>>(A2, K2, disc3, sa3, disn3, diag3);
  k_gemm128<<<Bb * K2 / 64, 256, 0, stream>>>(Xp2, W3, XW3);           // overwrites A1 region
  k_scale<<<(Bb * K2 * Fd + 255) / 256, 256, 0, stream>>>(XW3, disc3, XW3, Bb * K2 * Fd);
  k_mm<<<Bb * (K2 / 32), 256, 0, stream>>>(A2, XW3, T, K2);
  k_conv_epi<<<Bb * K2, 128, 0, stream>>>(T, XW3, disc3, sa3, b3, h3);
  k_readout<<<Bb, 1024, 0, stream>>>(h3, K2, g, 0);

  // head
  k_xskew<<<Bb, 128, 0, stream>>>(skew, Wsk, bsk, g);
  k_mlp1<<<Bb, 128, 0, stream>>>(g, Wl1, bl1, t1);
  k_mlp2<<<Bb, 64, 0, stream>>>(t1, Wl2, bl2, t2);
  k_mlp3<<<Bb, 64, 0, stream>>>(t2, Wl3, bl3, out);
}

// Round 4
// 667.505 us; speedup vs baseline: 1.7015x; 1.0739x over previous
//
#include <hip/hip_runtime.h>
#include <math.h>

#define Bb 64
#define N0 1024
#define NE 16384
#define Fd 128
#define K1 512
#define K2 256

__device__ __forceinline__ float wred_sum(float v) {
#pragma unroll
  for (int o = 32; o > 0; o >>= 1) v += __shfl_down(v, o, 64);
  return v;
}
__device__ __forceinline__ float wred_max(float v) {
#pragma unroll
  for (int o = 32; o > 0; o >>= 1) v = fmaxf(v, __shfl_down(v, o, 64));
  return v;
}

// ---- build binary adjacency as bitmask: adj[b][i] = 32 words of row bits ----
__global__ void k_scatter(const int* __restrict__ src, const int* __restrict__ dst,
                          unsigned* __restrict__ adj) {
  int idx = blockIdx.x * 256 + threadIdx.x;
  if (idx >= Bb * NE) return;
  int b = idx >> 14, e = idx & (NE - 1);
  int u = src[b * NE + e], v = dst[b * NE + e];
  if (u == v) return;
  atomicOr(&adj[((b << 10) + u) * 32 + (v >> 5)], 1u << (v & 31));
  atomicOr(&adj[((b << 10) + v) * 32 + (u >> 5)], 1u << (u & 31));
}

__global__ void k_degree(const unsigned* __restrict__ adj, float* __restrict__ dis0,
                         float* __restrict__ dis1) {
  int row = blockIdx.x * 256 + threadIdx.x;
  if (row >= Bb * N0) return;
  int d = 0;
  const unsigned* w = adj + (size_t)row * 32;
#pragma unroll
  for (int i = 0; i < 32; ++i) d += __popc(w[i]);
  dis0[row] = d > 0 ? rsqrtf((float)d) : 0.f;
  dis1[row] = rsqrtf((float)(d + 1));
}

// ---- one-time bitmask -> neighbor-list decode (padded cap 128/row) ----
__global__ __launch_bounds__(64) void k_adjlist(const unsigned* __restrict__ adj,
    int* __restrict__ nbr, int* __restrict__ degv) {
  __shared__ unsigned wbuf[32];
  __shared__ int boff[32];
  int row = blockIdx.x, t = threadIdx.x;
  if (t < 32) wbuf[t] = adj[(size_t)row * 32 + t];
  __syncthreads();
  if (t == 0) {
    int s = 0;
#pragma unroll
    for (int w = 0; w < 32; ++w) { boff[w] = s; s += __popc(wbuf[w]); }
    degv[row] = s;
  }
  __syncthreads();
  if (t < 32) {
    unsigned m = wbuf[t];
    int o = boff[t];
    int bas = t << 5;
    int* dstp = nbr + (size_t)row * 128;
    while (m) { int j = bas + __ffs(m) - 1; m &= m - 1; dstp[o++] = j; }
  }
}

// ---- C[M,128] = X[M,128] @ W[128,128], M % 64 == 0, grid = M/64, block 256 ----
__global__ __launch_bounds__(256) void k_gemm128(const float* __restrict__ X,
                                                 const float* __restrict__ W,
                                                 float* __restrict__ C) {
  __shared__ float Xs[64][132];
  __shared__ float Ws[32][132];
  int t = threadIdx.x;
  size_t row0 = (size_t)blockIdx.x * 64;
  const float4* Xg = (const float4*)(X + row0 * Fd);
#pragma unroll
  for (int i = 0; i < 8; ++i) {
    int f4 = t + 256 * i;
    float4 v = Xg[f4];
    *(float4*)&Xs[f4 >> 5][(f4 & 31) * 4] = v;
  }
  int r0 = (t >> 5) * 8, c0 = (t & 31) * 4;
  float acc[8][4] = {};
  for (int kb = 0; kb < 128; kb += 32) {
    __syncthreads();
#pragma unroll
    for (int i = 0; i < 4; ++i) {
      int f4 = t + 256 * i;
      float4 v = ((const float4*)(W + (size_t)kb * Fd))[f4];
      *(float4*)&Ws[f4 >> 5][(f4 & 31) * 4] = v;
    }
    __syncthreads();
#pragma unroll
    for (int k = 0; k < 32; ++k) {
      float4 wv = *(const float4*)&Ws[k][c0];
#pragma unroll
      for (int i = 0; i < 8; ++i) {
        float xv = Xs[r0 + i][kb + k];
        acc[i][0] += xv * wv.x; acc[i][1] += xv * wv.y;
        acc[i][2] += xv * wv.z; acc[i][3] += xv * wv.w;
      }
    }
  }
#pragma unroll
  for (int i = 0; i < 8; ++i) {
    float4 o = make_float4(acc[i][0], acc[i][1], acc[i][2], acc[i][3]);
    *(float4*)&C[(row0 + r0 + i) * Fd + c0] = o;
  }
}

// ---- gather-accumulate with 8 loads in flight ----
__device__ __forceinline__ float gather8(const float* __restrict__ srcb,
                                         const int* idxs, const float* wts,
                                         int deg, int f) {
  float acc = 0.f;
  int dp = (deg + 7) & ~7;
  for (int i = 0; i < dp; i += 8) {
    int jj[8]; float ww[8], vv[8];
#pragma unroll
    for (int u = 0; u < 8; ++u) { jj[u] = idxs[i + u]; ww[u] = wts[i + u]; }
#pragma unroll
    for (int u = 0; u < 8; ++u) vv[u] = srcb[(size_t)jj[u] * Fd + f];
#pragma unroll
    for (int u = 0; u < 8; ++u) acc += ww[u] * vv[u];
  }
  return acc;
}

// XCD-grouped row swizzle: blocks with bid%8==c -> XCD c -> graphs [c*8, c*8+8)
__device__ __forceinline__ int swz_row(int bid) {
  int c = bid & 7, q = bid >> 3;
  return (((c << 3) + (q >> 10)) << 10) + (q & 1023);
}

// ---- conv1: h1 = relu(dis1_i*(sum_{j in N(i)} dis1_j XW_j + dis1_i XW_i) + b1) ----
__global__ __launch_bounds__(128) void k_conv1(const int* __restrict__ nbr,
    const int* __restrict__ degv, const float* __restrict__ XW,
    const float* __restrict__ dis1, const float* __restrict__ b1, float* __restrict__ h1) {
  __shared__ int idxs[128];
  __shared__ float wts[128];
  int row = swz_row(blockIdx.x), f = threadIdx.x;
  int base = row & ~(N0 - 1);
  int deg = degv[row];
  int li = (f < deg) ? nbr[(size_t)row * 128 + f] : 0;
  idxs[f] = li;
  wts[f] = (f < deg) ? dis1[base + li] : 0.f;
  __syncthreads();
  float di = dis1[row];
  float acc = gather8(XW + (size_t)base * Fd, idxs, wts, deg, f);
  acc += di * XW[(size_t)row * Fd + f];
  h1[(size_t)row * Fd + f] = fmaxf(di * acc + b1[f], 0.f);
}

// ---- NIS on binary A: score_i = sum_f |h_i - dis0_i * sum_j dis0_j h_j| ----
__global__ __launch_bounds__(128) void k_nis1(const int* __restrict__ nbr,
    const int* __restrict__ degv, const float* __restrict__ h,
    const float* __restrict__ dis0, float* __restrict__ score) {
  __shared__ int idxs[128];
  __shared__ float wts[128];
  __shared__ float red[2];
  int row = swz_row(blockIdx.x), f = threadIdx.x;
  int base = row & ~(N0 - 1);
  int deg = degv[row];
  int li = (f < deg) ? nbr[(size_t)row * 128 + f] : 0;
  idxs[f] = li;
  wts[f] = (f < deg) ? dis0[base + li] : 0.f;
  __syncthreads();
  float acc = gather8(h + (size_t)base * Fd, idxs, wts, deg, f);
  float val = h[(size_t)row * Fd + f] - dis0[row] * acc;
  float p = wred_sum(fabsf(val));
  if ((f & 63) == 0) red[f >> 6] = p;
  __syncthreads();
  if (f == 0) score[row] = red[0] + red[1];
}

// ---- exact top-k per graph: bitonic sort of (score,idx) packed u64 keys ----
__global__ __launch_bounds__(1024) void k_topk(const float* __restrict__ score,
                                               int* __restrict__ perm, int n, int k) {
  __shared__ unsigned long long keys[1024];
  int b = blockIdx.x, t = threadIdx.x;
  float s = score[b * n + t];
  unsigned ub = __float_as_uint(s);
  unsigned su = (ub & 0x80000000u) ? ~ub : (ub | 0x80000000u);  // monotone map
  keys[t] = ((unsigned long long)(~su) << 32) | (unsigned)t;    // asc sort = desc score, asc idx
  __syncthreads();
  for (int kk = 2; kk <= n; kk <<= 1) {
    for (int j = kk >> 1; j > 0; j >>= 1) {
      int ixj = t ^ j;
      if (ixj > t) {
        unsigned long long a = keys[t], c = keys[ixj];
        bool up = ((t & kk) == 0);
        if ((a > c) == up) { keys[t] = c; keys[ixj] = a; }
      }
      __syncthreads();
    }
  }
  if (t < k) perm[b * k + t] = (int)(keys[t] & 0xffffffffu);
}

// ---- gather pooled rows + attention dots ----
__global__ __launch_bounds__(128) void k_gather(const float* __restrict__ h,
    const int* __restrict__ perm, const float* __restrict__ att, float* __restrict__ Xp,
    float* __restrict__ ar, float* __restrict__ ac, int n, int k) {
  int idx = blockIdx.x, f = threadIdx.x;
  int b = idx / k;
  __shared__ float red[4];
  int p = perm[idx];
  float v = h[((size_t)b * n + p) * Fd + f];
  Xp[(size_t)idx * Fd + f] = v;
  float r1 = wred_sum(v * att[f]);
  float r2 = wred_sum(v * att[Fd + f]);
  if ((f & 63) == 0) { red[f >> 6] = r1; red[2 + (f >> 6)] = r2; }
  __syncthreads();
  if (f == 0) { ar[idx] = red[0] + red[1]; ac[idx] = red[2] + red[3]; }
}

// ---- readout: g[b][0:128] (+)= relu(max), g[b][128:256] (+)= relu(mean) ----
__global__ __launch_bounds__(1024) void k_readout(const float* __restrict__ X, int n,
                                                  float* __restrict__ g, int init) {
  int b = blockIdx.x, t = threadIdx.x;
  int f = t & 127, rs = t >> 7;
  __shared__ float smax[8][128];
  __shared__ float ssum[8][128];
  int per = n >> 3;
  const float* Xs = X + ((size_t)b * n + (size_t)rs * per) * Fd + f;
  float mx = -3.0e38f, sm = 0.f;
  for (int j = 0; j < per; j += 8) {
    float vv[8];
#pragma unroll
    for (int u = 0; u < 8; ++u) vv[u] = Xs[(size_t)(j + u) * Fd];
#pragma unroll
    for (int u = 0; u < 8; ++u) { mx = fmaxf(mx, vv[u]); sm += vv[u]; }
  }
  smax[rs][f] = mx; ssum[rs][f] = sm;
  __syncthreads();
  if (t < 128) {
    float m = smax[0][f], s = ssum[0][f];
#pragma unroll
    for (int q = 1; q < 8; ++q) { m = fmaxf(m, smax[q][f]); s += ssum[q][f]; }
    float a = fmaxf(m, 0.f);
    float m2 = fmaxf(s / (float)n, 0.f);
    if (init) { g[b * 384 + f] = a; g[b * 384 + 128 + f] = m2; }
    else      { g[b * 384 + f] += a; g[b * 384 + 128 + f] += m2; }
  }
}

// ---- A1 = softmax_row(leakyrelu(ar_i+ac_j) + bit(pi,pj)), K1=512 wide ----
__global__ __launch_bounds__(512) void k_buildA_bit(const unsigned* __restrict__ adj,
    const int* __restrict__ perm, const float* __restrict__ ar, const float* __restrict__ ac,
    float* __restrict__ A) {
  int bi = blockIdx.x;
  int b = bi >> 9, i = bi & (K1 - 1), j = threadIdx.x;
  __shared__ float redA[8], redB[8];
  int pi = perm[(b << 9) + i];
  int pj = perm[(b << 9) + j];
  float x = ar[(b << 9) + i] + ac[(b << 9) + j];
  x = x > 0.f ? x : 0.2f * x;
  unsigned word = adj[(size_t)((b << 10) + pi) * 32 + (pj >> 5)];
  x += (float)((word >> (pj & 31)) & 1u);
  int lane = j & 63, w = j >> 6;
  float m = wred_max(x);
  if (lane == 0) redA[w] = m;
  __syncthreads();
  m = redA[0];
#pragma unroll
  for (int q = 1; q < 8; ++q) m = fmaxf(m, redA[q]);
  float e = expf(x - m);
  float s = wred_sum(e);
  if (lane == 0) redB[w] = s;
  __syncthreads();
  s = redB[0];
#pragma unroll
  for (int q = 1; q < 8; ++q) s += redB[q];
  A[((size_t)(b << 9) + i) * K1 + j] = e / s;
}

// ---- A2 = softmax_row(leakyrelu(ar_i+ac_j) + A1[pi,pj]), K2=256 wide ----
__global__ __launch_bounds__(256) void k_buildA_dense(const float* __restrict__ Aprev,
    const int* __restrict__ perm, const float* __restrict__ ar, const float* __restrict__ ac,
    float* __restrict__ A) {
  int bi = blockIdx.x;
  int b = bi >> 8, i = bi & (K2 - 1), j = threadIdx.x;
  __shared__ float redA[4], redB[4];
  int pi = perm[(b << 8) + i];
  int pj = perm[(b << 8) + j];
  float x = ar[(b << 8) + i] + ac[(b << 8) + j];
  x = x > 0.f ? x : 0.2f * x;
  x += Aprev[((size_t)(b << 9) + pi) * K1 + pj];
  int lane = j & 63, w = j >> 6;
  float m = wred_max(x);
  if (lane == 0) redA[w] = m;
  __syncthreads();
  m = redA[0];
#pragma unroll
  for (int q = 1; q < 4; ++q) m = fmaxf(m, redA[q]);
  float e = expf(x - m);
  float s = wred_sum(e);
  if (lane == 0) redB[w] = s;
  __syncthreads();
  s = redB[0];
#pragma unroll
  for (int q = 1; q < 4; ++q) s += redB[q];
  A[((size_t)(b << 8) + i) * K2 + j] = e / s;
}

// ---- per-row stats of dense A: rowsum, diag -> dis_conv, selfadd, dis_nis, diag ----
__global__ void k_prep(const float* __restrict__ A, int n, float* __restrict__ disc,
                       float* __restrict__ sa, float* __restrict__ disn,
                       float* __restrict__ diagO) {
  int row = blockIdx.x, j = threadIdx.x;
  int i = row & (n - 1);
  __shared__ float red[8];
  __shared__ float dsh;
  float a = A[(size_t)row * n + j];
  if (j == i) dsh = a;
  float v = wred_sum(a);
  int lane = j & 63, w = j >> 6, nw = blockDim.x >> 6;
  if (lane == 0) red[w] = v;
  __syncthreads();
  float s = 0.f;
  for (int q = 0; q < nw; ++q) s += red[q];
  float d = dsh;
  if (j == 0) {
    float sav = (d == 0.f) ? 1.f : 0.f;
    float deg = s + sav;
    disc[row] = deg > 0.f ? rsqrtf(deg) : 0.f;
    sa[row] = sav;
    float deg0 = s - d;
    disn[row] = deg0 > 0.f ? rsqrtf(deg0) : 0.f;
    diagO[row] = d;
  }
}

// ---- T[b] = A[b](n x n) @ (diag(w) Y[b])(n x 128); BM=64, block 256 ----
// thread: 4 rows (r0=(t>>4)*4) x 8 cols (c0=(t&15)*4 and c0+64)
__global__ __launch_bounds__(256) void k_mm(const float* __restrict__ A,
                                            const float* __restrict__ Y,
                                            const float* __restrict__ w,
                                            float* __restrict__ T, int n) {
  int tiles = n >> 6;
  int b = blockIdx.x / tiles, rt = blockIdx.x - b * tiles;
  __shared__ float As[64][36];
  __shared__ float Ys[32][132];
  int t = threadIdx.x;
  const float* Ab = A + (size_t)b * n * n + (size_t)(rt * 64) * n;
  const float* Yb = Y + (size_t)b * n * Fd;
  const float* wb = w ? (w + (size_t)b * n) : (const float*)0;
  int r0 = (t >> 4) * 4, c0 = (t & 15) * 4;
  float acc[4][8] = {};
  for (int kb = 0; kb < n; kb += 32) {
    __syncthreads();
#pragma unroll
    for (int ii = 0; ii < 2; ++ii) {
      int f4 = t + 256 * ii;
      int r = f4 >> 3, c4 = (f4 & 7) * 4;
      *(float4*)&As[r][c4] = *(const float4*)&Ab[(size_t)r * n + kb + c4];
    }
#pragma unroll
    for (int ii = 0; ii < 4; ++ii) {
      int f4 = t + 256 * ii;
      int r = f4 >> 5, c4 = (f4 & 31) * 4;
      float4 v = *(const float4*)&Yb[(size_t)(kb + r) * Fd + c4];
      float s = wb ? wb[kb + r] : 1.f;
      v.x *= s; v.y *= s; v.z *= s; v.w *= s;
      *(float4*)&Ys[r][c4] = v;
    }
    __syncthreads();
#pragma unroll
    for (int k4 = 0; k4 < 8; ++k4) {
      float a_[4][4];
#pragma unroll
      for (int i = 0; i < 4; ++i)
        *(float4*)a_[i] = *(const float4*)&As[r0 + i][k4 * 4];
#pragma unroll
      for (int kk = 0; kk < 4; ++kk) {
        float4 y0 = *(const float4*)&Ys[k4 * 4 + kk][c0];
        float4 y1 = *(const float4*)&Ys[k4 * 4 + kk][c0 + 64];
#pragma unroll
        for (int i = 0; i < 4; ++i) {
          float av = a_[i][kk];
          acc[i][0] += av * y0.x; acc[i][1] += av * y0.y;
          acc[i][2] += av * y0.z; acc[i][3] += av * y0.w;
          acc[i][4] += av * y1.x; acc[i][5] += av * y1.y;
          acc[i][6] += av * y1.z; acc[i][7] += av * y1.w;
        }
      }
    }
  }
  int orow = rt * 64 + r0;
#pragma unroll
  for (int i = 0; i < 4; ++i) {
    size_t ro = ((size_t)b * n + orow + i) * Fd;
    *(float4*)&T[ro + c0]      = make_float4(acc[i][0], acc[i][1], acc[i][2], acc[i][3]);
    *(float4*)&T[ro + c0 + 64] = make_float4(acc[i][4], acc[i][5], acc[i][6], acc[i][7]);
  }
}

__global__ __launch_bounds__(128) void k_conv_epi(const float* __restrict__ T,
    const float* __restrict__ Y, const float* __restrict__ disc, const float* __restrict__ sa,
    const float* __restrict__ bias, float* __restrict__ h) {
  int row = blockIdx.x, f = threadIdx.x;
  size_t o = (size_t)row * Fd + f;
  float dc = disc[row];
  float v = T[o] + sa[row] * dc * Y[o];
  h[o] = fmaxf(dc * v + bias[f], 0.f);
}

__global__ __launch_bounds__(128) void k_nis_epi(const float* __restrict__ h,
    const float* __restrict__ T, const float* __restrict__ disn,
    const float* __restrict__ diag, float* __restrict__ score) {
  int row = blockIdx.x, f = threadIdx.x;
  __shared__ float red[2];
  size_t o = (size_t)row * Fd + f;
  float dn = disn[row];
  float hv = h[o];
  float val = hv - dn * (T[o] - diag[row] * dn * hv);
  float p = wred_sum(fabsf(val));
  if ((f & 63) == 0) red[f >> 6] = p;
  __syncthreads();
  if (f == 0) score[row] = red[0] + red[1];
}

__global__ __launch_bounds__(128) void k_xskew(const float* __restrict__ skew,
    const float* __restrict__ Wsk, const float* __restrict__ bsk, float* __restrict__ g) {
  int b = blockIdx.x, f = threadIdx.x;
  float acc = bsk[f];
  for (int s = 0; s < 64; ++s) acc += skew[b * 64 + s] * Wsk[s * Fd + f];
  g[b * 384 + 256 + f] = fmaxf(acc, 0.f);
}

__global__ __launch_bounds__(128) void k_mlp1(const float* __restrict__ g,
    const float* __restrict__ Wl, const float* __restrict__ bl, float* __restrict__ o) {
  int b = blockIdx.x, f = threadIdx.x;
  float acc = bl[f];
  for (int s = 0; s < 384; ++s) acc += g[b * 384 + s] * Wl[s * 128 + f];
  o[b * 128 + f] = fmaxf(acc, 0.f);
}
__global__ __launch_bounds__(64) void k_mlp2(const float* __restrict__ x,
    const float* __restrict__ Wl, const float* __restrict__ bl, float* __restrict__ o) {
  int b = blockIdx.x, f = threadIdx.x;
  float acc = bl[f];
  for (int s = 0; s < 128; ++s) acc += x[b * 128 + s] * Wl[s * 64 + f];
  o[b * 64 + f] = fmaxf(acc, 0.f);
}
__global__ __launch_bounds__(64) void k_mlp3(const float* __restrict__ x,
    const float* __restrict__ Wl, const float* __restrict__ bl, float* __restrict__ out) {
  int b = blockIdx.x, f = threadIdx.x;
  __shared__ float lg[10];
  if (f < 10) {
    float acc = bl[f];
    for (int s = 0; s < 64; ++s) acc += x[b * 64 + s] * Wl[s * 10 + f];
    lg[f] = acc;
  }
  __syncthreads();
  if (f == 0) {
    float m = lg[0];
    for (int c = 1; c < 10; ++c) m = fmaxf(m, lg[c]);
    float s = 0.f;
    for (int c = 0; c < 10; ++c) s += expf(lg[c] - m);
    float l = logf(s);
    for (int c = 0; c < 10; ++c) out[b * 10 + c] = lg[c] - m - l;
  }
}

extern "C" void kernel_launch(void* const* d_in, const int* in_sizes, int n_in,
                              void* d_out, int out_size, void* d_ws, size_t ws_size,
                              hipStream_t stream) {
  const float* x    = (const float*)d_in[0];
  const int*   src  = (const int*)d_in[1];
  const int*   dst  = (const int*)d_in[2];
  const float* skew = (const float*)d_in[3];
  const float* W1   = (const float*)d_in[4];
  const float* b1   = (const float*)d_in[5];
  const float* W2   = (const float*)d_in[6];
  const float* b2   = (const float*)d_in[7];
  const float* W3   = (const float*)d_in[8];
  const float* b3   = (const float*)d_in[9];
  const float* att1 = (const float*)d_in[10];
  const float* att2 = (const float*)d_in[11];
  const float* Wsk  = (const float*)d_in[12];
  const float* bsk  = (const float*)d_in[13];
  const float* Wl1  = (const float*)d_in[14];
  const float* bl1  = (const float*)d_in[15];
  const float* Wl2  = (const float*)d_in[16];
  const float* bl2  = (const float*)d_in[17];
  const float* Wl3  = (const float*)d_in[18];
  const float* bl3  = (const float*)d_in[19];
  float* out = (float*)d_out;

  char* base = (char*)d_ws;
  size_t off = 0;
  auto alloc = [&](size_t bytes) -> void* {
    void* p = base + off;
    off += (bytes + 255) & ~(size_t)255;
    return p;
  };

  unsigned* adj = (unsigned*)alloc((size_t)Bb * N0 * 32 * 4);        // 8 MB
  float* dis0 = (float*)alloc((size_t)Bb * N0 * 4);
  float* dis1 = (float*)alloc((size_t)Bb * N0 * 4);
  int*   degv = (int*)alloc((size_t)Bb * N0 * 4);
  float* bigA = (float*)alloc((size_t)64 * 1024 * 1024);             // 64 MB multi-use
  float* XW  = bigA;                                                  // [B,1024,128]
  float* h1  = bigA + (size_t)Bb * N0 * Fd;                           // [B,1024,128]
  float* A1  = bigA;                                                  // [B,512,512] (after h1 dead)
  float* XW3 = bigA;                                                  // [B,256,128] (after A1 dead)
  float* h3  = bigA + (size_t)Bb * K2 * Fd;                           // [B,256,128]
  float* score = (float*)alloc((size_t)Bb * N0 * 4);
  int*   perm1 = (int*)alloc((size_t)Bb * K1 * 4);
  float* Xp1 = (float*)alloc((size_t)Bb * K1 * Fd * 4);               // later reused as A2
  float* A2  = Xp1;                                                   // [B,256,256] = same bytes
  float* ar1 = (float*)alloc((size_t)Bb * K1 * 4);
  float* ac1 = (float*)alloc((size_t)Bb * K1 * 4);
  float* disc2 = (float*)alloc((size_t)Bb * K1 * 4);
  float* sa2   = (float*)alloc((size_t)Bb * K1 * 4);
  float* disn2 = (float*)alloc((size_t)Bb * K1 * 4);
  float* diag2 = (float*)alloc((size_t)Bb * K1 * 4);
  float* XW2 = (float*)alloc((size_t)Bb * K1 * Fd * 4);               // 16 MB
  float* h2  = (float*)alloc((size_t)Bb * K1 * Fd * 4);               // 16 MB (contiguous w/ XW2)
  float* T   = (float*)alloc((size_t)Bb * K1 * Fd * 4);
  int*   perm2 = (int*)alloc((size_t)Bb * K2 * 4);
  float* Xp2 = (float*)alloc((size_t)Bb * K2 * Fd * 4);
  float* ar2 = (float*)alloc((size_t)Bb * K2 * 4);
  float* ac2 = (float*)alloc((size_t)Bb * K2 * 4);
  float* disc3 = (float*)alloc((size_t)Bb * K2 * 4);
  float* sa3   = (float*)alloc((size_t)Bb * K2 * 4);
  float* disn3 = (float*)alloc((size_t)Bb * K2 * 4);
  float* diag3 = (float*)alloc((size_t)Bb * K2 * 4);
  float* g  = (float*)alloc((size_t)Bb * 384 * 4);
  float* t1 = (float*)alloc((size_t)Bb * 128 * 4);
  float* t2 = (float*)alloc((size_t)Bb * 64 * 4);
  // nbr [B*N0][128] ints = 32 MB; overlays XW2+h2 (dead until stage-2 gemm,
  // nbr dead after k_nis1). XW2/h2 are adjacent 16 MB 256-aligned blocks.
  int* nbr = (int*)XW2;
  (void)ws_size; (void)in_sizes; (void)n_in; (void)out_size;

  // stage 1: binary graph
  hipMemsetAsync(adj, 0, (size_t)Bb * N0 * 32 * 4, stream);
  k_scatter<<<(Bb * NE + 255) / 256, 256, 0, stream>>>(src, dst, adj);
  k_degree<<<(Bb * N0 + 255) / 256, 256, 0, stream>>>(adj, dis0, dis1);
  k_adjlist<<<Bb * N0, 64, 0, stream>>>(adj, nbr, degv);
  k_gemm128<<<Bb * N0 / 64, 256, 0, stream>>>(x, W1, XW);
  k_conv1<<<Bb * N0, 128, 0, stream>>>(nbr, degv, XW, dis1, b1, h1);
  k_nis1<<<Bb * N0, 128, 0, stream>>>(nbr, degv, h1, dis0, score);
  k_topk<<<Bb, N0, 0, stream>>>(score, perm1, N0, K1);
  k_gather<<<Bb * K1, 128, 0, stream>>>(h1, perm1, att1, Xp1, ar1, ac1, N0, K1);
  k_readout<<<Bb, 1024, 0, stream>>>(Xp1, K1, g, 1);
  k_buildA_bit<<<Bb * K1, K1, 0, stream>>>(adj, perm1, ar1, ac1, A1);  // overwrites XW/h1

  // stage 2: dense A1
  k_prep<<<Bb * K1, K1, 0, stream>>>(A1, K1, disc2, sa2, disn2, diag2);
  k_gemm128<<<Bb * K1 / 64, 256, 0, stream>>>(Xp1, W2, XW2);
  k_mm<<<Bb * (K1 / 64), 256, 0, stream>>>(A1, XW2, disc2, T, K1);
  k_conv_epi<<<Bb * K1, 128, 0, stream>>>(T, XW2, disc2, sa2, b2, h2);
  k_mm<<<Bb * (K1 / 64), 256, 0, stream>>>(A1, h2, disn2, T, K1);
  k_nis_epi<<<Bb * K1, 128, 0, stream>>>(h2, T, disn2, diag2, score);
  k_topk<<<Bb, K1, 0, stream>>>(score, perm2, K1, K2);
  k_gather<<<Bb * K2, 128, 0, stream>>>(h2, perm2, att2, Xp2, ar2, ac2, K1, K2);
  k_readout<<<Bb, 1024, 0, stream>>>(Xp2, K2, g, 0);
  k_buildA_dense<<<Bb * K2, K2, 0, stream>>>(A1, perm2, ar2, ac2, A2);  // overwrites Xp1

  // stage 3: dense A2
  k_prep<<<Bb * K2, K2, 0, stream>>>(A2, K2, disc3, sa3, disn3, diag3);
  k_gemm128<<<Bb * K2 / 64, 256, 0, stream>>>(Xp2, W3, XW3);           // overwrites A1 region
  k_mm<<<Bb * (K2 / 64), 256, 0, stream>>>(A2, XW3, disc3, T, K2);
  k_conv_epi<<<Bb * K2, 128, 0, stream>>>(T, XW3, disc3, sa3, b3, h3);
  k_readout<<<Bb, 1024, 0, stream>>>(h3, K2, g, 0);

  // head
  k_xskew<<<Bb, 128, 0, stream>>>(skew, Wsk, bsk, g);
  k_mlp1<<<Bb, 128, 0, stream>>>(g, Wl1, bl1, t1);
  k_mlp2<<<Bb, 64, 0, stream>>>(t1, Wl2, bl2, t2);
  k_mlp3<<<Bb, 64, 0, stream>>>(t2, Wl3, bl3, out);
}

// Round 5
// 578.300 us; speedup vs baseline: 1.9640x; 1.1543x over previous
//
#include <hip/hip_runtime.h>
#include <math.h>

#define Bb 64
#define N0 1024
#define NE 16384
#define Fd 128
#define K1 512
#define K2 256

__device__ __forceinline__ float wred_sum(float v) {
#pragma unroll
  for (int o = 32; o > 0; o >>= 1) v += __shfl_down(v, o, 64);
  return v;
}
__device__ __forceinline__ float wred_max(float v) {
#pragma unroll
  for (int o = 32; o > 0; o >>= 1) v = fmaxf(v, __shfl_down(v, o, 64));
  return v;
}

// ---- build binary adjacency as bitmask: adj[b][i] = 32 words of row bits ----
__global__ void k_scatter(const int* __restrict__ src, const int* __restrict__ dst,
                          unsigned* __restrict__ adj) {
  int idx = blockIdx.x * 256 + threadIdx.x;
  if (idx >= Bb * NE) return;
  int b = idx >> 14, e = idx & (NE - 1);
  int u = src[b * NE + e], v = dst[b * NE + e];
  if (u == v) return;
  atomicOr(&adj[((b << 10) + u) * 32 + (v >> 5)], 1u << (v & 31));
  atomicOr(&adj[((b << 10) + v) * 32 + (u >> 5)], 1u << (u & 31));
}

__global__ void k_degree(const unsigned* __restrict__ adj, float* __restrict__ dis0,
                         float* __restrict__ dis1) {
  int row = blockIdx.x * 256 + threadIdx.x;
  if (row >= Bb * N0) return;
  int d = 0;
  const unsigned* w = adj + (size_t)row * 32;
#pragma unroll
  for (int i = 0; i < 32; ++i) d += __popc(w[i]);
  dis0[row] = d > 0 ? rsqrtf((float)d) : 0.f;
  dis1[row] = rsqrtf((float)(d + 1));
}

// ---- one-time bitmask -> neighbor-list decode (padded cap 128/row) ----
__global__ __launch_bounds__(64) void k_adjlist(const unsigned* __restrict__ adj,
    int* __restrict__ nbr, int* __restrict__ degv) {
  __shared__ unsigned wbuf[32];
  __shared__ int boff[32];
  int row = blockIdx.x, t = threadIdx.x;
  if (t < 32) wbuf[t] = adj[(size_t)row * 32 + t];
  __syncthreads();
  if (t == 0) {
    int s = 0;
#pragma unroll
    for (int w = 0; w < 32; ++w) { boff[w] = s; s += __popc(wbuf[w]); }
    degv[row] = s;
  }
  __syncthreads();
  if (t < 32) {
    unsigned m = wbuf[t];
    int o = boff[t];
    int bas = t << 5;
    int* dstp = nbr + (size_t)row * 128;
    while (m) { int j = bas + __ffs(m) - 1; m &= m - 1; dstp[o++] = j; }
  }
}

// ---- C[M,128] = X[M,128] @ W[128,128], M % 64 == 0, grid = M/64, block 256 ----
__global__ __launch_bounds__(256) void k_gemm128(const float* __restrict__ X,
                                                 const float* __restrict__ W,
                                                 float* __restrict__ C) {
  __shared__ float Xs[64][132];
  __shared__ float Ws[32][132];
  int t = threadIdx.x;
  size_t row0 = (size_t)blockIdx.x * 64;
  const float4* Xg = (const float4*)(X + row0 * Fd);
#pragma unroll
  for (int i = 0; i < 8; ++i) {
    int f4 = t + 256 * i;
    float4 v = Xg[f4];
    *(float4*)&Xs[f4 >> 5][(f4 & 31) * 4] = v;
  }
  int r0 = (t >> 5) * 8, c0 = (t & 31) * 4;
  float acc[8][4] = {};
  for (int kb = 0; kb < 128; kb += 32) {
    __syncthreads();
#pragma unroll
    for (int i = 0; i < 4; ++i) {
      int f4 = t + 256 * i;
      float4 v = ((const float4*)(W + (size_t)kb * Fd))[f4];
      *(float4*)&Ws[f4 >> 5][(f4 & 31) * 4] = v;
    }
    __syncthreads();
#pragma unroll
    for (int k = 0; k < 32; ++k) {
      float4 wv = *(const float4*)&Ws[k][c0];
#pragma unroll
      for (int i = 0; i < 8; ++i) {
        float xv = Xs[r0 + i][kb + k];
        acc[i][0] += xv * wv.x; acc[i][1] += xv * wv.y;
        acc[i][2] += xv * wv.z; acc[i][3] += xv * wv.w;
      }
    }
  }
#pragma unroll
  for (int i = 0; i < 8; ++i) {
    float4 o = make_float4(acc[i][0], acc[i][1], acc[i][2], acc[i][3]);
    *(float4*)&C[(row0 + r0 + i) * Fd + c0] = o;
  }
}

// ---- gather-accumulate with 8 loads in flight ----
__device__ __forceinline__ float gather8(const float* __restrict__ srcb,
                                         const int* idxs, const float* wts,
                                         int deg, int f) {
  float acc = 0.f;
  int dp = (deg + 7) & ~7;
  for (int i = 0; i < dp; i += 8) {
    int jj[8]; float ww[8], vv[8];
#pragma unroll
    for (int u = 0; u < 8; ++u) { jj[u] = idxs[i + u]; ww[u] = wts[i + u]; }
#pragma unroll
    for (int u = 0; u < 8; ++u) vv[u] = srcb[(size_t)jj[u] * Fd + f];
#pragma unroll
    for (int u = 0; u < 8; ++u) acc += ww[u] * vv[u];
  }
  return acc;
}

// XCD-grouped row swizzle: blocks with bid%8==c -> XCD c -> graphs [c*8, c*8+8)
__device__ __forceinline__ int swz_row(int bid) {
  int c = bid & 7, q = bid >> 3;
  return (((c << 3) + (q >> 10)) << 10) + (q & 1023);
}

// ---- conv1: h1 = relu(dis1_i*(sum_{j in N(i)} dis1_j XW_j + dis1_i XW_i) + b1) ----
__global__ __launch_bounds__(128) void k_conv1(const int* __restrict__ nbr,
    const int* __restrict__ degv, const float* __restrict__ XW,
    const float* __restrict__ dis1, const float* __restrict__ b1, float* __restrict__ h1) {
  __shared__ int idxs[128];
  __shared__ float wts[128];
  int row = swz_row(blockIdx.x), f = threadIdx.x;
  int base = row & ~(N0 - 1);
  int deg = degv[row];
  int li = (f < deg) ? nbr[(size_t)row * 128 + f] : 0;
  idxs[f] = li;
  wts[f] = (f < deg) ? dis1[base + li] : 0.f;
  __syncthreads();
  float di = dis1[row];
  float acc = gather8(XW + (size_t)base * Fd, idxs, wts, deg, f);
  acc += di * XW[(size_t)row * Fd + f];
  h1[(size_t)row * Fd + f] = fmaxf(di * acc + b1[f], 0.f);
}

// ---- NIS on binary A: score_i = sum_f |h_i - dis0_i * sum_j dis0_j h_j| ----
__global__ __launch_bounds__(128) void k_nis1(const int* __restrict__ nbr,
    const int* __restrict__ degv, const float* __restrict__ h,
    const float* __restrict__ dis0, float* __restrict__ score) {
  __shared__ int idxs[128];
  __shared__ float wts[128];
  __shared__ float red[2];
  int row = swz_row(blockIdx.x), f = threadIdx.x;
  int base = row & ~(N0 - 1);
  int deg = degv[row];
  int li = (f < deg) ? nbr[(size_t)row * 128 + f] : 0;
  idxs[f] = li;
  wts[f] = (f < deg) ? dis0[base + li] : 0.f;
  __syncthreads();
  float acc = gather8(h + (size_t)base * Fd, idxs, wts, deg, f);
  float val = h[(size_t)row * Fd + f] - dis0[row] * acc;
  float p = wred_sum(fabsf(val));
  if ((f & 63) == 0) red[f >> 6] = p;
  __syncthreads();
  if (f == 0) score[row] = red[0] + red[1];
}

// ---- exact top-k per graph: bitonic sort of (score,idx) packed u64 keys ----
__global__ __launch_bounds__(1024) void k_topk(const float* __restrict__ score,
                                               int* __restrict__ perm, int n, int k) {
  __shared__ unsigned long long keys[1024];
  int b = blockIdx.x, t = threadIdx.x;
  float s = score[b * n + t];
  unsigned ub = __float_as_uint(s);
  unsigned su = (ub & 0x80000000u) ? ~ub : (ub | 0x80000000u);  // monotone map
  keys[t] = ((unsigned long long)(~su) << 32) | (unsigned)t;    // asc sort = desc score, asc idx
  __syncthreads();
  for (int kk = 2; kk <= n; kk <<= 1) {
    for (int j = kk >> 1; j > 0; j >>= 1) {
      int ixj = t ^ j;
      if (ixj > t) {
        unsigned long long a = keys[t], c = keys[ixj];
        bool up = ((t & kk) == 0);
        if ((a > c) == up) { keys[t] = c; keys[ixj] = a; }
      }
      __syncthreads();
    }
  }
  if (t < k) perm[b * k + t] = (int)(keys[t] & 0xffffffffu);
}

// ---- gather pooled rows + attention dots ----
__global__ __launch_bounds__(128) void k_gather(const float* __restrict__ h,
    const int* __restrict__ perm, const float* __restrict__ att, float* __restrict__ Xp,
    float* __restrict__ ar, float* __restrict__ ac, int n, int k) {
  int idx = blockIdx.x, f = threadIdx.x;
  int b = idx / k;
  __shared__ float red[4];
  int p = perm[idx];
  float v = h[((size_t)b * n + p) * Fd + f];
  Xp[(size_t)idx * Fd + f] = v;
  float r1 = wred_sum(v * att[f]);
  float r2 = wred_sum(v * att[Fd + f]);
  if ((f & 63) == 0) { red[f >> 6] = r1; red[2 + (f >> 6)] = r2; }
  __syncthreads();
  if (f == 0) { ar[idx] = red[0] + red[1]; ac[idx] = red[2] + red[3]; }
}

// ---- readout: g[b][0:128] (+)= relu(max), g[b][128:256] (+)= relu(mean) ----
__global__ __launch_bounds__(1024) void k_readout(const float* __restrict__ X, int n,
                                                  float* __restrict__ g, int init) {
  int b = blockIdx.x, t = threadIdx.x;
  int f = t & 127, rs = t >> 7;
  __shared__ float smax[8][128];
  __shared__ float ssum[8][128];
  int per = n >> 3;
  const float* Xs = X + ((size_t)b * n + (size_t)rs * per) * Fd + f;
  float mx = -3.0e38f, sm = 0.f;
  for (int j = 0; j < per; j += 8) {
    float vv[8];
#pragma unroll
    for (int u = 0; u < 8; ++u) vv[u] = Xs[(size_t)(j + u) * Fd];
#pragma unroll
    for (int u = 0; u < 8; ++u) { mx = fmaxf(mx, vv[u]); sm += vv[u]; }
  }
  smax[rs][f] = mx; ssum[rs][f] = sm;
  __syncthreads();
  if (t < 128) {
    float m = smax[0][f], s = ssum[0][f];
#pragma unroll
    for (int q = 1; q < 8; ++q) { m = fmaxf(m, smax[q][f]); s += ssum[q][f]; }
    float a = fmaxf(m, 0.f);
    float m2 = fmaxf(s / (float)n, 0.f);
    if (init) { g[b * 384 + f] = a; g[b * 384 + 128 + f] = m2; }
    else      { g[b * 384 + f] += a; g[b * 384 + 128 + f] += m2; }
  }
}

// ---- A1 = softmax_row(leakyrelu(ar_i+ac_j) + bit(pi,pj)) + row stats ----
__global__ __launch_bounds__(512) void k_buildA_bit(const unsigned* __restrict__ adj,
    const int* __restrict__ perm, const float* __restrict__ ar, const float* __restrict__ ac,
    float* __restrict__ A, float* __restrict__ disc, float* __restrict__ saO,
    float* __restrict__ disn, float* __restrict__ diagO) {
  int bi = blockIdx.x;
  int b = bi >> 9, i = bi & (K1 - 1), j = threadIdx.x;
  __shared__ float redA[8], redB[8], redC[8];
  __shared__ float dsh;
  int pi = perm[(b << 9) + i];
  int pj = perm[(b << 9) + j];
  float x = ar[(b << 9) + i] + ac[(b << 9) + j];
  x = x > 0.f ? x : 0.2f * x;
  unsigned word = adj[(size_t)((b << 10) + pi) * 32 + (pj >> 5)];
  x += (float)((word >> (pj & 31)) & 1u);
  int lane = j & 63, w = j >> 6;
  float m = wred_max(x);
  if (lane == 0) redA[w] = m;
  __syncthreads();
  m = redA[0];
#pragma unroll
  for (int q = 1; q < 8; ++q) m = fmaxf(m, redA[q]);
  float e = expf(x - m);
  float s = wred_sum(e);
  if (lane == 0) redB[w] = s;
  __syncthreads();
  s = redB[0];
#pragma unroll
  for (int q = 1; q < 8; ++q) s += redB[q];
  float av = e / s;
  int row = (b << 9) + i;
  A[(size_t)row * K1 + j] = av;
  float rsw = wred_sum(av);
  if (lane == 0) redC[w] = rsw;
  if (j == i) dsh = av;
  __syncthreads();
  if (j == 0) {
    float rs = redC[0];
#pragma unroll
    for (int q = 1; q < 8; ++q) rs += redC[q];
    float dg = dsh;
    float sav = (dg == 0.f) ? 1.f : 0.f;
    float deg = rs + sav;
    disc[row] = deg > 0.f ? rsqrtf(deg) : 0.f;
    saO[row] = sav;
    float deg0 = rs - dg;
    disn[row] = deg0 > 0.f ? rsqrtf(deg0) : 0.f;
    diagO[row] = dg;
  }
}

// ---- A2 = softmax_row(leakyrelu(ar_i+ac_j) + A1[pi,pj]) + row stats ----
__global__ __launch_bounds__(256) void k_buildA_dense(const float* __restrict__ Aprev,
    const int* __restrict__ perm, const float* __restrict__ ar, const float* __restrict__ ac,
    float* __restrict__ A, float* __restrict__ disc, float* __restrict__ saO,
    float* __restrict__ disn, float* __restrict__ diagO) {
  int bi = blockIdx.x;
  int b = bi >> 8, i = bi & (K2 - 1), j = threadIdx.x;
  __shared__ float redA[4], redB[4], redC[4];
  __shared__ float dsh;
  int pi = perm[(b << 8) + i];
  int pj = perm[(b << 8) + j];
  float x = ar[(b << 8) + i] + ac[(b << 8) + j];
  x = x > 0.f ? x : 0.2f * x;
  x += Aprev[((size_t)(b << 9) + pi) * K1 + pj];
  int lane = j & 63, w = j >> 6;
  float m = wred_max(x);
  if (lane == 0) redA[w] = m;
  __syncthreads();
  m = redA[0];
#pragma unroll
  for (int q = 1; q < 4; ++q) m = fmaxf(m, redA[q]);
  float e = expf(x - m);
  float s = wred_sum(e);
  if (lane == 0) redB[w] = s;
  __syncthreads();
  s = redB[0];
#pragma unroll
  for (int q = 1; q < 4; ++q) s += redB[q];
  float av = e / s;
  int row = (b << 8) + i;
  A[(size_t)row * K2 + j] = av;
  float rsw = wred_sum(av);
  if (lane == 0) redC[w] = rsw;
  if (j == i) dsh = av;
  __syncthreads();
  if (j == 0) {
    float rs = redC[0];
#pragma unroll
    for (int q = 1; q < 4; ++q) rs += redC[q];
    float dg = dsh;
    float sav = (dg == 0.f) ? 1.f : 0.f;
    float deg = rs + sav;
    disc[row] = deg > 0.f ? rsqrtf(deg) : 0.f;
    saO[row] = sav;
    float deg0 = rs - dg;
    disn[row] = deg0 > 0.f ? rsqrtf(deg0) : 0.f;
    diagO[row] = dg;
  }
}

// ---- fused dense mm: out = epilogue(A[b] @ diag(wrow) Y[b]) ----
// 512 threads = 2 split-K groups of 256; BM=64, BN=128 (full).
// MODE 0 (conv): h = relu(dc*(acc + sa*dc*Y) + bias)
// MODE 1 (nis):  score = sum_f |hv - dn*(acc - diag*dn*hv)|, Y == h
template <int MODE>
__global__ __launch_bounds__(512) void k_mmf(const float* __restrict__ A,
    const float* __restrict__ Y, const float* __restrict__ wrow,
    const float* __restrict__ aux, const float* __restrict__ bias,
    float* __restrict__ outp, int n) {
  __shared__ float smem[13056];  // As[2][64][36] @0, Ys[2][32][132] @4608
  int t = threadIdx.x;
  int kg = t >> 8, tt = t & 255;
  int tiles = n >> 6;
  int bid = blockIdx.x;
  int c = bid & 7, q = bid >> 3;
  int g = c * 8 + q / tiles;     // graph (8 graphs per XCD)
  int rt = q % tiles;            // row tile
  const float* Ab = A + (size_t)g * n * n + (size_t)(rt * 64) * n;
  const float* Yb = Y + (size_t)g * n * Fd;
  const float* wb = wrow + (size_t)g * n;
  int r0 = (tt >> 4) * 4, c0 = (tt & 15) * 4;
  float acc[4][8] = {};
  int kbase = kg * (n >> 1);
  float* Asg = smem + kg * 2304;
  float* Ysg = smem + 4608 + kg * 4224;
  for (int kb = 0; kb < (n >> 1); kb += 32) {
    int kglob = kbase + kb;
    __syncthreads();
#pragma unroll
    for (int ii = 0; ii < 2; ++ii) {
      int f4 = tt + 256 * ii;
      int r = f4 >> 3, c4 = (f4 & 7) * 4;
      *(float4*)&Asg[r * 36 + c4] = *(const float4*)&Ab[(size_t)r * n + kglob + c4];
    }
#pragma unroll
    for (int ii = 0; ii < 4; ++ii) {
      int f4 = tt + 256 * ii;
      int r = f4 >> 5, c4 = (f4 & 31) * 4;
      float4 v = *(const float4*)&Yb[(size_t)(kglob + r) * Fd + c4];
      float sc = wb[kglob + r];
      v.x *= sc; v.y *= sc; v.z *= sc; v.w *= sc;
      *(float4*)&Ysg[r * 132 + c4] = v;
    }
    __syncthreads();
#pragma unroll
    for (int k4 = 0; k4 < 8; ++k4) {
      float a_[4][4];
#pragma unroll
      for (int i = 0; i < 4; ++i)
        *(float4*)a_[i] = *(const float4*)&Asg[(r0 + i) * 36 + k4 * 4];
#pragma unroll
      for (int kk = 0; kk < 4; ++kk) {
        float4 y0 = *(const float4*)&Ysg[(k4 * 4 + kk) * 132 + c0];
        float4 y1 = *(const float4*)&Ysg[(k4 * 4 + kk) * 132 + c0 + 64];
#pragma unroll
        for (int i = 0; i < 4; ++i) {
          float av = a_[i][kk];
          acc[i][0] += av * y0.x; acc[i][1] += av * y0.y;
          acc[i][2] += av * y0.z; acc[i][3] += av * y0.w;
          acc[i][4] += av * y1.x; acc[i][5] += av * y1.y;
          acc[i][6] += av * y1.z; acc[i][7] += av * y1.w;
        }
      }
    }
  }
  // merge split-K partials: group 1 -> LDS -> group 0
  float* mrg = smem + 4608;  // 8448-float region, need 8192
  __syncthreads();
  if (kg == 1) {
#pragma unroll
    for (int i = 0; i < 4; ++i) {
      *(float4*)&mrg[(r0 + i) * 128 + c0]      = *(float4*)&acc[i][0];
      *(float4*)&mrg[(r0 + i) * 128 + c0 + 64] = *(float4*)&acc[i][4];
    }
  }
  __syncthreads();
  if (kg == 0) {
#pragma unroll
    for (int i = 0; i < 4; ++i) {
      float4 m0 = *(float4*)&mrg[(r0 + i) * 128 + c0];
      float4 m1 = *(float4*)&mrg[(r0 + i) * 128 + c0 + 64];
      acc[i][0] += m0.x; acc[i][1] += m0.y; acc[i][2] += m0.z; acc[i][3] += m0.w;
      acc[i][4] += m1.x; acc[i][5] += m1.y; acc[i][6] += m1.z; acc[i][7] += m1.w;
    }
    if (MODE == 0) {
      float4 bv0 = *(const float4*)&bias[c0];
      float4 bv1 = *(const float4*)&bias[c0 + 64];
#pragma unroll
      for (int i = 0; i < 4; ++i) {
        int rl = rt * 64 + r0 + i;
        size_t R = (size_t)g * n + rl;
        float dc = wb[rl];
        float sv = aux[R] * dc;
        float4 y0 = *(const float4*)&Y[R * Fd + c0];
        float4 y1 = *(const float4*)&Y[R * Fd + c0 + 64];
        float4 o0, o1;
        o0.x = fmaxf(dc * (acc[i][0] + sv * y0.x) + bv0.x, 0.f);
        o0.y = fmaxf(dc * (acc[i][1] + sv * y0.y) + bv0.y, 0.f);
        o0.z = fmaxf(dc * (acc[i][2] + sv * y0.z) + bv0.z, 0.f);
        o0.w = fmaxf(dc * (acc[i][3] + sv * y0.w) + bv0.w, 0.f);
        o1.x = fmaxf(dc * (acc[i][4] + sv * y1.x) + bv1.x, 0.f);
        o1.y = fmaxf(dc * (acc[i][5] + sv * y1.y) + bv1.y, 0.f);
        o1.z = fmaxf(dc * (acc[i][6] + sv * y1.z) + bv1.z, 0.f);
        o1.w = fmaxf(dc * (acc[i][7] + sv * y1.w) + bv1.w, 0.f);
        *(float4*)&outp[R * Fd + c0]      = o0;
        *(float4*)&outp[R * Fd + c0 + 64] = o1;
      }
    } else {
      float* rowred = smem;  // [64][16] floats
#pragma unroll
      for (int i = 0; i < 4; ++i) {
        int rl = rt * 64 + r0 + i;
        size_t R = (size_t)g * n + rl;
        float dn = wb[rl];
        float dg = aux[R] * dn;
        float4 h0 = *(const float4*)&Y[R * Fd + c0];
        float4 h1 = *(const float4*)&Y[R * Fd + c0 + 64];
        float p = 0.f;
        p += fabsf(h0.x - dn * (acc[i][0] - dg * h0.x));
        p += fabsf(h0.y - dn * (acc[i][1] - dg * h0.y));
        p += fabsf(h0.z - dn * (acc[i][2] - dg * h0.z));
        p += fabsf(h0.w - dn * (acc[i][3] - dg * h0.w));
        p += fabsf(h1.x - dn * (acc[i][4] - dg * h1.x));
        p += fabsf(h1.y - dn * (acc[i][5] - dg * h1.y));
        p += fabsf(h1.z - dn * (acc[i][6] - dg * h1.z));
        p += fabsf(h1.w - dn * (acc[i][7] - dg * h1.w));
        rowred[(r0 + i) * 16 + (tt & 15)] = p;
      }
    }
  }
  if (MODE == 1) {
    __syncthreads();
    if (t < 64) {
      float s = 0.f;
#pragma unroll
      for (int qq = 0; qq < 16; ++qq) s += smem[t * 16 + qq];
      outp[(size_t)g * n + rt * 64 + t] = s;
    }
  }
}

__global__ __launch_bounds__(128) void k_xskew(const float* __restrict__ skew,
    const float* __restrict__ Wsk, const float* __restrict__ bsk, float* __restrict__ g) {
  int b = blockIdx.x, f = threadIdx.x;
  float acc = bsk[f];
  for (int s = 0; s < 64; ++s) acc += skew[b * 64 + s] * Wsk[s * Fd + f];
  g[b * 384 + 256 + f] = fmaxf(acc, 0.f);
}

__global__ __launch_bounds__(128) void k_mlp1(const float* __restrict__ g,
    const float* __restrict__ Wl, const float* __restrict__ bl, float* __restrict__ o) {
  int b = blockIdx.x, f = threadIdx.x;
  float acc = bl[f];
  for (int s = 0; s < 384; ++s) acc += g[b * 384 + s] * Wl[s * 128 + f];
  o[b * 128 + f] = fmaxf(acc, 0.f);
}
__global__ __launch_bounds__(64) void k_mlp2(const float* __restrict__ x,
    const float* __restrict__ Wl, const float* __restrict__ bl, float* __restrict__ o) {
  int b = blockIdx.x, f = threadIdx.x;
  float acc = bl[f];
  for (int s = 0; s < 128; ++s) acc += x[b * 128 + s] * Wl[s * 64 + f];
  o[b * 64 + f] = fmaxf(acc, 0.f);
}
__global__ __launch_bounds__(64) void k_mlp3(const float* __restrict__ x,
    const float* __restrict__ Wl, const float* __restrict__ bl, float* __restrict__ out) {
  int b = blockIdx.x, f = threadIdx.x;
  __shared__ float lg[10];
  if (f < 10) {
    float acc = bl[f];
    for (int s = 0; s < 64; ++s) acc += x[b * 64 + s] * Wl[s * 10 + f];
    lg[f] = acc;
  }
  __syncthreads();
  if (f == 0) {
    float m = lg[0];
    for (int c = 1; c < 10; ++c) m = fmaxf(m, lg[c]);
    float s = 0.f;
    for (int c = 0; c < 10; ++c) s += expf(lg[c] - m);
    float l = logf(s);
    for (int c = 0; c < 10; ++c) out[b * 10 + c] = lg[c] - m - l;
  }
}

extern "C" void kernel_launch(void* const* d_in, const int* in_sizes, int n_in,
                              void* d_out, int out_size, void* d_ws, size_t ws_size,
                              hipStream_t stream) {
  const float* x    = (const float*)d_in[0];
  const int*   src  = (const int*)d_in[1];
  const int*   dst  = (const int*)d_in[2];
  const float* skew = (const float*)d_in[3];
  const float* W1   = (const float*)d_in[4];
  const float* b1   = (const float*)d_in[5];
  const float* W2   = (const float*)d_in[6];
  const float* b2   = (const float*)d_in[7];
  const float* W3   = (const float*)d_in[8];
  const float* b3   = (const float*)d_in[9];
  const float* att1 = (const float*)d_in[10];
  const float* att2 = (const float*)d_in[11];
  const float* Wsk  = (const float*)d_in[12];
  const float* bsk  = (const float*)d_in[13];
  const float* Wl1  = (const float*)d_in[14];
  const float* bl1  = (const float*)d_in[15];
  const float* Wl2  = (const float*)d_in[16];
  const float* bl2  = (const float*)d_in[17];
  const float* Wl3  = (const float*)d_in[18];
  const float* bl3  = (const float*)d_in[19];
  float* out = (float*)d_out;

  char* base = (char*)d_ws;
  size_t off = 0;
  auto alloc = [&](size_t bytes) -> void* {
    void* p = base + off;
    off += (bytes + 255) & ~(size_t)255;
    return p;
  };

  unsigned* adj = (unsigned*)alloc((size_t)Bb * N0 * 32 * 4);        // 8 MB
  float* dis0 = (float*)alloc((size_t)Bb * N0 * 4);
  float* dis1 = (float*)alloc((size_t)Bb * N0 * 4);
  int*   degv = (int*)alloc((size_t)Bb * N0 * 4);
  float* bigA = (float*)alloc((size_t)64 * 1024 * 1024);             // 64 MB multi-use
  float* XW  = bigA;                                                  // [B,1024,128]
  float* h1  = bigA + (size_t)Bb * N0 * Fd;                           // [B,1024,128]
  float* A1  = bigA;                                                  // [B,512,512] (after h1 dead)
  float* XW3 = bigA;                                                  // [B,256,128] (after A1 dead)
  float* h3  = bigA + (size_t)Bb * K2 * Fd;                           // [B,256,128]
  float* score = (float*)alloc((size_t)Bb * N0 * 4);
  int*   perm1 = (int*)alloc((size_t)Bb * K1 * 4);
  float* Xp1 = (float*)alloc((size_t)Bb * K1 * Fd * 4);               // later reused as A2
  float* A2  = Xp1;                                                   // [B,256,256] = same bytes
  float* ar1 = (float*)alloc((size_t)Bb * K1 * 4);
  float* ac1 = (float*)alloc((size_t)Bb * K1 * 4);
  float* disc2 = (float*)alloc((size_t)Bb * K1 * 4);
  float* sa2   = (float*)alloc((size_t)Bb * K1 * 4);
  float* disn2 = (float*)alloc((size_t)Bb * K1 * 4);
  float* diag2 = (float*)alloc((size_t)Bb * K1 * 4);
  float* XW2 = (float*)alloc((size_t)Bb * K1 * Fd * 4);               // 16 MB
  float* h2  = (float*)alloc((size_t)Bb * K1 * Fd * 4);               // 16 MB (contiguous w/ XW2)
  int*   perm2 = (int*)alloc((size_t)Bb * K2 * 4);
  float* Xp2 = (float*)alloc((size_t)Bb * K2 * Fd * 4);
  float* ar2 = (float*)alloc((size_t)Bb * K2 * 4);
  float* ac2 = (float*)alloc((size_t)Bb * K2 * 4);
  float* disc3 = (float*)alloc((size_t)Bb * K2 * 4);
  float* sa3   = (float*)alloc((size_t)Bb * K2 * 4);
  float* disn3 = (float*)alloc((size_t)Bb * K2 * 4);
  float* diag3 = (float*)alloc((size_t)Bb * K2 * 4);
  float* g  = (float*)alloc((size_t)Bb * 384 * 4);
  float* t1 = (float*)alloc((size_t)Bb * 128 * 4);
  float* t2 = (float*)alloc((size_t)Bb * 64 * 4);
  // nbr [B*N0][128] ints = 32 MB; overlays XW2+h2 (dead until stage-2 gemm,
  // nbr dead after k_nis1). XW2/h2 are adjacent 16 MB 256-aligned blocks.
  int* nbr = (int*)XW2;
  (void)ws_size; (void)in_sizes; (void)n_in; (void)out_size;

  // stage 1: binary graph
  hipMemsetAsync(adj, 0, (size_t)Bb * N0 * 32 * 4, stream);
  k_scatter<<<(Bb * NE + 255) / 256, 256, 0, stream>>>(src, dst, adj);
  k_degree<<<(Bb * N0 + 255) / 256, 256, 0, stream>>>(adj, dis0, dis1);
  k_adjlist<<<Bb * N0, 64, 0, stream>>>(adj, nbr, degv);
  k_gemm128<<<Bb * N0 / 64, 256, 0, stream>>>(x, W1, XW);
  k_conv1<<<Bb * N0, 128, 0, stream>>>(nbr, degv, XW, dis1, b1, h1);
  k_nis1<<<Bb * N0, 128, 0, stream>>>(nbr, degv, h1, dis0, score);
  k_topk<<<Bb, N0, 0, stream>>>(score, perm1, N0, K1);
  k_gather<<<Bb * K1, 128, 0, stream>>>(h1, perm1, att1, Xp1, ar1, ac1, N0, K1);
  k_readout<<<Bb, 1024, 0, stream>>>(Xp1, K1, g, 1);
  k_buildA_bit<<<Bb * K1, K1, 0, stream>>>(adj, perm1, ar1, ac1, A1,
                                           disc2, sa2, disn2, diag2);  // overwrites XW/h1

  // stage 2: dense A1 (fused mm + epilogues, split-K x2)
  k_gemm128<<<Bb * K1 / 64, 256, 0, stream>>>(Xp1, W2, XW2);
  k_mmf<0><<<Bb * (K1 / 64), 512, 0, stream>>>(A1, XW2, disc2, sa2, b2, h2, K1);
  k_mmf<1><<<Bb * (K1 / 64), 512, 0, stream>>>(A1, h2, disn2, diag2, nullptr, score, K1);
  k_topk<<<Bb, K1, 0, stream>>>(score, perm2, K1, K2);
  k_gather<<<Bb * K2, 128, 0, stream>>>(h2, perm2, att2, Xp2, ar2, ac2, K1, K2);
  k_readout<<<Bb, 1024, 0, stream>>>(Xp2, K2, g, 0);
  k_buildA_dense<<<Bb * K2, K2, 0, stream>>>(A1, perm2, ar2, ac2, A2,
                                             disc3, sa3, disn3, diag3);  // overwrites Xp1

  // stage 3: dense A2
  k_gemm128<<<Bb * K2 / 64, 256, 0, stream>>>(Xp2, W3, XW3);           // overwrites A1 region
  k_mmf<0><<<Bb * (K2 / 64), 512, 0, stream>>>(A2, XW3, disc3, sa3, b3, h3, K2);
  k_readout<<<Bb, 1024, 0, stream>>>(h3, K2, g, 0);

  // head
  k_xskew<<<Bb, 128, 0, stream>>>(skew, Wsk, bsk, g);
  k_mlp1<<<Bb, 128, 0, stream>>>(g, Wl1, bl1, t1);
  k_mlp2<<<Bb, 64, 0, stream>>>(t1, Wl2, bl2, t2);
  k_mlp3<<<Bb, 64, 0, stream>>>(t2, Wl3, bl3, out);
}

// Round 6
// 518.762 us; speedup vs baseline: 2.1894x; 1.1148x over previous
//
#include <hip/hip_runtime.h>
#include <math.h>

#define Bb 64
#define N0 1024
#define NE 16384
#define Fd 128
#define K1 512
#define K2 256

__device__ __forceinline__ float wred_sum(float v) {
#pragma unroll
  for (int o = 32; o > 0; o >>= 1) v += __shfl_down(v, o, 64);
  return v;
}
__device__ __forceinline__ float wred_max(float v) {
#pragma unroll
  for (int o = 32; o > 0; o >>= 1) v = fmaxf(v, __shfl_down(v, o, 64));
  return v;
}
__device__ __forceinline__ float wred_sum_all(float v) {
#pragma unroll
  for (int o = 32; o > 0; o >>= 1) v += __shfl_xor(v, o, 64);
  return v;
}
__device__ __forceinline__ float wred_max_all(float v) {
#pragma unroll
  for (int o = 32; o > 0; o >>= 1) v = fmaxf(v, __shfl_xor(v, o, 64));
  return v;
}

// ---- build binary adjacency as bitmask: adj[b][i] = 32 words of row bits ----
__global__ void k_scatter(const int* __restrict__ src, const int* __restrict__ dst,
                          unsigned* __restrict__ adj) {
  int idx = blockIdx.x * 256 + threadIdx.x;
  if (idx >= Bb * NE) return;
  int b = idx >> 14, e = idx & (NE - 1);
  int u = src[b * NE + e], v = dst[b * NE + e];
  if (u == v) return;
  atomicOr(&adj[((b << 10) + u) * 32 + (v >> 5)], 1u << (v & 31));
  atomicOr(&adj[((b << 10) + v) * 32 + (u >> 5)], 1u << (u & 31));
}

__global__ void k_degree(const unsigned* __restrict__ adj, float* __restrict__ dis0,
                         float* __restrict__ dis1) {
  int row = blockIdx.x * 256 + threadIdx.x;
  if (row >= Bb * N0) return;
  int d = 0;
  const unsigned* w = adj + (size_t)row * 32;
#pragma unroll
  for (int i = 0; i < 32; ++i) d += __popc(w[i]);
  dis0[row] = d > 0 ? rsqrtf((float)d) : 0.f;
  dis1[row] = rsqrtf((float)(d + 1));
}

// ---- one-time bitmask -> neighbor-list decode (padded cap 128/row) ----
__global__ __launch_bounds__(64) void k_adjlist(const unsigned* __restrict__ adj,
    int* __restrict__ nbr, int* __restrict__ degv) {
  __shared__ unsigned wbuf[32];
  __shared__ int boff[32];
  int row = blockIdx.x, t = threadIdx.x;
  if (t < 32) wbuf[t] = adj[(size_t)row * 32 + t];
  __syncthreads();
  if (t == 0) {
    int s = 0;
#pragma unroll
    for (int w = 0; w < 32; ++w) { boff[w] = s; s += __popc(wbuf[w]); }
    degv[row] = s;
  }
  __syncthreads();
  if (t < 32) {
    unsigned m = wbuf[t];
    int o = boff[t];
    int bas = t << 5;
    int* dstp = nbr + (size_t)row * 128;
    while (m) { int j = bas + __ffs(m) - 1; m &= m - 1; dstp[o++] = j; }
  }
}

// ---- C[M,128] = X[M,128] @ W[128,128], M % 64 == 0, grid = M/64, block 256 ----
__global__ __launch_bounds__(256) void k_gemm128(const float* __restrict__ X,
                                                 const float* __restrict__ W,
                                                 float* __restrict__ C) {
  __shared__ float Xs[64][132];
  __shared__ float Ws[32][132];
  int t = threadIdx.x;
  size_t row0 = (size_t)blockIdx.x * 64;
  const float4* Xg = (const float4*)(X + row0 * Fd);
#pragma unroll
  for (int i = 0; i < 8; ++i) {
    int f4 = t + 256 * i;
    float4 v = Xg[f4];
    *(float4*)&Xs[f4 >> 5][(f4 & 31) * 4] = v;
  }
  int r0 = (t >> 5) * 8, c0 = (t & 31) * 4;
  float acc[8][4] = {};
  for (int kb = 0; kb < 128; kb += 32) {
    __syncthreads();
#pragma unroll
    for (int i = 0; i < 4; ++i) {
      int f4 = t + 256 * i;
      float4 v = ((const float4*)(W + (size_t)kb * Fd))[f4];
      *(float4*)&Ws[f4 >> 5][(f4 & 31) * 4] = v;
    }
    __syncthreads();
#pragma unroll
    for (int k = 0; k < 32; ++k) {
      float4 wv = *(const float4*)&Ws[k][c0];
#pragma unroll
      for (int i = 0; i < 8; ++i) {
        float xv = Xs[r0 + i][kb + k];
        acc[i][0] += xv * wv.x; acc[i][1] += xv * wv.y;
        acc[i][2] += xv * wv.z; acc[i][3] += xv * wv.w;
      }
    }
  }
#pragma unroll
  for (int i = 0; i < 8; ++i) {
    float4 o = make_float4(acc[i][0], acc[i][1], acc[i][2], acc[i][3]);
    *(float4*)&C[(row0 + r0 + i) * Fd + c0] = o;
  }
}

// ---- gather-accumulate with 8 loads in flight ----
__device__ __forceinline__ float gather8(const float* __restrict__ srcb,
                                         const int* idxs, const float* wts,
                                         int deg, int f) {
  float acc = 0.f;
  int dp = (deg + 7) & ~7;
  for (int i = 0; i < dp; i += 8) {
    int jj[8]; float ww[8], vv[8];
#pragma unroll
    for (int u = 0; u < 8; ++u) { jj[u] = idxs[i + u]; ww[u] = wts[i + u]; }
#pragma unroll
    for (int u = 0; u < 8; ++u) vv[u] = srcb[(size_t)jj[u] * Fd + f];
#pragma unroll
    for (int u = 0; u < 8; ++u) acc += ww[u] * vv[u];
  }
  return acc;
}

// XCD-grouped row swizzle: blocks with bid%8==c -> XCD c -> graphs [c*8, c*8+8)
__device__ __forceinline__ int swz_row(int bid) {
  int c = bid & 7, q = bid >> 3;
  return (((c << 3) + (q >> 10)) << 10) + (q & 1023);
}

// ---- conv1: h1 = relu(dis1_i*(sum_{j in N(i)} dis1_j XW_j + dis1_i XW_i) + b1) ----
__global__ __launch_bounds__(128) void k_conv1(const int* __restrict__ nbr,
    const int* __restrict__ degv, const float* __restrict__ XW,
    const float* __restrict__ dis1, const float* __restrict__ b1, float* __restrict__ h1) {
  __shared__ int idxs[128];
  __shared__ float wts[128];
  int row = swz_row(blockIdx.x), f = threadIdx.x;
  int base = row & ~(N0 - 1);
  int deg = degv[row];
  int li = (f < deg) ? nbr[(size_t)row * 128 + f] : 0;
  idxs[f] = li;
  wts[f] = (f < deg) ? dis1[base + li] : 0.f;
  __syncthreads();
  float di = dis1[row];
  float acc = gather8(XW + (size_t)base * Fd, idxs, wts, deg, f);
  acc += di * XW[(size_t)row * Fd + f];
  h1[(size_t)row * Fd + f] = fmaxf(di * acc + b1[f], 0.f);
}

// ---- NIS on binary A: score_i = sum_f |h_i - dis0_i * sum_j dis0_j h_j| ----
__global__ __launch_bounds__(128) void k_nis1(const int* __restrict__ nbr,
    const int* __restrict__ degv, const float* __restrict__ h,
    const float* __restrict__ dis0, float* __restrict__ score) {
  __shared__ int idxs[128];
  __shared__ float wts[128];
  __shared__ float red[2];
  int row = swz_row(blockIdx.x), f = threadIdx.x;
  int base = row & ~(N0 - 1);
  int deg = degv[row];
  int li = (f < deg) ? nbr[(size_t)row * 128 + f] : 0;
  idxs[f] = li;
  wts[f] = (f < deg) ? dis0[base + li] : 0.f;
  __syncthreads();
  float acc = gather8(h + (size_t)base * Fd, idxs, wts, deg, f);
  float val = h[(size_t)row * Fd + f] - dis0[row] * acc;
  float p = wred_sum(fabsf(val));
  if ((f & 63) == 0) red[f >> 6] = p;
  __syncthreads();
  if (f == 0) score[row] = red[0] + red[1];
}

// ---- exact top-k per graph: bitonic sort of (score,idx) packed u64 keys ----
__global__ __launch_bounds__(1024) void k_topk(const float* __restrict__ score,
                                               int* __restrict__ perm, int n, int k) {
  __shared__ unsigned long long keys[1024];
  int b = blockIdx.x, t = threadIdx.x;
  float s = score[b * n + t];
  unsigned ub = __float_as_uint(s);
  unsigned su = (ub & 0x80000000u) ? ~ub : (ub | 0x80000000u);  // monotone map
  keys[t] = ((unsigned long long)(~su) << 32) | (unsigned)t;    // asc sort = desc score, asc idx
  __syncthreads();
  for (int kk = 2; kk <= n; kk <<= 1) {
    for (int j = kk >> 1; j > 0; j >>= 1) {
      int ixj = t ^ j;
      if (ixj > t) {
        unsigned long long a = keys[t], c = keys[ixj];
        bool up = ((t & kk) == 0);
        if ((a > c) == up) { keys[t] = c; keys[ixj] = a; }
      }
      __syncthreads();
    }
  }
  if (t < k) perm[b * k + t] = (int)(keys[t] & 0xffffffffu);
}

// ---- gather pooled rows + attention dots ----
__global__ __launch_bounds__(128) void k_gather(const float* __restrict__ h,
    const int* __restrict__ perm, const float* __restrict__ att, float* __restrict__ Xp,
    float* __restrict__ ar, float* __restrict__ ac, int n, int k) {
  int idx = blockIdx.x, f = threadIdx.x;
  int b = idx / k;
  __shared__ float red[4];
  int p = perm[idx];
  float v = h[((size_t)b * n + p) * Fd + f];
  Xp[(size_t)idx * Fd + f] = v;
  float r1 = wred_sum(v * att[f]);
  float r2 = wred_sum(v * att[Fd + f]);
  if ((f & 63) == 0) { red[f >> 6] = r1; red[2 + (f >> 6)] = r2; }
  __syncthreads();
  if (f == 0) { ar[idx] = red[0] + red[1]; ac[idx] = red[2] + red[3]; }
}

// ---- readout: g[b][0:128] (+)= relu(max), g[b][128:256] (+)= relu(mean) ----
__global__ __launch_bounds__(1024) void k_readout(const float* __restrict__ X, int n,
                                                  float* __restrict__ g, int init) {
  int b = blockIdx.x, t = threadIdx.x;
  int f = t & 127, rs = t >> 7;
  __shared__ float smax[8][128];
  __shared__ float ssum[8][128];
  int per = n >> 3;
  const float* Xs = X + ((size_t)b * n + (size_t)rs * per) * Fd + f;
  float mx = -3.0e38f, sm = 0.f;
  for (int j = 0; j < per; j += 8) {
    float vv[8];
#pragma unroll
    for (int u = 0; u < 8; ++u) vv[u] = Xs[(size_t)(j + u) * Fd];
#pragma unroll
    for (int u = 0; u < 8; ++u) { mx = fmaxf(mx, vv[u]); sm += vv[u]; }
  }
  smax[rs][f] = mx; ssum[rs][f] = sm;
  __syncthreads();
  if (t < 128) {
    float m = smax[0][f], s = ssum[0][f];
#pragma unroll
    for (int q = 1; q < 8; ++q) { m = fmaxf(m, smax[q][f]); s += ssum[q][f]; }
    float a = fmaxf(m, 0.f);
    float m2 = fmaxf(s / (float)n, 0.f);
    if (init) { g[b * 384 + f] = a; g[b * 384 + 128 + f] = m2; }
    else      { g[b * 384 + f] += a; g[b * 384 + 128 + f] += m2; }
  }
}

// ---- A1 = softmax_row(leakyrelu(ar_i+ac_j) + bit(pi,pj)) + row stats ----
// one wave per row, 8 elements per lane; block 256 = 4 rows
__global__ __launch_bounds__(256) void k_buildA_bit(const unsigned* __restrict__ adj,
    const int* __restrict__ perm, const float* __restrict__ ar, const float* __restrict__ ac,
    float* __restrict__ A, float* __restrict__ disc, float* __restrict__ saO,
    float* __restrict__ disn, float* __restrict__ diagO) {
  int wid = threadIdx.x >> 6, lane = threadIdx.x & 63;
  int row = blockIdx.x * 4 + wid;      // [0, Bb*K1)
  int b = row >> 9, i = row & (K1 - 1);
  int pbase = b << 9;
  int pi = perm[pbase + i];
  float ari = ar[pbase + i];
  int j0 = lane * 8;
  float acv[8]; int pj[8];
  *(float4*)&acv[0] = *(const float4*)&ac[pbase + j0];
  *(float4*)&acv[4] = *(const float4*)&ac[pbase + j0 + 4];
  *(int4*)&pj[0] = *(const int4*)&perm[pbase + j0];
  *(int4*)&pj[4] = *(const int4*)&perm[pbase + j0 + 4];
  const unsigned* arow = adj + (size_t)((b << 10) + pi) * 32;
  float xv[8];
#pragma unroll
  for (int u = 0; u < 8; ++u) {
    float x = ari + acv[u];
    x = x > 0.f ? x : 0.2f * x;
    unsigned word = arow[pj[u] >> 5];
    xv[u] = x + (float)((word >> (pj[u] & 31)) & 1u);
  }
  float m = xv[0];
#pragma unroll
  for (int u = 1; u < 8; ++u) m = fmaxf(m, xv[u]);
  m = wred_max_all(m);
  float e[8], ls = 0.f;
#pragma unroll
  for (int u = 0; u < 8; ++u) { e[u] = expf(xv[u] - m); ls += e[u]; }
  float s = wred_sum_all(ls);
  float inv = 1.0f / s;
  float av[8]; float lsum = 0.f;
#pragma unroll
  for (int u = 0; u < 8; ++u) { av[u] = e[u] * inv; lsum += av[u]; }
  float* Ar = A + (size_t)row * K1 + j0;
  *(float4*)&Ar[0] = make_float4(av[0], av[1], av[2], av[3]);
  *(float4*)&Ar[4] = make_float4(av[4], av[5], av[6], av[7]);
  float rs = wred_sum_all(lsum);
  float dsel = av[i & 7];                 // uniform index
  float dval = __shfl(dsel, i >> 3, 64);
  if (lane == 0) {
    float sav = (dval == 0.f) ? 1.f : 0.f;
    float deg = rs + sav;
    disc[row] = deg > 0.f ? rsqrtf(deg) : 0.f;
    saO[row] = sav;
    float deg0 = rs - dval;
    disn[row] = deg0 > 0.f ? rsqrtf(deg0) : 0.f;
    diagO[row] = dval;
  }
}

// ---- A2 = softmax_row(leakyrelu(ar_i+ac_j) + A1[pi,pj]) + row stats ----
// one wave per row, 4 elements per lane; block 256 = 4 rows
__global__ __launch_bounds__(256) void k_buildA_dense(const float* __restrict__ Aprev,
    const int* __restrict__ perm, const float* __restrict__ ar, const float* __restrict__ ac,
    float* __restrict__ A, float* __restrict__ disc, float* __restrict__ saO,
    float* __restrict__ disn, float* __restrict__ diagO) {
  int wid = threadIdx.x >> 6, lane = threadIdx.x & 63;
  int row = blockIdx.x * 4 + wid;      // [0, Bb*K2)
  int b = row >> 8, i = row & (K2 - 1);
  int pbase = b << 8;
  int pi = perm[pbase + i];
  float ari = ar[pbase + i];
  int j0 = lane * 4;
  float acv[4]; int pj[4];
  *(float4*)&acv[0] = *(const float4*)&ac[pbase + j0];
  *(int4*)&pj[0] = *(const int4*)&perm[pbase + j0];
  const float* aprow = Aprev + (size_t)((b << 9) + pi) * K1;
  float xv[4];
#pragma unroll
  for (int u = 0; u < 4; ++u) {
    float x = ari + acv[u];
    x = x > 0.f ? x : 0.2f * x;
    xv[u] = x + aprow[pj[u]];
  }
  float m = fmaxf(fmaxf(xv[0], xv[1]), fmaxf(xv[2], xv[3]));
  m = wred_max_all(m);
  float e[4], ls = 0.f;
#pragma unroll
  for (int u = 0; u < 4; ++u) { e[u] = expf(xv[u] - m); ls += e[u]; }
  float s = wred_sum_all(ls);
  float inv = 1.0f / s;
  float av[4]; float lsum = 0.f;
#pragma unroll
  for (int u = 0; u < 4; ++u) { av[u] = e[u] * inv; lsum += av[u]; }
  *(float4*)&A[(size_t)row * K2 + j0] = make_float4(av[0], av[1], av[2], av[3]);
  float rs = wred_sum_all(lsum);
  float dsel = av[i & 3];
  float dval = __shfl(dsel, i >> 2, 64);
  if (lane == 0) {
    float sav = (dval == 0.f) ? 1.f : 0.f;
    float deg = rs + sav;
    disc[row] = deg > 0.f ? rsqrtf(deg) : 0.f;
    saO[row] = sav;
    float deg0 = rs - dval;
    disn[row] = deg0 > 0.f ? rsqrtf(deg0) : 0.f;
    diagO[row] = dval;
  }
}

// ---- fused dense mm: out = epilogue(A[b] @ diag(wrow) Y[b]) ----
// 512 threads = 2 split-K groups of 256; BM=64, BN=128 (full).
// MODE 0 (conv): h = relu(dc*(acc + sa*dc*Y) + bias)
// MODE 1 (nis):  score = sum_f |hv - dn*(acc - diag*dn*hv)|, Y == h
template <int MODE>
__global__ __launch_bounds__(512) void k_mmf(const float* __restrict__ A,
    const float* __restrict__ Y, const float* __restrict__ wrow,
    const float* __restrict__ aux, const float* __restrict__ bias,
    float* __restrict__ outp, int n) {
  __shared__ float smem[13056];  // As[2][64][36] @0, Ys[2][32][132] @4608
  int t = threadIdx.x;
  int kg = t >> 8, tt = t & 255;
  int tiles = n >> 6;
  int bid = blockIdx.x;
  int c = bid & 7, q = bid >> 3;
  int g = c * 8 + q / tiles;     // graph (8 graphs per XCD)
  int rt = q % tiles;            // row tile
  const float* Ab = A + (size_t)g * n * n + (size_t)(rt * 64) * n;
  const float* Yb = Y + (size_t)g * n * Fd;
  const float* wb = wrow + (size_t)g * n;
  int r0 = (tt >> 4) * 4, c0 = (tt & 15) * 4;
  float acc[4][8] = {};
  int kbase = kg * (n >> 1);
  float* Asg = smem + kg * 2304;
  float* Ysg = smem + 4608 + kg * 4224;
  for (int kb = 0; kb < (n >> 1); kb += 32) {
    int kglob = kbase + kb;
    __syncthreads();
#pragma unroll
    for (int ii = 0; ii < 2; ++ii) {
      int f4 = tt + 256 * ii;
      int r = f4 >> 3, c4 = (f4 & 7) * 4;
      *(float4*)&Asg[r * 36 + c4] = *(const float4*)&Ab[(size_t)r * n + kglob + c4];
    }
#pragma unroll
    for (int ii = 0; ii < 4; ++ii) {
      int f4 = tt + 256 * ii;
      int r = f4 >> 5, c4 = (f4 & 31) * 4;
      float4 v = *(const float4*)&Yb[(size_t)(kglob + r) * Fd + c4];
      float sc = wb[kglob + r];
      v.x *= sc; v.y *= sc; v.z *= sc; v.w *= sc;
      *(float4*)&Ysg[r * 132 + c4] = v;
    }
    __syncthreads();
#pragma unroll
    for (int k4 = 0; k4 < 8; ++k4) {
      float a_[4][4];
#pragma unroll
      for (int i = 0; i < 4; ++i)
        *(float4*)a_[i] = *(const float4*)&Asg[(r0 + i) * 36 + k4 * 4];
#pragma unroll
      for (int kk = 0; kk < 4; ++kk) {
        float4 y0 = *(const float4*)&Ysg[(k4 * 4 + kk) * 132 + c0];
        float4 y1 = *(const float4*)&Ysg[(k4 * 4 + kk) * 132 + c0 + 64];
#pragma unroll
        for (int i = 0; i < 4; ++i) {
          float av = a_[i][kk];
          acc[i][0] += av * y0.x; acc[i][1] += av * y0.y;
          acc[i][2] += av * y0.z; acc[i][3] += av * y0.w;
          acc[i][4] += av * y1.x; acc[i][5] += av * y1.y;
          acc[i][6] += av * y1.z; acc[i][7] += av * y1.w;
        }
      }
    }
  }
  // merge split-K partials: group 1 -> LDS -> group 0
  float* mrg = smem + 4608;  // 8448-float region, need 8192
  __syncthreads();
  if (kg == 1) {
#pragma unroll
    for (int i = 0; i < 4; ++i) {
      *(float4*)&mrg[(r0 + i) * 128 + c0]      = *(float4*)&acc[i][0];
      *(float4*)&mrg[(r0 + i) * 128 + c0 + 64] = *(float4*)&acc[i][4];
    }
  }
  __syncthreads();
  if (kg == 0) {
#pragma unroll
    for (int i = 0; i < 4; ++i) {
      float4 m0 = *(float4*)&mrg[(r0 + i) * 128 + c0];
      float4 m1 = *(float4*)&mrg[(r0 + i) * 128 + c0 + 64];
      acc[i][0] += m0.x; acc[i][1] += m0.y; acc[i][2] += m0.z; acc[i][3] += m0.w;
      acc[i][4] += m1.x; acc[i][5] += m1.y; acc[i][6] += m1.z; acc[i][7] += m1.w;
    }
    if (MODE == 0) {
      float4 bv0 = *(const float4*)&bias[c0];
      float4 bv1 = *(const float4*)&bias[c0 + 64];
#pragma unroll
      for (int i = 0; i < 4; ++i) {
        int rl = rt * 64 + r0 + i;
        size_t R = (size_t)g * n + rl;
        float dc = wb[rl];
        float sv = aux[R] * dc;
        float4 y0 = *(const float4*)&Y[R * Fd + c0];
        float4 y1 = *(const float4*)&Y[R * Fd + c0 + 64];
        float4 o0, o1;
        o0.x = fmaxf(dc * (acc[i][0] + sv * y0.x) + bv0.x, 0.f);
        o0.y = fmaxf(dc * (acc[i][1] + sv * y0.y) + bv0.y, 0.f);
        o0.z = fmaxf(dc * (acc[i][2] + sv * y0.z) + bv0.z, 0.f);
        o0.w = fmaxf(dc * (acc[i][3] + sv * y0.w) + bv0.w, 0.f);
        o1.x = fmaxf(dc * (acc[i][4] + sv * y1.x) + bv1.x, 0.f);
        o1.y = fmaxf(dc * (acc[i][5] + sv * y1.y) + bv1.y, 0.f);
        o1.z = fmaxf(dc * (acc[i][6] + sv * y1.z) + bv1.z, 0.f);
        o1.w = fmaxf(dc * (acc[i][7] + sv * y1.w) + bv1.w, 0.f);
        *(float4*)&outp[R * Fd + c0]      = o0;
        *(float4*)&outp[R * Fd + c0 + 64] = o1;
      }
    } else {
      float* rowred = smem;  // [64][16] floats
#pragma unroll
      for (int i = 0; i < 4; ++i) {
        int rl = rt * 64 + r0 + i;
        size_t R = (size_t)g * n + rl;
        float dn = wb[rl];
        float dg = aux[R] * dn;
        float4 h0 = *(const float4*)&Y[R * Fd + c0];
        float4 h1 = *(const float4*)&Y[R * Fd + c0 + 64];
        float p = 0.f;
        p += fabsf(h0.x - dn * (acc[i][0] - dg * h0.x));
        p += fabsf(h0.y - dn * (acc[i][1] - dg * h0.y));
        p += fabsf(h0.z - dn * (acc[i][2] - dg * h0.z));
        p += fabsf(h0.w - dn * (acc[i][3] - dg * h0.w));
        p += fabsf(h1.x - dn * (acc[i][4] - dg * h1.x));
        p += fabsf(h1.y - dn * (acc[i][5] - dg * h1.y));
        p += fabsf(h1.z - dn * (acc[i][6] - dg * h1.z));
        p += fabsf(h1.w - dn * (acc[i][7] - dg * h1.w));
        rowred[(r0 + i) * 16 + (tt & 15)] = p;
      }
    }
  }
  if (MODE == 1) {
    __syncthreads();
    if (t < 64) {
      float s = 0.f;
#pragma unroll
      for (int qq = 0; qq < 16; ++qq) s += smem[t * 16 + qq];
      outp[(size_t)g * n + rt * 64 + t] = s;
    }
  }
}

__global__ __launch_bounds__(128) void k_xskew(const float* __restrict__ skew,
    const float* __restrict__ Wsk, const float* __restrict__ bsk, float* __restrict__ g) {
  int b = blockIdx.x, f = threadIdx.x;
  float acc = bsk[f];
  for (int s = 0; s < 64; ++s) acc += skew[b * 64 + s] * Wsk[s * Fd + f];
  g[b * 384 + 256 + f] = fmaxf(acc, 0.f);
}

__global__ __launch_bounds__(128) void k_mlp1(const float* __restrict__ g,
    const float* __restrict__ Wl, const float* __restrict__ bl, float* __restrict__ o) {
  int b = blockIdx.x, f = threadIdx.x;
  float acc = bl[f];
  for (int s = 0; s < 384; ++s) acc += g[b * 384 + s] * Wl[s * 128 + f];
  o[b * 128 + f] = fmaxf(acc, 0.f);
}
__global__ __launch_bounds__(64) void k_mlp2(const float* __restrict__ x,
    const float* __restrict__ Wl, const float* __restrict__ bl, float* __restrict__ o) {
  int b = blockIdx.x, f = threadIdx.x;
  float acc = bl[f];
  for (int s = 0; s < 128; ++s) acc += x[b * 128 + s] * Wl[s * 64 + f];
  o[b * 64 + f] = fmaxf(acc, 0.f);
}
__global__ __launch_bounds__(64) void k_mlp3(const float* __restrict__ x,
    const float* __restrict__ Wl, const float* __restrict__ bl, float* __restrict__ out) {
  int b = blockIdx.x, f = threadIdx.x;
  __shared__ float lg[10];
  if (f < 10) {
    float acc = bl[f];
    for (int s = 0; s < 64; ++s) acc += x[b * 64 + s] * Wl[s * 10 + f];
    lg[f] = acc;
  }
  __syncthreads();
  if (f == 0) {
    float m = lg[0];
    for (int c = 1; c < 10; ++c) m = fmaxf(m, lg[c]);
    float s = 0.f;
    for (int c = 0; c < 10; ++c) s += expf(lg[c] - m);
    float l = logf(s);
    for (int c = 0; c < 10; ++c) out[b * 10 + c] = lg[c] - m - l;
  }
}

extern "C" void kernel_launch(void* const* d_in, const int* in_sizes, int n_in,
                              void* d_out, int out_size, void* d_ws, size_t ws_size,
                              hipStream_t stream) {
  const float* x    = (const float*)d_in[0];
  const int*   src  = (const int*)d_in[1];
  const int*   dst  = (const int*)d_in[2];
  const float* skew = (const float*)d_in[3];
  const float* W1   = (const float*)d_in[4];
  const float* b1   = (const float*)d_in[5];
  const float* W2   = (const float*)d_in[6];
  const float* b2   = (const float*)d_in[7];
  const float* W3   = (const float*)d_in[8];
  const float* b3   = (const float*)d_in[9];
  const float* att1 = (const float*)d_in[10];
  const float* att2 = (const float*)d_in[11];
  const float* Wsk  = (const float*)d_in[12];
  const float* bsk  = (const float*)d_in[13];
  const float* Wl1  = (const float*)d_in[14];
  const float* bl1  = (const float*)d_in[15];
  const float* Wl2  = (const float*)d_in[16];
  const float* bl2  = (const float*)d_in[17];
  const float* Wl3  = (const float*)d_in[18];
  const float* bl3  = (const float*)d_in[19];
  float* out = (float*)d_out;

  char* base = (char*)d_ws;
  size_t off = 0;
  auto alloc = [&](size_t bytes) -> void* {
    void* p = base + off;
    off += (bytes + 255) & ~(size_t)255;
    return p;
  };

  unsigned* adj = (unsigned*)alloc((size_t)Bb * N0 * 32 * 4);        // 8 MB
  float* dis0 = (float*)alloc((size_t)Bb * N0 * 4);
  float* dis1 = (float*)alloc((size_t)Bb * N0 * 4);
  int*   degv = (int*)alloc((size_t)Bb * N0 * 4);
  float* bigA = (float*)alloc((size_t)64 * 1024 * 1024);             // 64 MB multi-use
  float* XW  = bigA;                                                  // [B,1024,128]
  float* h1  = bigA + (size_t)Bb * N0 * Fd;                           // [B,1024,128]
  float* A1  = bigA;                                                  // [B,512,512] (after h1 dead)
  float* XW3 = bigA;                                                  // [B,256,128] (after A1 dead)
  float* h3  = bigA + (size_t)Bb * K2 * Fd;                           // [B,256,128]
  float* score = (float*)alloc((size_t)Bb * N0 * 4);
  int*   perm1 = (int*)alloc((size_t)Bb * K1 * 4);
  float* Xp1 = (float*)alloc((size_t)Bb * K1 * Fd * 4);               // later reused as A2
  float* A2  = Xp1;                                                   // [B,256,256] = same bytes
  float* ar1 = (float*)alloc((size_t)Bb * K1 * 4);
  float* ac1 = (float*)alloc((size_t)Bb * K1 * 4);
  float* disc2 = (float*)alloc((size_t)Bb * K1 * 4);
  float* sa2   = (float*)alloc((size_t)Bb * K1 * 4);
  float* disn2 = (float*)alloc((size_t)Bb * K1 * 4);
  float* diag2 = (float*)alloc((size_t)Bb * K1 * 4);
  float* XW2 = (float*)alloc((size_t)Bb * K1 * Fd * 4);               // 16 MB
  float* h2  = (float*)alloc((size_t)Bb * K1 * Fd * 4);               // 16 MB (contiguous w/ XW2)
  int*   perm2 = (int*)alloc((size_t)Bb * K2 * 4);
  float* Xp2 = (float*)alloc((size_t)Bb * K2 * Fd * 4);
  float* ar2 = (float*)alloc((size_t)Bb * K2 * 4);
  float* ac2 = (float*)alloc((size_t)Bb * K2 * 4);
  float* disc3 = (float*)alloc((size_t)Bb * K2 * 4);
  float* sa3   = (float*)alloc((size_t)Bb * K2 * 4);
  float* disn3 = (float*)alloc((size_t)Bb * K2 * 4);
  float* diag3 = (float*)alloc((size_t)Bb * K2 * 4);
  float* g  = (float*)alloc((size_t)Bb * 384 * 4);
  float* t1 = (float*)alloc((size_t)Bb * 128 * 4);
  float* t2 = (float*)alloc((size_t)Bb * 64 * 4);
  // nbr [B*N0][128] ints = 32 MB; overlays XW2+h2 (dead until stage-2 gemm,
  // nbr dead after k_nis1). XW2/h2 are adjacent 16 MB 256-aligned blocks.
  int* nbr = (int*)XW2;
  (void)ws_size; (void)in_sizes; (void)n_in; (void)out_size;

  // stage 1: binary graph
  hipMemsetAsync(adj, 0, (size_t)Bb * N0 * 32 * 4, stream);
  k_scatter<<<(Bb * NE + 255) / 256, 256, 0, stream>>>(src, dst, adj);
  k_degree<<<(Bb * N0 + 255) / 256, 256, 0, stream>>>(adj, dis0, dis1);
  k_adjlist<<<Bb * N0, 64, 0, stream>>>(adj, nbr, degv);
  k_gemm128<<<Bb * N0 / 64, 256, 0, stream>>>(x, W1, XW);
  k_conv1<<<Bb * N0, 128, 0, stream>>>(nbr, degv, XW, dis1, b1, h1);
  k_nis1<<<Bb * N0, 128, 0, stream>>>(nbr, degv, h1, dis0, score);
  k_topk<<<Bb, N0, 0, stream>>>(score, perm1, N0, K1);
  k_gather<<<Bb * K1, 128, 0, stream>>>(h1, perm1, att1, Xp1, ar1, ac1, N0, K1);
  k_readout<<<Bb, 1024, 0, stream>>>(Xp1, K1, g, 1);
  k_buildA_bit<<<Bb * K1 / 4, 256, 0, stream>>>(adj, perm1, ar1, ac1, A1,
                                                disc2, sa2, disn2, diag2);  // overwrites XW/h1

  // stage 2: dense A1 (fused mm + epilogues, split-K x2)
  k_gemm128<<<Bb * K1 / 64, 256, 0, stream>>>(Xp1, W2, XW2);
  k_mmf<0><<<Bb * (K1 / 64), 512, 0, stream>>>(A1, XW2, disc2, sa2, b2, h2, K1);
  k_mmf<1><<<Bb * (K1 / 64), 512, 0, stream>>>(A1, h2, disn2, diag2, nullptr, score, K1);
  k_topk<<<Bb, K1, 0, stream>>>(score, perm2, K1, K2);
  k_gather<<<Bb * K2, 128, 0, stream>>>(h2, perm2, att2, Xp2, ar2, ac2, K1, K2);
  k_readout<<<Bb, 1024, 0, stream>>>(Xp2, K2, g, 0);
  k_buildA_dense<<<Bb * K2 / 4, 256, 0, stream>>>(A1, perm2, ar2, ac2, A2,
                                                  disc3, sa3, disn3, diag3);  // overwrites Xp1

  // stage 3: dense A2
  k_gemm128<<<Bb * K2 / 64, 256, 0, stream>>>(Xp2, W3, XW3);           // overwrites A1 region
  k_mmf<0><<<Bb * (K2 / 64), 512, 0, stream>>>(A2, XW3, disc3, sa3, b3, h3, K2);
  k_readout<<<Bb, 1024, 0, stream>>>(h3, K2, g, 0);

  // head
  k_xskew<<<Bb, 128, 0, stream>>>(skew, Wsk, bsk, g);
  k_mlp1<<<Bb, 128, 0, stream>>>(g, Wl1, bl1, t1);
  k_mlp2<<<Bb, 64, 0, stream>>>(t1, Wl2, bl2, t2);
  k_mlp3<<<Bb, 64, 0, stream>>>(t2, Wl3, bl3, out);
}

// Round 7
// 429.943 us; speedup vs baseline: 2.6417x; 1.2066x over previous
//
#include <hip/hip_runtime.h>
#include <math.h>

#define Bb 64
#define N0 1024
#define NE 16384
#define Fd 128
#define K1 512
#define K2 256
#define RPB 256  // rows per k_graph block

__device__ __forceinline__ float wred_sum(float v) {
#pragma unroll
  for (int o = 32; o > 0; o >>= 1) v += __shfl_down(v, o, 64);
  return v;
}
__device__ __forceinline__ float wred_sum_all(float v) {
#pragma unroll
  for (int o = 32; o > 0; o >>= 1) v += __shfl_xor(v, o, 64);
  return v;
}
__device__ __forceinline__ float wred_max_all(float v) {
#pragma unroll
  for (int o = 32; o > 0; o >>= 1) v = fmaxf(v, __shfl_xor(v, o, 64));
  return v;
}

// ---- fused graph build: edges -> LDS bitmask -> adj + degree + nbr list ----
// grid = Bb*4 (graph x row-quarter), block = 1024
__global__ __launch_bounds__(1024) void k_graph(const int* __restrict__ src,
    const int* __restrict__ dst, unsigned* __restrict__ adj,
    unsigned short* __restrict__ nbr, int* __restrict__ degv,
    float* __restrict__ dis0, float* __restrict__ dis1) {
  __shared__ unsigned lmask[RPB * 32];  // 32 KB
  int t = threadIdx.x;
  int b = blockIdx.x >> 2;
  int rlo = (blockIdx.x & 3) * RPB;
#pragma unroll
  for (int i = t; i < RPB * 32; i += 1024) lmask[i] = 0;
  __syncthreads();
  const int* sp = src + b * NE;
  const int* dp = dst + b * NE;
#pragma unroll
  for (int e = t; e < NE; e += 1024) {
    int u = sp[e], v = dp[e];
    if (u == v) continue;
    if ((unsigned)(u - rlo) < RPB)
      atomicOr(&lmask[(u - rlo) * 32 + (v >> 5)], 1u << (v & 31));
    if ((unsigned)(v - rlo) < RPB)
      atomicOr(&lmask[(v - rlo) * 32 + (u >> 5)], 1u << (u & 31));
  }
  __syncthreads();
  unsigned* adjg = adj + ((size_t)(b << 10) + rlo) * 32;
#pragma unroll
  for (int i = t; i < RPB * 32; i += 1024) adjg[i] = lmask[i];
  if (t < RPB) {
    int row = (b << 10) + rlo + t;
    const unsigned* wm = &lmask[t * 32];
    int d = 0;
#pragma unroll
    for (int i = 0; i < 32; ++i) d += __popc(wm[i]);
    degv[row] = d;
    dis0[row] = d > 0 ? rsqrtf((float)d) : 0.f;
    dis1[row] = rsqrtf((float)(d + 1));
    unsigned short* dstp = nbr + (size_t)row * 128;
    int o = 0;
#pragma unroll
    for (int w = 0; w < 32; ++w) {
      unsigned m = wm[w];
      int bas = w << 5;
      while (m) { int j = bas + __ffs(m) - 1; m &= m - 1; dstp[o++] = (unsigned short)j; }
    }
  }
}

// ---- C[M,128] = X[M,128] @ W[128,128], M % 64 == 0, grid = M/64, block 256 ----
__global__ __launch_bounds__(256) void k_gemm128(const float* __restrict__ X,
                                                 const float* __restrict__ W,
                                                 float* __restrict__ C) {
  __shared__ float Xs[64][132];
  __shared__ float Ws[32][132];
  int t = threadIdx.x;
  size_t row0 = (size_t)blockIdx.x * 64;
  const float4* Xg = (const float4*)(X + row0 * Fd);
#pragma unroll
  for (int i = 0; i < 8; ++i) {
    int f4 = t + 256 * i;
    float4 v = Xg[f4];
    *(float4*)&Xs[f4 >> 5][(f4 & 31) * 4] = v;
  }
  int r0 = (t >> 5) * 8, c0 = (t & 31) * 4;
  float acc[8][4] = {};
  for (int kb = 0; kb < 128; kb += 32) {
    __syncthreads();
#pragma unroll
    for (int i = 0; i < 4; ++i) {
      int f4 = t + 256 * i;
      float4 v = ((const float4*)(W + (size_t)kb * Fd))[f4];
      *(float4*)&Ws[f4 >> 5][(f4 & 31) * 4] = v;
    }
    __syncthreads();
#pragma unroll
    for (int k = 0; k < 32; ++k) {
      float4 wv = *(const float4*)&Ws[k][c0];
#pragma unroll
      for (int i = 0; i < 8; ++i) {
        float xv = Xs[r0 + i][kb + k];
        acc[i][0] += xv * wv.x; acc[i][1] += xv * wv.y;
        acc[i][2] += xv * wv.z; acc[i][3] += xv * wv.w;
      }
    }
  }
#pragma unroll
  for (int i = 0; i < 8; ++i) {
    float4 o = make_float4(acc[i][0], acc[i][1], acc[i][2], acc[i][3]);
    *(float4*)&C[(row0 + r0 + i) * Fd + c0] = o;
  }
}

// ---- gather-accumulate with 8 loads in flight ----
__device__ __forceinline__ float gather8(const float* __restrict__ srcb,
                                         const unsigned short* idxs, const float* wts,
                                         int deg, int f) {
  float acc = 0.f;
  int dp = (deg + 7) & ~7;
  for (int i = 0; i < dp; i += 8) {
    int jj[8]; float ww[8], vv[8];
#pragma unroll
    for (int u = 0; u < 8; ++u) { jj[u] = idxs[i + u]; ww[u] = wts[i + u]; }
#pragma unroll
    for (int u = 0; u < 8; ++u) vv[u] = srcb[(size_t)jj[u] * Fd + f];
#pragma unroll
    for (int u = 0; u < 8; ++u) acc += ww[u] * vv[u];
  }
  return acc;
}

// XCD-grouped row swizzle: blocks with bid%8==c -> XCD c -> graphs [c*8, c*8+8)
__device__ __forceinline__ int swz_row(int bid) {
  int c = bid & 7, q = bid >> 3;
  return (((c << 3) + (q >> 10)) << 10) + (q & 1023);
}

// ---- conv1: h1 = relu(dis1_i*(sum_{j in N(i)} dis1_j XW_j + dis1_i XW_i) + b1) ----
__global__ __launch_bounds__(128) void k_conv1(const unsigned short* __restrict__ nbr,
    const int* __restrict__ degv, const float* __restrict__ XW,
    const float* __restrict__ dis1, const float* __restrict__ b1, float* __restrict__ h1) {
  __shared__ unsigned short idxs[128];
  __shared__ float wts[128];
  int row = swz_row(blockIdx.x), f = threadIdx.x;
  int base = row & ~(N0 - 1);
  int deg = degv[row];
  int li = (f < deg) ? (int)nbr[(size_t)row * 128 + f] : 0;
  idxs[f] = (unsigned short)li;
  wts[f] = (f < deg) ? dis1[base + li] : 0.f;
  __syncthreads();
  float di = dis1[row];
  float acc = gather8(XW + (size_t)base * Fd, idxs, wts, deg, f);
  acc += di * XW[(size_t)row * Fd + f];
  h1[(size_t)row * Fd + f] = fmaxf(di * acc + b1[f], 0.f);
}

// ---- NIS on binary A: score_i = sum_f |h_i - dis0_i * sum_j dis0_j h_j| ----
__global__ __launch_bounds__(128) void k_nis1(const unsigned short* __restrict__ nbr,
    const int* __restrict__ degv, const float* __restrict__ h,
    const float* __restrict__ dis0, float* __restrict__ score) {
  __shared__ unsigned short idxs[128];
  __shared__ float wts[128];
  __shared__ float red[2];
  int row = swz_row(blockIdx.x), f = threadIdx.x;
  int base = row & ~(N0 - 1);
  int deg = degv[row];
  int li = (f < deg) ? (int)nbr[(size_t)row * 128 + f] : 0;
  idxs[f] = (unsigned short)li;
  wts[f] = (f < deg) ? dis0[base + li] : 0.f;
  __syncthreads();
  float acc = gather8(h + (size_t)base * Fd, idxs, wts, deg, f);
  float val = h[(size_t)row * Fd + f] - dis0[row] * acc;
  float p = wred_sum(fabsf(val));
  if ((f & 63) == 0) red[f >> 6] = p;
  __syncthreads();
  if (f == 0) score[row] = red[0] + red[1];
}

// ---- exact top-k per graph: bitonic sort of (score,idx) packed u64 keys ----
__global__ __launch_bounds__(1024) void k_topk(const float* __restrict__ score,
                                               int* __restrict__ perm, int n, int k) {
  __shared__ unsigned long long keys[1024];
  int b = blockIdx.x, t = threadIdx.x;
  float s = score[b * n + t];
  unsigned ub = __float_as_uint(s);
  unsigned su = (ub & 0x80000000u) ? ~ub : (ub | 0x80000000u);  // monotone map
  keys[t] = ((unsigned long long)(~su) << 32) | (unsigned)t;    // asc sort = desc score, asc idx
  __syncthreads();
  for (int kk = 2; kk <= n; kk <<= 1) {
    for (int j = kk >> 1; j > 0; j >>= 1) {
      int ixj = t ^ j;
      if (ixj > t) {
        unsigned long long a = keys[t], c = keys[ixj];
        bool up = ((t & kk) == 0);
        if ((a > c) == up) { keys[t] = c; keys[ixj] = a; }
      }
      __syncthreads();
    }
  }
  if (t < k) perm[b * k + t] = (int)(keys[t] & 0xffffffffu);
}

// ---- gather pooled rows + attention dots ----
__global__ __launch_bounds__(128) void k_gather(const float* __restrict__ h,
    const int* __restrict__ perm, const float* __restrict__ att, float* __restrict__ Xp,
    float* __restrict__ ar, float* __restrict__ ac, int n, int k) {
  int idx = blockIdx.x, f = threadIdx.x;
  int b = idx / k;
  __shared__ float red[4];
  int p = perm[idx];
  float v = h[((size_t)b * n + p) * Fd + f];
  Xp[(size_t)idx * Fd + f] = v;
  float r1 = wred_sum(v * att[f]);
  float r2 = wred_sum(v * att[Fd + f]);
  if ((f & 63) == 0) { red[f >> 6] = r1; red[2 + (f >> 6)] = r2; }
  __syncthreads();
  if (f == 0) { ar[idx] = red[0] + red[1]; ac[idx] = red[2] + red[3]; }
}

// ---- readout: g[b][0:128] (+)= relu(max), g[b][128:256] (+)= relu(mean) ----
__global__ __launch_bounds__(1024) void k_readout(const float* __restrict__ X, int n,
                                                  float* __restrict__ g, int init) {
  int b = blockIdx.x, t = threadIdx.x;
  int f = t & 127, rs = t >> 7;
  __shared__ float smax[8][128];
  __shared__ float ssum[8][128];
  int per = n >> 3;
  const float* Xs = X + ((size_t)b * n + (size_t)rs * per) * Fd + f;
  float mx = -3.0e38f, sm = 0.f;
  for (int j = 0; j < per; j += 8) {
    float vv[8];
#pragma unroll
    for (int u = 0; u < 8; ++u) vv[u] = Xs[(size_t)(j + u) * Fd];
#pragma unroll
    for (int u = 0; u < 8; ++u) { mx = fmaxf(mx, vv[u]); sm += vv[u]; }
  }
  smax[rs][f] = mx; ssum[rs][f] = sm;
  __syncthreads();
  if (t < 128) {
    float m = smax[0][f], s = ssum[0][f];
#pragma unroll
    for (int q = 1; q < 8; ++q) { m = fmaxf(m, smax[q][f]); s += ssum[q][f]; }
    float a = fmaxf(m, 0.f);
    float m2 = fmaxf(s / (float)n, 0.f);
    if (init) { g[b * 384 + f] = a; g[b * 384 + 128 + f] = m2; }
    else      { g[b * 384 + f] += a; g[b * 384 + 128 + f] += m2; }
  }
}

// ---- A1 = softmax_row(leakyrelu(ar_i+ac_j) + bit(pi,pj)) + row stats ----
// one wave per row, 8 elements per lane; block 256 = 4 rows
__global__ __launch_bounds__(256) void k_buildA_bit(const unsigned* __restrict__ adj,
    const int* __restrict__ perm, const float* __restrict__ ar, const float* __restrict__ ac,
    float* __restrict__ A, float* __restrict__ disc, float* __restrict__ saO,
    float* __restrict__ disn, float* __restrict__ diagO) {
  int wid = threadIdx.x >> 6, lane = threadIdx.x & 63;
  int row = blockIdx.x * 4 + wid;      // [0, Bb*K1)
  int b = row >> 9, i = row & (K1 - 1);
  int pbase = b << 9;
  int pi = perm[pbase + i];
  float ari = ar[pbase + i];
  int j0 = lane * 8;
  float acv[8]; int pj[8];
  *(float4*)&acv[0] = *(const float4*)&ac[pbase + j0];
  *(float4*)&acv[4] = *(const float4*)&ac[pbase + j0 + 4];
  *(int4*)&pj[0] = *(const int4*)&perm[pbase + j0];
  *(int4*)&pj[4] = *(const int4*)&perm[pbase + j0 + 4];
  const unsigned* arow = adj + (size_t)((b << 10) + pi) * 32;
  float xv[8];
#pragma unroll
  for (int u = 0; u < 8; ++u) {
    float x = ari + acv[u];
    x = x > 0.f ? x : 0.2f * x;
    unsigned word = arow[pj[u] >> 5];
    xv[u] = x + (float)((word >> (pj[u] & 31)) & 1u);
  }
  float m = xv[0];
#pragma unroll
  for (int u = 1; u < 8; ++u) m = fmaxf(m, xv[u]);
  m = wred_max_all(m);
  float e[8], ls = 0.f;
#pragma unroll
  for (int u = 0; u < 8; ++u) { e[u] = expf(xv[u] - m); ls += e[u]; }
  float s = wred_sum_all(ls);
  float inv = 1.0f / s;
  float av[8]; float lsum = 0.f;
#pragma unroll
  for (int u = 0; u < 8; ++u) { av[u] = e[u] * inv; lsum += av[u]; }
  float* Ar = A + (size_t)row * K1 + j0;
  *(float4*)&Ar[0] = make_float4(av[0], av[1], av[2], av[3]);
  *(float4*)&Ar[4] = make_float4(av[4], av[5], av[6], av[7]);
  float rs = wred_sum_all(lsum);
  float dsel = av[i & 7];                 // uniform index
  float dval = __shfl(dsel, i >> 3, 64);
  if (lane == 0) {
    float sav = (dval == 0.f) ? 1.f : 0.f;
    float deg = rs + sav;
    disc[row] = deg > 0.f ? rsqrtf(deg) : 0.f;
    saO[row] = sav;
    float deg0 = rs - dval;
    disn[row] = deg0 > 0.f ? rsqrtf(deg0) : 0.f;
    diagO[row] = dval;
  }
}

// ---- A2 = softmax_row(leakyrelu(ar_i+ac_j) + A1[pi,pj]) + row stats ----
// one wave per row, 4 elements per lane; block 256 = 4 rows
__global__ __launch_bounds__(256) void k_buildA_dense(const float* __restrict__ Aprev,
    const int* __restrict__ perm, const float* __restrict__ ar, const float* __restrict__ ac,
    float* __restrict__ A, float* __restrict__ disc, float* __restrict__ saO,
    float* __restrict__ disn, float* __restrict__ diagO) {
  int wid = threadIdx.x >> 6, lane = threadIdx.x & 63;
  int row = blockIdx.x * 4 + wid;      // [0, Bb*K2)
  int b = row >> 8, i = row & (K2 - 1);
  int pbase = b << 8;
  int pi = perm[pbase + i];
  float ari = ar[pbase + i];
  int j0 = lane * 4;
  float acv[4]; int pj[4];
  *(float4*)&acv[0] = *(const float4*)&ac[pbase + j0];
  *(int4*)&pj[0] = *(const int4*)&perm[pbase + j0];
  const float* aprow = Aprev + (size_t)((b << 9) + pi) * K1;
  float xv[4];
#pragma unroll
  for (int u = 0; u < 4; ++u) {
    float x = ari + acv[u];
    x = x > 0.f ? x : 0.2f * x;
    xv[u] = x + aprow[pj[u]];
  }
  float m = fmaxf(fmaxf(xv[0], xv[1]), fmaxf(xv[2], xv[3]));
  m = wred_max_all(m);
  float e[4], ls = 0.f;
#pragma unroll
  for (int u = 0; u < 4; ++u) { e[u] = expf(xv[u] - m); ls += e[u]; }
  float s = wred_sum_all(ls);
  float inv = 1.0f / s;
  float av[4]; float lsum = 0.f;
#pragma unroll
  for (int u = 0; u < 4; ++u) { av[u] = e[u] * inv; lsum += av[u]; }
  *(float4*)&A[(size_t)row * K2 + j0] = make_float4(av[0], av[1], av[2], av[3]);
  float rs = wred_sum_all(lsum);
  float dsel = av[i & 3];
  float dval = __shfl(dsel, i >> 2, 64);
  if (lane == 0) {
    float sav = (dval == 0.f) ? 1.f : 0.f;
    float deg = rs + sav;
    disc[row] = deg > 0.f ? rsqrtf(deg) : 0.f;
    saO[row] = sav;
    float deg0 = rs - dval;
    disn[row] = deg0 > 0.f ? rsqrtf(deg0) : 0.f;
    diagO[row] = dval;
  }
}

// ---- fused dense mm: out = epilogue(A[b] @ diag(wrow) Y[b]) ----
// 512 threads = 2 split-K groups of 256; BM=64, BN=128 (full).
// MODE 0 (conv): h = relu(dc*(acc + sa*dc*Y) + bias)
// MODE 1 (nis):  score = sum_f |hv - dn*(acc - diag*dn*hv)|, Y == h
template <int MODE>
__global__ __launch_bounds__(512) void k_mmf(const float* __restrict__ A,
    const float* __restrict__ Y, const float* __restrict__ wrow,
    const float* __restrict__ aux, const float* __restrict__ bias,
    float* __restrict__ outp, int n) {
  __shared__ float smem[13056];  // As[2][64][36] @0, Ys[2][32][132] @4608
  int t = threadIdx.x;
  int kg = t >> 8, tt = t & 255;
  int tiles = n >> 6;
  int bid = blockIdx.x;
  int c = bid & 7, q = bid >> 3;
  int g = c * 8 + q / tiles;     // graph (8 graphs per XCD)
  int rt = q % tiles;            // row tile
  const float* Ab = A + (size_t)g * n * n + (size_t)(rt * 64) * n;
  const float* Yb = Y + (size_t)g * n * Fd;
  const float* wb = wrow + (size_t)g * n;
  int r0 = (tt >> 4) * 4, c0 = (tt & 15) * 4;
  float acc[4][8] = {};
  int kbase = kg * (n >> 1);
  float* Asg = smem + kg * 2304;
  float* Ysg = smem + 4608 + kg * 4224;
  for (int kb = 0; kb < (n >> 1); kb += 32) {
    int kglob = kbase + kb;
    __syncthreads();
#pragma unroll
    for (int ii = 0; ii < 2; ++ii) {
      int f4 = tt + 256 * ii;
      int r = f4 >> 3, c4 = (f4 & 7) * 4;
      *(float4*)&Asg[r * 36 + c4] = *(const float4*)&Ab[(size_t)r * n + kglob + c4];
    }
#pragma unroll
    for (int ii = 0; ii < 4; ++ii) {
      int f4 = tt + 256 * ii;
      int r = f4 >> 5, c4 = (f4 & 31) * 4;
      float4 v = *(const float4*)&Yb[(size_t)(kglob + r) * Fd + c4];
      float sc = wb[kglob + r];
      v.x *= sc; v.y *= sc; v.z *= sc; v.w *= sc;
      *(float4*)&Ysg[r * 132 + c4] = v;
    }
    __syncthreads();
#pragma unroll
    for (int k4 = 0; k4 < 8; ++k4) {
      float a_[4][4];
#pragma unroll
      for (int i = 0; i < 4; ++i)
        *(float4*)a_[i] = *(const float4*)&Asg[(r0 + i) * 36 + k4 * 4];
#pragma unroll
      for (int kk = 0; kk < 4; ++kk) {
        float4 y0 = *(const float4*)&Ysg[(k4 * 4 + kk) * 132 + c0];
        float4 y1 = *(const float4*)&Ysg[(k4 * 4 + kk) * 132 + c0 + 64];
#pragma unroll
        for (int i = 0; i < 4; ++i) {
          float av = a_[i][kk];
          acc[i][0] += av * y0.x; acc[i][1] += av * y0.y;
          acc[i][2] += av * y0.z; acc[i][3] += av * y0.w;
          acc[i][4] += av * y1.x; acc[i][5] += av * y1.y;
          acc[i][6] += av * y1.z; acc[i][7] += av * y1.w;
        }
      }
    }
  }
  // merge split-K partials: group 1 -> LDS -> group 0
  float* mrg = smem + 4608;  // 8448-float region, need 8192
  __syncthreads();
  if (kg == 1) {
#pragma unroll
    for (int i = 0; i < 4; ++i) {
      *(float4*)&mrg[(r0 + i) * 128 + c0]      = *(float4*)&acc[i][0];
      *(float4*)&mrg[(r0 + i) * 128 + c0 + 64] = *(float4*)&acc[i][4];
    }
  }
  __syncthreads();
  if (kg == 0) {
#pragma unroll
    for (int i = 0; i < 4; ++i) {
      float4 m0 = *(float4*)&mrg[(r0 + i) * 128 + c0];
      float4 m1 = *(float4*)&mrg[(r0 + i) * 128 + c0 + 64];
      acc[i][0] += m0.x; acc[i][1] += m0.y; acc[i][2] += m0.z; acc[i][3] += m0.w;
      acc[i][4] += m1.x; acc[i][5] += m1.y; acc[i][6] += m1.z; acc[i][7] += m1.w;
    }
    if (MODE == 0) {
      float4 bv0 = *(const float4*)&bias[c0];
      float4 bv1 = *(const float4*)&bias[c0 + 64];
#pragma unroll
      for (int i = 0; i < 4; ++i) {
        int rl = rt * 64 + r0 + i;
        size_t R = (size_t)g * n + rl;
        float dc = wb[rl];
        float sv = aux[R] * dc;
        float4 y0 = *(const float4*)&Y[R * Fd + c0];
        float4 y1 = *(const float4*)&Y[R * Fd + c0 + 64];
        float4 o0, o1;
        o0.x = fmaxf(dc * (acc[i][0] + sv * y0.x) + bv0.x, 0.f);
        o0.y = fmaxf(dc * (acc[i][1] + sv * y0.y) + bv0.y, 0.f);
        o0.z = fmaxf(dc * (acc[i][2] + sv * y0.z) + bv0.z, 0.f);
        o0.w = fmaxf(dc * (acc[i][3] + sv * y0.w) + bv0.w, 0.f);
        o1.x = fmaxf(dc * (acc[i][4] + sv * y1.x) + bv1.x, 0.f);
        o1.y = fmaxf(dc * (acc[i][5] + sv * y1.y) + bv1.y, 0.f);
        o1.z = fmaxf(dc * (acc[i][6] + sv * y1.z) + bv1.z, 0.f);
        o1.w = fmaxf(dc * (acc[i][7] + sv * y1.w) + bv1.w, 0.f);
        *(float4*)&outp[R * Fd + c0]      = o0;
        *(float4*)&outp[R * Fd + c0 + 64] = o1;
      }
    } else {
      float* rowred = smem;  // [64][16] floats
#pragma unroll
      for (int i = 0; i < 4; ++i) {
        int rl = rt * 64 + r0 + i;
        size_t R = (size_t)g * n + rl;
        float dn = wb[rl];
        float dg = aux[R] * dn;
        float4 h0 = *(const float4*)&Y[R * Fd + c0];
        float4 h1 = *(const float4*)&Y[R * Fd + c0 + 64];
        float p = 0.f;
        p += fabsf(h0.x - dn * (acc[i][0] - dg * h0.x));
        p += fabsf(h0.y - dn * (acc[i][1] - dg * h0.y));
        p += fabsf(h0.z - dn * (acc[i][2] - dg * h0.z));
        p += fabsf(h0.w - dn * (acc[i][3] - dg * h0.w));
        p += fabsf(h1.x - dn * (acc[i][4] - dg * h1.x));
        p += fabsf(h1.y - dn * (acc[i][5] - dg * h1.y));
        p += fabsf(h1.z - dn * (acc[i][6] - dg * h1.z));
        p += fabsf(h1.w - dn * (acc[i][7] - dg * h1.w));
        rowred[(r0 + i) * 16 + (tt & 15)] = p;
      }
    }
  }
  if (MODE == 1) {
    __syncthreads();
    if (t < 64) {
      float s = 0.f;
#pragma unroll
      for (int qq = 0; qq < 16; ++qq) s += smem[t * 16 + qq];
      outp[(size_t)g * n + rt * 64 + t] = s;
    }
  }
}

__global__ __launch_bounds__(128) void k_xskew(const float* __restrict__ skew,
    const float* __restrict__ Wsk, const float* __restrict__ bsk, float* __restrict__ g) {
  int b = blockIdx.x, f = threadIdx.x;
  float acc = bsk[f];
  for (int s = 0; s < 64; ++s) acc += skew[b * 64 + s] * Wsk[s * Fd + f];
  g[b * 384 + 256 + f] = fmaxf(acc, 0.f);
}

__global__ __launch_bounds__(128) void k_mlp1(const float* __restrict__ g,
    const float* __restrict__ Wl, const float* __restrict__ bl, float* __restrict__ o) {
  int b = blockIdx.x, f = threadIdx.x;
  float acc = bl[f];
  for (int s = 0; s < 384; ++s) acc += g[b * 384 + s] * Wl[s * 128 + f];
  o[b * 128 + f] = fmaxf(acc, 0.f);
}
__global__ __launch_bounds__(64) void k_mlp2(const float* __restrict__ x,
    const float* __restrict__ Wl, const float* __restrict__ bl, float* __restrict__ o) {
  int b = blockIdx.x, f = threadIdx.x;
  float acc = bl[f];
  for (int s = 0; s < 128; ++s) acc += x[b * 128 + s] * Wl[s * 64 + f];
  o[b * 64 + f] = fmaxf(acc, 0.f);
}
__global__ __launch_bounds__(64) void k_mlp3(const float* __restrict__ x,
    const float* __restrict__ Wl, const float* __restrict__ bl, float* __restrict__ out) {
  int b = blockIdx.x, f = threadIdx.x;
  __shared__ float lg[10];
  if (f < 10) {
    float acc = bl[f];
    for (int s = 0; s < 64; ++s) acc += x[b * 64 + s] * Wl[s * 10 + f];
    lg[f] = acc;
  }
  __syncthreads();
  if (f == 0) {
    float m = lg[0];
    for (int c = 1; c < 10; ++c) m = fmaxf(m, lg[c]);
    float s = 0.f;
    for (int c = 0; c < 10; ++c) s += expf(lg[c] - m);
    float l = logf(s);
    for (int c = 0; c < 10; ++c) out[b * 10 + c] = lg[c] - m - l;
  }
}

extern "C" void kernel_launch(void* const* d_in, const int* in_sizes, int n_in,
                              void* d_out, int out_size, void* d_ws, size_t ws_size,
                              hipStream_t stream) {
  const float* x    = (const float*)d_in[0];
  const int*   src  = (const int*)d_in[1];
  const int*   dst  = (const int*)d_in[2];
  const float* skew = (const float*)d_in[3];
  const float* W1   = (const float*)d_in[4];
  const float* b1   = (const float*)d_in[5];
  const float* W2   = (const float*)d_in[6];
  const float* b2   = (const float*)d_in[7];
  const float* W3   = (const float*)d_in[8];
  const float* b3   = (const float*)d_in[9];
  const float* att1 = (const float*)d_in[10];
  const float* att2 = (const float*)d_in[11];
  const float* Wsk  = (const float*)d_in[12];
  const float* bsk  = (const float*)d_in[13];
  const float* Wl1  = (const float*)d_in[14];
  const float* bl1  = (const float*)d_in[15];
  const float* Wl2  = (const float*)d_in[16];
  const float* bl2  = (const float*)d_in[17];
  const float* Wl3  = (const float*)d_in[18];
  const float* bl3  = (const float*)d_in[19];
  float* out = (float*)d_out;

  char* base = (char*)d_ws;
  size_t off = 0;
  auto alloc = [&](size_t bytes) -> void* {
    void* p = base + off;
    off += (bytes + 255) & ~(size_t)255;
    return p;
  };

  unsigned* adj = (unsigned*)alloc((size_t)Bb * N0 * 32 * 4);        // 8 MB
  float* dis0 = (float*)alloc((size_t)Bb * N0 * 4);
  float* dis1 = (float*)alloc((size_t)Bb * N0 * 4);
  int*   degv = (int*)alloc((size_t)Bb * N0 * 4);
  float* bigA = (float*)alloc((size_t)64 * 1024 * 1024);             // 64 MB multi-use
  float* XW  = bigA;                                                  // [B,1024,128]
  float* h1  = bigA + (size_t)Bb * N0 * Fd;                           // [B,1024,128]
  float* A1  = bigA;                                                  // [B,512,512] (after h1 dead)
  float* XW3 = bigA;                                                  // [B,256,128] (after A1 dead)
  float* h3  = bigA + (size_t)Bb * K2 * Fd;                           // [B,256,128]
  float* score = (float*)alloc((size_t)Bb * N0 * 4);
  int*   perm1 = (int*)alloc((size_t)Bb * K1 * 4);
  float* Xp1 = (float*)alloc((size_t)Bb * K1 * Fd * 4);               // later reused as A2
  float* A2  = Xp1;                                                   // [B,256,256] = same bytes
  float* ar1 = (float*)alloc((size_t)Bb * K1 * 4);
  float* ac1 = (float*)alloc((size_t)Bb * K1 * 4);
  float* disc2 = (float*)alloc((size_t)Bb * K1 * 4);
  float* sa2   = (float*)alloc((size_t)Bb * K1 * 4);
  float* disn2 = (float*)alloc((size_t)Bb * K1 * 4);
  float* diag2 = (float*)alloc((size_t)Bb * K1 * 4);
  float* XW2 = (float*)alloc((size_t)Bb * K1 * Fd * 4);               // 16 MB
  float* h2  = (float*)alloc((size_t)Bb * K1 * Fd * 4);               // 16 MB (contiguous w/ XW2)
  int*   perm2 = (int*)alloc((size_t)Bb * K2 * 4);
  float* Xp2 = (float*)alloc((size_t)Bb * K2 * Fd * 4);
  float* ar2 = (float*)alloc((size_t)Bb * K2 * 4);
  float* ac2 = (float*)alloc((size_t)Bb * K2 * 4);
  float* disc3 = (float*)alloc((size_t)Bb * K2 * 4);
  float* sa3   = (float*)alloc((size_t)Bb * K2 * 4);
  float* disn3 = (float*)alloc((size_t)Bb * K2 * 4);
  float* diag3 = (float*)alloc((size_t)Bb * K2 * 4);
  float* g  = (float*)alloc((size_t)Bb * 384 * 4);
  float* t1 = (float*)alloc((size_t)Bb * 128 * 4);
  float* t2 = (float*)alloc((size_t)Bb * 64 * 4);
  // nbr [B*N0][128] u16 = 16 MB; overlays XW2 (dead until stage-2 gemm,
  // nbr dead after k_nis1).
  unsigned short* nbr = (unsigned short*)XW2;
  (void)ws_size; (void)in_sizes; (void)n_in; (void)out_size;

  // stage 1: fused graph build (scatter+degree+adjlist in LDS), then conv/nis
  k_graph<<<Bb * 4, 1024, 0, stream>>>(src, dst, adj, nbr, degv, dis0, dis1);
  k_gemm128<<<Bb * N0 / 64, 256, 0, stream>>>(x, W1, XW);
  k_conv1<<<Bb * N0, 128, 0, stream>>>(nbr, degv, XW, dis1, b1, h1);
  k_nis1<<<Bb * N0, 128, 0, stream>>>(nbr, degv, h1, dis0, score);
  k_topk<<<Bb, N0, 0, stream>>>(score, perm1, N0, K1);
  k_gather<<<Bb * K1, 128, 0, stream>>>(h1, perm1, att1, Xp1, ar1, ac1, N0, K1);
  k_readout<<<Bb, 1024, 0, stream>>>(Xp1, K1, g, 1);
  k_buildA_bit<<<Bb * K1 / 4, 256, 0, stream>>>(adj, perm1, ar1, ac1, A1,
                                                disc2, sa2, disn2, diag2);  // overwrites XW/h1

  // stage 2: dense A1 (fused mm + epilogues, split-K x2)
  k_gemm128<<<Bb * K1 / 64, 256, 0, stream>>>(Xp1, W2, XW2);
  k_mmf<0><<<Bb * (K1 / 64), 512, 0, stream>>>(A1, XW2, disc2, sa2, b2, h2, K1);
  k_mmf<1><<<Bb * (K1 / 64), 512, 0, stream>>>(A1, h2, disn2, diag2, nullptr, score, K1);
  k_topk<<<Bb, K1, 0, stream>>>(score, perm2, K1, K2);
  k_gather<<<Bb * K2, 128, 0, stream>>>(h2, perm2, att2, Xp2, ar2, ac2, K1, K2);
  k_readout<<<Bb, 1024, 0, stream>>>(Xp2, K2, g, 0);
  k_buildA_dense<<<Bb * K2 / 4, 256, 0, stream>>>(A1, perm2, ar2, ac2, A2,
                                                  disc3, sa3, disn3, diag3);  // overwrites Xp1

  // stage 3: dense A2
  k_gemm128<<<Bb * K2 / 64, 256, 0, stream>>>(Xp2, W3, XW3);           // overwrites A1 region
  k_mmf<0><<<Bb * (K2 / 64), 512, 0, stream>>>(A2, XW3, disc3, sa3, b3, h3, K2);
  k_readout<<<Bb, 1024, 0, stream>>>(h3, K2, g, 0);

  // head
  k_xskew<<<Bb, 128, 0, stream>>>(skew, Wsk, bsk, g);
  k_mlp1<<<Bb, 128, 0, stream>>>(g, Wl1, bl1, t1);
  k_mlp2<<<Bb, 64, 0, stream>>>(t1, Wl2, bl2, t2);
  k_mlp3<<<Bb, 64, 0, stream>>>(t2, Wl3, bl3, out);
}